// Round 3
// baseline (1209.828 us; speedup 1.0000x reference)
//
#include <hip/hip_runtime.h>
#include <hip/hip_bf16.h>

#define T_ 4
#define N_ 20000
#define E_ 320000
#define R_ 2
#define DIN 64
#define G_ 256   // H*Dh
#define P_ 8     // T*R

typedef unsigned short u16;
typedef __attribute__((ext_vector_type(8))) short bf16x8;
typedef __attribute__((ext_vector_type(4))) float f32x4;

__device__ __forceinline__ float bf2f(u16 u) {
    unsigned int i = ((unsigned int)u) << 16; float f;
    __builtin_memcpy(&f, &i, 4); return f;
}
__device__ __forceinline__ u16 f2bf(float f) {
    unsigned int i; __builtin_memcpy(&i, &f, 4);
    unsigned int r = i + 0x7fffu + ((i >> 16) & 1u);
    return (u16)(r >> 16);
}
__device__ __forceinline__ float sigm(float x) { return 1.f / (1.f + __expf(-x)); }

// ---------------- shared MFMA GEMM core (bf16 operands, f32 acc) ----------------
// C[m0+wv*16+row16, 0:256] = A[., 0:K] @ B[0:K, 0:256], K = kchunks*64.
// C/D layout: col = lane&15, row = (lane>>4)*4 + reg.
// AF32: A is f32 in global, converted to bf16 during LDS staging.
template <bool AF32>
__device__ __forceinline__ void gemm_core(
    const void* __restrict__ Av, const u16* __restrict__ B,
    int M, int Astride, int kchunks, int m0,
    u16* Ats, u16* Bts, f32x4* acc)
{
    const int tid = threadIdx.x;
    const int lane = tid & 63, wv = tid >> 6;
    const int col = lane & 15, quad = lane >> 4;
    #pragma unroll
    for (int cf = 0; cf < 16; ++cf) { acc[cf][0]=0.f; acc[cf][1]=0.f; acc[cf][2]=0.f; acc[cf][3]=0.f; }

    for (int kc = 0; kc < kchunks; ++kc) {
        // stage B chunk transposed: Bts[n][kk] (pad stride 72 halves)
        {
            const u16* Bg = B + (size_t)kc * 64 * G_;
            #pragma unroll 8
            for (int kk = 0; kk < 64; ++kk)
                Bts[tid * 72 + kk] = Bg[kk * G_ + tid];
        }
        // stage A chunk: 64 rows x 64 halves; each thread covers 16 elements
        {
            int rowi = tid >> 2, seg = (tid & 3) * 16;
            int row = m0 + rowi;
            if (AF32) {
                const float* A = (const float*)Av;
                float fv[16];
                #pragma unroll
                for (int j = 0; j < 16; ++j) fv[j] = 0.f;
                if (row < M) {
                    const float4* Ag = (const float4*)(A + (size_t)row * Astride + kc * 64 + seg);
                    float4 f0 = Ag[0], f1 = Ag[1], f2 = Ag[2], f3 = Ag[3];
                    fv[0]=f0.x; fv[1]=f0.y; fv[2]=f0.z; fv[3]=f0.w;
                    fv[4]=f1.x; fv[5]=f1.y; fv[6]=f1.z; fv[7]=f1.w;
                    fv[8]=f2.x; fv[9]=f2.y; fv[10]=f2.z; fv[11]=f2.w;
                    fv[12]=f3.x; fv[13]=f3.y; fv[14]=f3.z; fv[15]=f3.w;
                }
                union { u16 h[16]; uint4 q[2]; } cv;
                #pragma unroll
                for (int j = 0; j < 16; ++j) cv.h[j] = f2bf(fv[j]);
                *(uint4*)(Ats + rowi * 72 + seg)     = cv.q[0];
                *(uint4*)(Ats + rowi * 72 + seg + 8) = cv.q[1];
            } else {
                const u16* A = (const u16*)Av;
                uint4 v0 = make_uint4(0,0,0,0), v1 = make_uint4(0,0,0,0);
                if (row < M) {
                    const uint4* Ag = (const uint4*)(A + (size_t)row * Astride + kc * 64 + seg);
                    v0 = Ag[0]; v1 = Ag[1];
                }
                *(uint4*)(Ats + rowi * 72 + seg)     = v0;
                *(uint4*)(Ats + rowi * 72 + seg + 8) = v1;
            }
        }
        __syncthreads();
        #pragma unroll
        for (int ks = 0; ks < 2; ++ks) {
            bf16x8 a = *(const bf16x8*)(Ats + (wv * 16 + col) * 72 + ks * 32 + quad * 8);
            #pragma unroll
            for (int cf = 0; cf < 16; ++cf) {
                bf16x8 b = *(const bf16x8*)(Bts + (cf * 16 + col) * 72 + ks * 32 + quad * 8);
                acc[cf] = __builtin_amdgcn_mfma_f32_16x16x32_bf16(a, b, acc[cf], 0, 0, 0);
            }
        }
        __syncthreads();
    }
}

// ---------------- GAT projection (per (t,r) slice) + als epilogue ----------------
__global__ __launch_bounds__(256) void k_proj(
    const float* __restrict__ x_t, const u16* __restrict__ Wsrc_r, const float* __restrict__ att_src_r,
    u16* __restrict__ hs, float* __restrict__ als_p)
{
    __shared__ u16 Bts[256 * 72];
    __shared__ u16 Ats[64 * 72];
    int m0 = blockIdx.x * 64;
    f32x4 acc[16];
    gemm_core<true>(x_t, Wsrc_r, N_, DIN, 1, m0, Ats, Bts, acc);

    const int tid = threadIdx.x, lane = tid & 63, wv = tid >> 6;
    const int col = lane & 15, quad = lane >> 4;
    int rowbase = m0 + wv * 16 + quad * 4;

    float ap[4][4]; // [h][reg]
    #pragma unroll
    for (int h = 0; h < 4; ++h)
        #pragma unroll
        for (int reg = 0; reg < 4; ++reg) ap[h][reg] = 0.f;

    #pragma unroll
    for (int cf = 0; cf < 16; ++cf) {
        int gcol = cf * 16 + col;
        float av = att_src_r[gcol];
        int h = cf >> 2;
        #pragma unroll
        for (int reg = 0; reg < 4; ++reg) {
            float v = acc[cf][reg];
            int row = rowbase + reg;
            if (row < N_) hs[(size_t)row * G_ + gcol] = f2bf(v);
            ap[h][reg] += v * av;
        }
    }
    #pragma unroll
    for (int h = 0; h < 4; ++h)
        #pragma unroll
        for (int reg = 0; reg < 4; ++reg) {
            float v = ap[h][reg];
            v += __shfl_xor(v, 1); v += __shfl_xor(v, 2);
            v += __shfl_xor(v, 4); v += __shfl_xor(v, 8);
            ap[h][reg] = v;
        }
    if (col == 0) {
        #pragma unroll
        for (int reg = 0; reg < 4; ++reg) {
            int row = rowbase + reg;
            if (row < N_) {
                #pragma unroll
                for (int h = 0; h < 4; ++h)
                    als_p[(size_t)row * 4 + h] = ap[h][reg];
            }
        }
    }
}

// ---------------- ald via folded GEMV (f32 x) ----------------
__global__ __launch_bounds__(256) void k_ald(
    const float* __restrict__ x, const float* __restrict__ wd, float* __restrict__ ald_all)
{
    int p = blockIdx.y, t = p >> 1, r = p & 1;
    int idx = blockIdx.x * 256 + threadIdx.x;
    if (idx >= N_ * 4) return;
    int n = idx >> 2, h = idx & 3;
    const float* xr = x + ((size_t)t * N_ + n) * 64;
    const float* wp = wd + r * 64 * 4 + h;
    float s = 0.f;
    #pragma unroll 8
    for (int k = 0; k < 64; ++k) s += xr[k] * wp[k * 4];
    ald_all[(size_t)p * N_ * 4 + idx] = s;
}

// ---------------- prep: wd, weight casts, transposed LSTM weights, folded bias ----------------
__global__ void k_prep(const float* __restrict__ Wdst, const float* __restrict__ att_dst,
                       const float* __restrict__ Wih, const float* __restrict__ Whh,
                       const float* __restrict__ bih, const float* __restrict__ bhh,
                       const float* __restrict__ Wsrc, const float* __restrict__ raW1,
                       float* __restrict__ wd, u16* __restrict__ Wc, float* __restrict__ biasv,
                       u16* __restrict__ Wsrc_bf, u16* __restrict__ raW1_bf)
{
    int tid = threadIdx.x;
    for (int r = 0; r < 2; ++r) {
        int k = tid >> 2, h = tid & 3;
        float s = 0.f;
        for (int c = 0; c < 64; ++c)
            s += Wdst[((size_t)r * 64 + k) * 256 + h * 64 + c] * att_dst[r * 256 + h * 64 + c];
        wd[(r * 64 + k) * 4 + h] = s;
    }
    for (int idx = tid; idx < 128 * 256; idx += 256) {
        int k = idx >> 8, j = idx & 255;
        Wc[idx] = f2bf((k < 64) ? Wih[j * 64 + k] : Whh[j * 64 + (k - 64)]);
    }
    biasv[tid] = bih[tid] + bhh[tid];
    for (int idx = tid; idx < 2 * 64 * 256; idx += 256) Wsrc_bf[idx] = f2bf(Wsrc[idx]);
    for (int idx = tid; idx < 64 * 256; idx += 256)     raW1_bf[idx] = f2bf(raW1[idx]);
}

// ---------------- CSR build ----------------
__global__ void k_hist(const int* __restrict__ ei, int* __restrict__ counts) {
    int p = blockIdx.y;
    int e = blockIdx.x * 256 + threadIdx.x;
    if (e >= E_) return;
    int dst = ei[((size_t)p * 2 + 1) * E_ + e];
    atomicAdd(&counts[p * N_ + dst], 1);
}

__global__ __launch_bounds__(1024) void k_scan(const int* __restrict__ counts,
                                               int* __restrict__ offsets, int* __restrict__ cursor)
{
    int p = blockIdx.x;
    __shared__ int wtot[16];
    int tid = threadIdx.x, lane = tid & 63, wid = tid >> 6;
    int carry = 0;
    const int* cnt = counts + (size_t)p * N_;
    int* ofs = offsets + (size_t)p * (N_ + 1);
    int* cur = cursor + (size_t)p * N_;
    for (int base = 0; base < N_; base += 1024) {
        int i = base + tid;
        int v = (i < N_) ? cnt[i] : 0;
        int incl = v;
        for (int d = 1; d < 64; d <<= 1) { int u = __shfl_up(incl, d); if (lane >= d) incl += u; }
        if (lane == 63) wtot[wid] = incl;
        __syncthreads();
        if (tid < 16) {
            int iv = wtot[tid];
            for (int d = 1; d < 16; d <<= 1) { int u = __shfl_up(iv, d); if (tid >= d) iv += u; }
            wtot[tid] = iv;
        }
        __syncthreads();
        int woff = (wid > 0) ? wtot[wid - 1] : 0;
        int tot = wtot[15];
        int excl = carry + woff + incl - v;
        if (i < N_) { ofs[i] = excl; cur[i] = excl; }
        carry += tot;
        __syncthreads();
    }
    if (tid == 0) ofs[N_] = carry;
}

__global__ void k_scatter(const int* __restrict__ ei, int* __restrict__ cursor, u16* __restrict__ csr) {
    int p = blockIdx.y;
    int e = blockIdx.x * 256 + threadIdx.x;
    if (e >= E_) return;
    int src = ei[((size_t)p * 2 + 0) * E_ + e];
    int dst = ei[((size_t)p * 2 + 1) * E_ + e];
    int pos = atomicAdd(&cursor[p * N_ + dst], 1);
    csr[(size_t)p * E_ + pos] = (u16)src;
}

// ---------------- GAT softmax-aggregation: one wave per dst node ----------------
__global__ __launch_bounds__(256) void k_agg(
    const int* __restrict__ off, const u16* __restrict__ srcs,
    const float* __restrict__ als, const float* __restrict__ ald,
    const u16* __restrict__ hs, u16* __restrict__ intra, int t, int r)
{
    int tid = threadIdx.x, lane = tid & 63, wv = tid >> 6;
    int n = blockIdx.x * 4 + wv;
    int h = lane >> 4, c4 = (lane & 15) * 4;
    int o0 = off[n], o1 = off[n + 1];
    float aldv = ald[(size_t)n * 4 + h];

    float m = -1e30f;
    for (int i = o0; i < o1; ++i) {
        int s = srcs[i];
        float e = als[s * 4 + h] + aldv;
        e = (e > 0.f) ? e : 0.2f * e;
        m = fmaxf(m, e);
    }
    float den = 0.f, a0 = 0.f, a1 = 0.f, a2 = 0.f, a3 = 0.f;
    for (int i = o0; i < o1; ++i) {
        int s = srcs[i];
        float e = als[s * 4 + h] + aldv;
        e = (e > 0.f) ? e : 0.2f * e;
        float pv = __expf(e - m);
        den += pv;
        ushort4 hv = *(const ushort4*)(hs + (size_t)s * G_ + h * 64 + c4);
        a0 += pv * bf2f(hv.x); a1 += pv * bf2f(hv.y);
        a2 += pv * bf2f(hv.z); a3 += pv * bf2f(hv.w);
    }
    float sc = 0.25f / (den + 1e-16f);
    a0 *= sc; a1 *= sc; a2 *= sc; a3 *= sc;
    a0 += __shfl_xor(a0, 16); a0 += __shfl_xor(a0, 32);
    a1 += __shfl_xor(a1, 16); a1 += __shfl_xor(a1, 32);
    a2 += __shfl_xor(a2, 16); a2 += __shfl_xor(a2, 32);
    a3 += __shfl_xor(a3, 16); a3 += __shfl_xor(a3, 32);
    if (h == 0) {
        u16* op = intra + (((size_t)t * N_ + n) * 2 + r) * 64 + c4;
        ushort4 ov;
        ov.x = f2bf(a0); ov.y = f2bf(a1); ov.z = f2bf(a2); ov.w = f2bf(a3);
        *(ushort4*)op = ov;
    }
}

// ---------------- RelationAgg GEMM with fused tanh(.)@W2 epilogue ----------------
__global__ __launch_bounds__(256) void k_relagg(
    const u16* __restrict__ A, const u16* __restrict__ W1bf, const float* __restrict__ b1,
    const float* __restrict__ W2, float* __restrict__ svals)
{
    __shared__ u16 Bts[256 * 72];
    __shared__ u16 Ats[64 * 72];
    int m0 = blockIdx.x * 64;
    f32x4 acc[16];
    gemm_core<false>(A, W1bf, T_ * N_ * R_, 64, 1, m0, Ats, Bts, acc);

    const int tid = threadIdx.x, lane = tid & 63, wv = tid >> 6;
    const int col = lane & 15, quad = lane >> 4;
    int rowbase = m0 + wv * 16 + quad * 4;
    float sp[4] = {0.f, 0.f, 0.f, 0.f};
    #pragma unroll
    for (int cf = 0; cf < 16; ++cf) {
        int gcol = cf * 16 + col;
        float bb = b1[gcol];
        float ww = W2[gcol];
        #pragma unroll
        for (int reg = 0; reg < 4; ++reg)
            sp[reg] += tanhf(acc[cf][reg] + bb) * ww;
    }
    #pragma unroll
    for (int reg = 0; reg < 4; ++reg) {
        float v = sp[reg];
        v += __shfl_xor(v, 1); v += __shfl_xor(v, 2);
        v += __shfl_xor(v, 4); v += __shfl_xor(v, 8);
        sp[reg] = v;
    }
    if (col == 0) {
        #pragma unroll
        for (int reg = 0; reg < 4; ++reg) {
            int row = rowbase + reg;
            if (row < T_ * N_ * R_) svals[row] = sp[reg];
        }
    }
}

__global__ void k_betasum(const float* __restrict__ svals, float* __restrict__ ssum) {
    int p = blockIdx.x, t = p >> 1, r = p & 1;
    __shared__ float red[256];
    float s = 0.f;
    for (int n = threadIdx.x; n < N_; n += 256)
        s += svals[((size_t)t * N_ + n) * 2 + r];
    red[threadIdx.x] = s;
    __syncthreads();
    for (int st = 128; st > 0; st >>= 1) {
        if (threadIdx.x < st) red[threadIdx.x] += red[threadIdx.x + st];
        __syncthreads();
    }
    if (threadIdx.x == 0) ssum[p] = red[0];
}

__global__ void k_betafinal(const float* __restrict__ ssum, float* __restrict__ beta) {
    int t = threadIdx.x;
    if (t >= 4) return;
    float s0 = ssum[t * 2] * (1.f / N_), s1 = ssum[t * 2 + 1] * (1.f / N_);
    float mx = fmaxf(s0, s1);
    float e0 = __expf(s0 - mx), e1 = __expf(s1 - mx);
    float inv = 1.f / (e0 + e1);
    beta[t * 2] = e0 * inv; beta[t * 2 + 1] = e1 * inv;
}

// ---------------- LSTM: assemble intra-half of A_step ----------------
__global__ void k_assemble(const u16* __restrict__ intra, const float* __restrict__ beta,
                           u16* __restrict__ A_step, int t)
{
    int idx = blockIdx.x * 256 + threadIdx.x;
    if (idx >= N_ * 64) return;
    int n = idx >> 6, c = idx & 63;
    float b0 = beta[t * 2], b1 = beta[t * 2 + 1];
    const u16* ib = intra + ((size_t)t * N_ + n) * 128;
    float iv = b0 * bf2f(ib[c]) + b1 * bf2f(ib[64 + c]);
    A_step[(size_t)n * 128 + c] = f2bf(iv);
}

// ---------------- LSTM GEMM + fused cell update ----------------
// Lane (col,quad) holds, for row=rowbase+reg, gate columns col+16*cf.
// Channel c = j*16+col (j in [0,4)): gates i,f,g,o are cf = j, j+4, j+8, j+12.
__global__ __launch_bounds__(256) void k_lstm(
    const u16* __restrict__ A_step_in, const u16* __restrict__ Wc,
    const float* __restrict__ biasv, float* __restrict__ cbuf,
    u16* __restrict__ A_step_h, u16* __restrict__ feats, int t)
{
    __shared__ u16 Bts[256 * 72];
    __shared__ u16 Ats[64 * 72];
    int m0 = blockIdx.x * 64;
    f32x4 acc[16];
    gemm_core<false>(A_step_in, Wc, N_, 128, 2, m0, Ats, Bts, acc);

    const int tid = threadIdx.x, lane = tid & 63, wv = tid >> 6;
    const int col = lane & 15, quad = lane >> 4;
    int rowbase = m0 + wv * 16 + quad * 4;
    #pragma unroll
    for (int j = 0; j < 4; ++j) {
        int c = j * 16 + col;
        float bi = biasv[c], bf_ = biasv[64 + c], bg = biasv[128 + c], bo = biasv[192 + c];
        #pragma unroll
        for (int reg = 0; reg < 4; ++reg) {
            int row = rowbase + reg;
            if (row < N_) {
                float gi = acc[j][reg] + bi;
                float gf = acc[j + 4][reg] + bf_;
                float gg = acc[j + 8][reg] + bg;
                float go = acc[j + 12][reg] + bo;
                float cc = cbuf[(size_t)row * 64 + c];
                cc = sigm(gf) * cc + sigm(gi) * tanhf(gg);
                float hh = sigm(go) * tanhf(cc);
                cbuf[(size_t)row * 64 + c] = cc;
                A_step_h[(size_t)row * 128 + 64 + c] = f2bf(hh);
                feats[(size_t)row * 256 + t * 64 + c] = f2bf(hh);
            }
        }
    }
}

// ---------------- temporal causal MHA, fully fused, one wave per node ----------------
__global__ __launch_bounds__(256) void k_attn(
    const u16* __restrict__ feats, const float* __restrict__ pos_emb,
    const float* __restrict__ Wq, const float* __restrict__ Wk, const float* __restrict__ Wv,
    float* __restrict__ out)
{
    __shared__ u16 Wl[3 * 4096];
    __shared__ float scr[4][1088];
    int tid = threadIdx.x, lane = tid & 63, wv = tid >> 6;
    for (int i = tid; i < 4096; i += 256) {
        Wl[i] = f2bf(Wq[i]); Wl[4096 + i] = f2bf(Wk[i]); Wl[8192 + i] = f2bf(Wv[i]);
    }
    __syncthreads();
    int n = blockIdx.x * 4 + wv;
    float* ti = scr[wv];
    float* qs = ti + 256; float* ks_ = qs + 256; float* vs = ks_ + 256; float* as_ = vs + 256;

    #pragma unroll
    for (int t = 0; t < 4; ++t)
        ti[t * 64 + lane] = bf2f(feats[(size_t)n * 256 + t * 64 + lane]) + pos_emb[t * 64 + lane];
    __syncthreads();

    float aq[4] = {0,0,0,0}, ak[4] = {0,0,0,0}, av[4] = {0,0,0,0};
    for (int k = 0; k < 64; ++k) {
        float wq = bf2f(Wl[k * 64 + lane]);
        float wk = bf2f(Wl[4096 + k * 64 + lane]);
        float wvv = bf2f(Wl[8192 + k * 64 + lane]);
        #pragma unroll
        for (int t = 0; t < 4; ++t) {
            float tv = ti[t * 64 + k];
            aq[t] += tv * wq; ak[t] += tv * wk; av[t] += tv * wvv;
        }
    }
    #pragma unroll
    for (int t = 0; t < 4; ++t) {
        qs[t * 64 + lane] = aq[t]; ks_[t * 64 + lane] = ak[t]; vs[t * 64 + lane] = av[t];
    }
    __syncthreads();

    // scores: lane -> (h, tq, tk)
    {
        int h = lane >> 4, tq = (lane >> 2) & 3, tk = lane & 3;
        float s = 0.f;
        #pragma unroll
        for (int j = 0; j < 16; ++j)
            s += qs[tq * 64 + h * 16 + j] * ks_[tk * 64 + h * 16 + j];
        s *= 0.5f;                       // 1/sqrt(T), T=4
        if (tk > tq) s = -4294967295.0f; // NEG_INF = -2^32+1
        float mx = fmaxf(s, __shfl_xor(s, 1)); mx = fmaxf(mx, __shfl_xor(mx, 2));
        float pv = __expf(s - mx);
        float sm = pv + __shfl_xor(pv, 1); sm += __shfl_xor(sm, 2);
        as_[lane] = pv / sm;
    }
    __syncthreads();

    int h = lane >> 4;
    #pragma unroll
    for (int t = 0; t < 4; ++t) {
        float o = 0.f;
        #pragma unroll
        for (int k2 = 0; k2 < 4; ++k2)
            o += as_[h * 16 + t * 4 + k2] * vs[k2 * 64 + lane];
        out[(size_t)n * 256 + t * 64 + lane] = o;
    }
}

// ---------------- launcher ----------------
extern "C" void kernel_launch(void* const* d_in, const int* in_sizes, int n_in,
                              void* d_out, int out_size, void* d_ws, size_t ws_size,
                              hipStream_t stream) {
    const float* x     = (const float*)d_in[0];
    const int* ei      = (const int*)d_in[1];
    const float* Wsrc  = (const float*)d_in[2];
    const float* Wdst  = (const float*)d_in[3];
    const float* att_src = (const float*)d_in[4];
    const float* att_dst = (const float*)d_in[5];
    const float* raW1  = (const float*)d_in[6];
    const float* rab1  = (const float*)d_in[7];
    const float* raW2  = (const float*)d_in[8];
    const float* Wih   = (const float*)d_in[9];
    const float* Whh   = (const float*)d_in[10];
    const float* bih   = (const float*)d_in[11];
    const float* bhh   = (const float*)d_in[12];
    const float* pos   = (const float*)d_in[13];
    const float* Wq    = (const float*)d_in[14];
    const float* Wk    = (const float*)d_in[15];
    const float* Wv    = (const float*)d_in[16];
    float* out = (float*)d_out;

    char* w = (char*)d_ws;
    size_t off = 0;
    auto alloc = [&](size_t bytes) -> char* {
        char* pp = w + off; off += (bytes + 255) & ~(size_t)255; return pp;
    };
    // ---- long-lived ----
    u16*   intra   = (u16*)  alloc((size_t)T_ * N_ * R_ * 64 * 2);  // 20.48 MB
    float* svals   = (float*)alloc((size_t)T_ * N_ * R_ * 4);       // 0.64 MB
    float* ssum    = (float*)alloc(256);
    float* beta    = (float*)alloc(256);
    float* wd      = (float*)alloc(2 * 64 * 4 * 4);
    u16*   Wc      = (u16*)  alloc(128 * 256 * 2);
    float* biasv   = (float*)alloc(256 * 4);
    u16*   Wsrc_bf = (u16*)  alloc(2 * 64 * 256 * 2);
    u16*   raW1_bf = (u16*)  alloc(64 * 256 * 2);
    // ---- union region: phase-1 (GAT) / phase-2 (LSTM+attn) overlay ----
    char*  ubase   = alloc(0);
    // phase 1
    size_t uoff = 0;
    auto ualloc = [&](size_t bytes) -> char* {
        char* pp = ubase + uoff; uoff += (bytes + 255) & ~(size_t)255; return pp;
    };
    int*   counts  = (int*)  ualloc((size_t)P_ * N_ * 4);           // 0.64 MB
    int*   offsets = (int*)  ualloc((size_t)P_ * (N_ + 1) * 4);     // 0.64 MB
    int*   cursor  = (int*)  ualloc((size_t)P_ * N_ * 4);           // 0.64 MB
    u16*   csr     = (u16*)  ualloc((size_t)P_ * E_ * 2);           // 5.12 MB
    float* als_all = (float*)ualloc((size_t)P_ * N_ * 4 * 4);       // 2.56 MB
    float* ald_all = (float*)ualloc((size_t)P_ * N_ * 4 * 4);       // 2.56 MB
    u16*   hs_p    = (u16*)  ualloc((size_t)N_ * G_ * 2);           // 10.24 MB
    // phase 2 (overlays phase 1 from ubase)
    float* cbuf    = (float*)(ubase);                                // 5.12 MB
    u16*   A_step  = (u16*)  (ubase + 5300000);                      // 5.12 MB
    u16*   feats   = (u16*)  (ubase + 10600000);                     // 10.24 MB
    (void)ws_size; (void)in_sizes; (void)n_in;

    hipMemsetAsync(out, 0, (size_t)out_size * 4, stream);
    hipMemsetAsync(counts, 0, (size_t)P_ * N_ * 4, stream);
    k_prep<<<1, 256, 0, stream>>>(Wdst, att_dst, Wih, Whh, bih, bhh, Wsrc, raW1,
                                  wd, Wc, biasv, Wsrc_bf, raW1_bf);
    k_hist<<<dim3(1250, 8), 256, 0, stream>>>(ei, counts);
    k_scan<<<8, 1024, 0, stream>>>(counts, offsets, cursor);
    k_scatter<<<dim3(1250, 8), 256, 0, stream>>>(ei, cursor, csr);
    k_ald<<<dim3(313, 8), 256, 0, stream>>>(x, wd, ald_all);
    for (int p = 0; p < P_; ++p) {
        int t = p >> 1, r = p & 1;
        k_proj<<<313, 256, 0, stream>>>(x + (size_t)t * N_ * DIN, Wsrc_bf + (size_t)r * DIN * G_,
                                        att_src + r * G_, hs_p, als_all + (size_t)p * N_ * 4);
        k_agg<<<5000, 256, 0, stream>>>(offsets + (size_t)p * (N_ + 1), csr + (size_t)p * E_,
                                        als_all + (size_t)p * N_ * 4, ald_all + (size_t)p * N_ * 4,
                                        hs_p, intra, t, r);
    }
    k_relagg<<<2500, 256, 0, stream>>>(intra, raW1_bf, rab1, raW2, svals);
    k_betasum<<<8, 256, 0, stream>>>(svals, ssum);
    k_betafinal<<<1, 64, 0, stream>>>(ssum, beta);
    hipMemsetAsync(cbuf, 0, (size_t)N_ * 64 * 4, stream);
    hipMemsetAsync(A_step, 0, (size_t)N_ * 128 * 2, stream);
    for (int t = 0; t < T_; ++t) {
        k_assemble<<<5000, 256, 0, stream>>>(intra, beta, A_step, t);
        k_lstm<<<313, 256, 0, stream>>>(A_step, Wc, biasv, cbuf, A_step, feats, t);
    }
    k_attn<<<5000, 256, 0, stream>>>(feats, pos, Wq, Wk, Wv, out);
}

// Round 4
// 849.860 us; speedup vs baseline: 1.4236x; 1.4236x over previous
//
#include <hip/hip_runtime.h>
#include <hip/hip_bf16.h>

#define T_ 4
#define N_ 20000
#define E_ 320000
#define R_ 2
#define DIN 64
#define G_ 256   // H*Dh
#define P_ 8     // T*R
#define BPAD 18432  // 256 * 72 padded B-table halves per 64-k chunk

typedef unsigned short u16;
typedef __attribute__((ext_vector_type(8))) short bf16x8;
typedef __attribute__((ext_vector_type(4))) float f32x4;

__device__ __forceinline__ float bf2f(u16 u) {
    unsigned int i = ((unsigned int)u) << 16; float f;
    __builtin_memcpy(&f, &i, 4); return f;
}
__device__ __forceinline__ u16 f2bf(float f) {
    unsigned int i; __builtin_memcpy(&i, &f, 4);
    unsigned int r = i + 0x7fffu + ((i >> 16) & 1u);
    return (u16)(r >> 16);
}
__device__ __forceinline__ float sigm(float x) { return 1.f / (1.f + __expf(-x)); }

__device__ __forceinline__ bf16x8 load_a_f32(const float* p) {
    float4 f0 = *(const float4*)p;
    float4 f1 = *(const float4*)(p + 4);
    union { u16 h[8]; bf16x8 v; } u;
    u.h[0] = f2bf(f0.x); u.h[1] = f2bf(f0.y); u.h[2] = f2bf(f0.z); u.h[3] = f2bf(f0.w);
    u.h[4] = f2bf(f1.x); u.h[5] = f2bf(f1.y); u.h[6] = f2bf(f1.z); u.h[7] = f2bf(f1.w);
    return u.v;
}

// ---------------- LDS-free MFMA GEMM core ----------------
// C[m0+wv*16+row16, 0:256] = A[., 0:K] @ B[0:K, 0:256], K = kchunks*64.
// A read directly (wave-private rows); B from pre-padded table [n*72+kk] per chunk.
// C/D layout: col = lane&15, row = (lane>>4)*4 + reg.
template <bool AF32>
__device__ __forceinline__ void gemm_direct(
    const void* __restrict__ Av, const u16* __restrict__ Bpad,
    int M, int Astride, int kchunks, int m0, f32x4* acc)
{
    const int tid = threadIdx.x;
    const int lane = tid & 63, wv = tid >> 6;
    const int col = lane & 15, quad = lane >> 4;
    #pragma unroll
    for (int cf = 0; cf < 16; ++cf) { acc[cf][0]=0.f; acc[cf][1]=0.f; acc[cf][2]=0.f; acc[cf][3]=0.f; }

    int row = m0 + wv * 16 + col;
    int row_c = (row < M) ? row : (M - 1);

    for (int kc = 0; kc < kchunks; ++kc) {
        #pragma unroll
        for (int ks = 0; ks < 2; ++ks) {
            bf16x8 a;
            if (AF32) {
                const float* A = (const float*)Av + (size_t)row_c * Astride + kc * 64 + ks * 32 + quad * 8;
                a = load_a_f32(A);
            } else {
                a = *(const bf16x8*)((const u16*)Av + (size_t)row_c * Astride + kc * 64 + ks * 32 + quad * 8);
            }
            const u16* bb = Bpad + kc * BPAD + ks * 32 + quad * 8;
            #pragma unroll
            for (int cf = 0; cf < 16; ++cf) {
                bf16x8 b = *(const bf16x8*)(bb + (cf * 16 + col) * 72);
                acc[cf] = __builtin_amdgcn_mfma_f32_16x16x32_bf16(a, b, acc[cf], 0, 0, 0);
            }
        }
    }
}

// ---------------- GAT projection (per (t,r) slice) + als epilogue ----------------
__global__ __launch_bounds__(256) void k_proj(
    const float* __restrict__ x_t, const u16* __restrict__ Bpad, const float* __restrict__ att_src_r,
    u16* __restrict__ hs, float* __restrict__ als_p)
{
    int m0 = blockIdx.x * 64;
    f32x4 acc[16];
    gemm_direct<true>(x_t, Bpad, N_, DIN, 1, m0, acc);

    const int tid = threadIdx.x, lane = tid & 63, wv = tid >> 6;
    const int col = lane & 15, quad = lane >> 4;
    int rowbase = m0 + wv * 16 + quad * 4;

    float ap[4][4]; // [h][reg]
    #pragma unroll
    for (int h = 0; h < 4; ++h)
        #pragma unroll
        for (int reg = 0; reg < 4; ++reg) ap[h][reg] = 0.f;

    #pragma unroll
    for (int cf = 0; cf < 16; ++cf) {
        int gcol = cf * 16 + col;
        float av = att_src_r[gcol];
        int h = cf >> 2;
        #pragma unroll
        for (int reg = 0; reg < 4; ++reg) {
            float v = acc[cf][reg];
            int row = rowbase + reg;
            if (row < N_) hs[(size_t)row * G_ + gcol] = f2bf(v);
            ap[h][reg] += v * av;
        }
    }
    #pragma unroll
    for (int h = 0; h < 4; ++h)
        #pragma unroll
        for (int reg = 0; reg < 4; ++reg) {
            float v = ap[h][reg];
            v += __shfl_xor(v, 1); v += __shfl_xor(v, 2);
            v += __shfl_xor(v, 4); v += __shfl_xor(v, 8);
            ap[h][reg] = v;
        }
    if (col == 0) {
        #pragma unroll
        for (int reg = 0; reg < 4; ++reg) {
            int row = rowbase + reg;
            if (row < N_) {
                #pragma unroll
                for (int h = 0; h < 4; ++h)
                    als_p[(size_t)row * 4 + h] = ap[h][reg];
            }
        }
    }
}

// ---------------- ald via folded GEMV (f32 x) ----------------
__global__ __launch_bounds__(256) void k_ald(
    const float* __restrict__ x, const float* __restrict__ wd, float* __restrict__ ald_all)
{
    int p = blockIdx.y, t = p >> 1, r = p & 1;
    int idx = blockIdx.x * 256 + threadIdx.x;
    if (idx >= N_ * 4) return;
    int n = idx >> 2, h = idx & 3;
    const float* xr = x + ((size_t)t * N_ + n) * 64;
    const float* wp = wd + r * 64 * 4 + h;
    float s = 0.f;
    #pragma unroll 8
    for (int k = 0; k < 64; ++k) s += xr[k] * wp[k * 4];
    ald_all[(size_t)p * N_ * 4 + idx] = s;
}

// ---------------- prep: wd, padded B-tables (bf16), folded bias ----------------
__global__ void k_prep(const float* __restrict__ Wdst, const float* __restrict__ att_dst,
                       const float* __restrict__ Wih, const float* __restrict__ Whh,
                       const float* __restrict__ bih, const float* __restrict__ bhh,
                       const float* __restrict__ Wsrc, const float* __restrict__ raW1,
                       float* __restrict__ wd, float* __restrict__ biasv,
                       u16* __restrict__ Wsrc_pad, u16* __restrict__ raW1_pad,
                       u16* __restrict__ Wc_pad)
{
    int tid = threadIdx.x, bid = blockIdx.x;
    if (bid == 0) {
        for (int r = 0; r < 2; ++r) {
            int k = tid >> 2, h = tid & 3;
            float s = 0.f;
            for (int c = 0; c < 64; ++c)
                s += Wdst[((size_t)r * 64 + k) * 256 + h * 64 + c] * att_dst[r * 256 + h * 64 + c];
            wd[(r * 64 + k) * 4 + h] = s;
        }
        biasv[tid] = bih[tid] + bhh[tid];
    }
    // Wsrc_pad[r][n*72+kk] = Wsrc[r,kk,n]; raW1_pad[n*72+kk] = raW1[kk,n]
    for (int i = bid * 256 + tid; i < 3 * BPAD; i += gridDim.x * 256) {
        int r = i / BPAD, q = i % BPAD, n = q / 72, kk = q % 72;
        if (r < 2)
            Wsrc_pad[i] = (kk < 64) ? f2bf(Wsrc[(size_t)r * 64 * 256 + kk * 256 + n]) : (u16)0;
        else
            raW1_pad[q] = (kk < 64) ? f2bf(raW1[kk * 256 + n]) : (u16)0;
    }
    // Wc_pad[kc][n*72+kk] = (kc==0 ? Wih : Whh)[n,kk]  (n = gate-col, kk = input-k)
    for (int i = bid * 256 + tid; i < 2 * BPAD; i += gridDim.x * 256) {
        int kc = i / BPAD, q = i % BPAD, n = q / 72, kk = q % 72;
        const float* W = kc ? Whh : Wih;
        Wc_pad[i] = (kk < 64) ? f2bf(W[n * 64 + kk]) : (u16)0;
    }
}

// ---------------- CSR build ----------------
__global__ void k_hist(const int* __restrict__ ei, int* __restrict__ counts, u16* __restrict__ rank) {
    int p = blockIdx.y;
    int e = blockIdx.x * 256 + threadIdx.x;
    if (e >= E_) return;
    int dst = ei[((size_t)p * 2 + 1) * E_ + e];
    rank[(size_t)p * E_ + e] = (u16)atomicAdd(&counts[p * N_ + dst], 1);
}

__global__ __launch_bounds__(1024) void k_scan(const int* __restrict__ counts,
                                               int* __restrict__ offsets)
{
    int p = blockIdx.x;
    __shared__ int wtot[16];
    int tid = threadIdx.x, lane = tid & 63, wid = tid >> 6;
    int carry = 0;
    const int* cnt = counts + (size_t)p * N_;
    int* ofs = offsets + (size_t)p * (N_ + 1);
    for (int base = 0; base < N_; base += 1024) {
        int i = base + tid;
        int v = (i < N_) ? cnt[i] : 0;
        int incl = v;
        for (int d = 1; d < 64; d <<= 1) { int u = __shfl_up(incl, d); if (lane >= d) incl += u; }
        if (lane == 63) wtot[wid] = incl;
        __syncthreads();
        if (tid < 16) {
            int iv = wtot[tid];
            for (int d = 1; d < 16; d <<= 1) { int u = __shfl_up(iv, d); if (tid >= d) iv += u; }
            wtot[tid] = iv;
        }
        __syncthreads();
        int woff = (wid > 0) ? wtot[wid - 1] : 0;
        int tot = wtot[15];
        int excl = carry + woff + incl - v;
        if (i < N_) ofs[i] = excl;
        carry += tot;
        __syncthreads();
    }
    if (tid == 0) ofs[N_] = carry;
}

__global__ void k_scatter(const int* __restrict__ ei, const int* __restrict__ offsets,
                          const u16* __restrict__ rank, u16* __restrict__ csr) {
    int p = blockIdx.y;
    int e = blockIdx.x * 256 + threadIdx.x;
    if (e >= E_) return;
    int src = ei[((size_t)p * 2 + 0) * E_ + e];
    int dst = ei[((size_t)p * 2 + 1) * E_ + e];
    int pos = offsets[p * (N_ + 1) + dst] + (int)rank[(size_t)p * E_ + e];
    csr[(size_t)p * E_ + pos] = (u16)src;
}

// ---------------- GAT softmax-aggregation: one wave per dst node, single pass ----------------
__global__ __launch_bounds__(256) void k_agg(
    const int* __restrict__ off, const u16* __restrict__ srcs,
    const float* __restrict__ als, const float* __restrict__ ald,
    const u16* __restrict__ hs, u16* __restrict__ intra, int t, int r)
{
    int tid = threadIdx.x, lane = tid & 63, wv = tid >> 6;
    int n = blockIdx.x * 4 + wv;
    int h = lane >> 4, c4 = (lane & 15) * 4;
    int o0 = off[n], o1 = off[n + 1];
    float aldv = ald[(size_t)n * 4 + h];

    float den = 0.f, a0 = 0.f, a1 = 0.f, a2 = 0.f, a3 = 0.f;
    for (int base = o0; base < o1; base += 16) {
        int cnt = o1 - base; if (cnt > 16) cnt = 16;
        int idx = base + (lane & 15);
        int sv = (idx < o1) ? (int)srcs[idx] : 0;
        #pragma unroll
        for (int j = 0; j < 16; ++j) {
            if (j < cnt) {
                int s = __shfl(sv, j);
                float e = als[s * 4 + h] + aldv;
                e = (e > 0.f) ? e : 0.2f * e;
                float pv = __expf(e);
                ushort4 hv = *(const ushort4*)(hs + (size_t)s * G_ + h * 64 + c4);
                den += pv;
                a0 += pv * bf2f(hv.x); a1 += pv * bf2f(hv.y);
                a2 += pv * bf2f(hv.z); a3 += pv * bf2f(hv.w);
            }
        }
    }
    float sc = 0.25f / (den + 1e-16f);
    a0 *= sc; a1 *= sc; a2 *= sc; a3 *= sc;
    a0 += __shfl_xor(a0, 16); a0 += __shfl_xor(a0, 32);
    a1 += __shfl_xor(a1, 16); a1 += __shfl_xor(a1, 32);
    a2 += __shfl_xor(a2, 16); a2 += __shfl_xor(a2, 32);
    a3 += __shfl_xor(a3, 16); a3 += __shfl_xor(a3, 32);
    if (h == 0) {
        u16* op = intra + (((size_t)t * N_ + n) * 2 + r) * 64 + c4;
        ushort4 ov;
        ov.x = f2bf(a0); ov.y = f2bf(a1); ov.z = f2bf(a2); ov.w = f2bf(a3);
        *(ushort4*)op = ov;
    }
}

// ---------------- RelationAgg GEMM with fused tanh(.)@W2 epilogue ----------------
__global__ __launch_bounds__(256) void k_relagg(
    const u16* __restrict__ A, const u16* __restrict__ W1pad, const float* __restrict__ b1,
    const float* __restrict__ W2, float* __restrict__ svals)
{
    int m0 = blockIdx.x * 64;
    f32x4 acc[16];
    gemm_direct<false>(A, W1pad, T_ * N_ * R_, 64, 1, m0, acc);

    const int tid = threadIdx.x, lane = tid & 63, wv = tid >> 6;
    const int col = lane & 15, quad = lane >> 4;
    int rowbase = m0 + wv * 16 + quad * 4;
    float sp[4] = {0.f, 0.f, 0.f, 0.f};
    #pragma unroll
    for (int cf = 0; cf < 16; ++cf) {
        int gcol = cf * 16 + col;
        float bb = b1[gcol];
        float ww = W2[gcol];
        #pragma unroll
        for (int reg = 0; reg < 4; ++reg)
            sp[reg] += tanhf(acc[cf][reg] + bb) * ww;
    }
    #pragma unroll
    for (int reg = 0; reg < 4; ++reg) {
        float v = sp[reg];
        v += __shfl_xor(v, 1); v += __shfl_xor(v, 2);
        v += __shfl_xor(v, 4); v += __shfl_xor(v, 8);
        sp[reg] = v;
    }
    if (col == 0) {
        #pragma unroll
        for (int reg = 0; reg < 4; ++reg) {
            int row = rowbase + reg;
            if (row < T_ * N_ * R_) svals[row] = sp[reg];
        }
    }
}

__global__ void k_betasum(const float* __restrict__ svals, float* __restrict__ ssum) {
    int p = blockIdx.x, t = p >> 1, r = p & 1;
    __shared__ float red[256];
    float s = 0.f;
    for (int n = threadIdx.x; n < N_; n += 256)
        s += svals[((size_t)t * N_ + n) * 2 + r];
    red[threadIdx.x] = s;
    __syncthreads();
    for (int st = 128; st > 0; st >>= 1) {
        if (threadIdx.x < st) red[threadIdx.x] += red[threadIdx.x + st];
        __syncthreads();
    }
    if (threadIdx.x == 0) ssum[p] = red[0];
}

__global__ void k_betafinal(const float* __restrict__ ssum, float* __restrict__ beta) {
    int t = threadIdx.x;
    if (t >= 4) return;
    float s0 = ssum[t * 2] * (1.f / N_), s1 = ssum[t * 2 + 1] * (1.f / N_);
    float mx = fmaxf(s0, s1);
    float e0 = __expf(s0 - mx), e1 = __expf(s1 - mx);
    float inv = 1.f / (e0 + e1);
    beta[t * 2] = e0 * inv; beta[t * 2 + 1] = e1 * inv;
}

// ---------------- LSTM: assemble intra-half of A_step (vectorized x4) ----------------
__global__ void k_assemble(const u16* __restrict__ intra, const float* __restrict__ beta,
                           u16* __restrict__ A_step, int t)
{
    int idx = blockIdx.x * 256 + threadIdx.x;
    if (idx >= N_ * 16) return;
    int n = idx >> 4, q = idx & 15;
    float b0 = beta[t * 2], b1 = beta[t * 2 + 1];
    const u16* ib = intra + ((size_t)t * N_ + n) * 128;
    ushort4 i0 = *(const ushort4*)(ib + q * 4);
    ushort4 i1 = *(const ushort4*)(ib + 64 + q * 4);
    ushort4 ov;
    ov.x = f2bf(b0 * bf2f(i0.x) + b1 * bf2f(i1.x));
    ov.y = f2bf(b0 * bf2f(i0.y) + b1 * bf2f(i1.y));
    ov.z = f2bf(b0 * bf2f(i0.z) + b1 * bf2f(i1.z));
    ov.w = f2bf(b0 * bf2f(i0.w) + b1 * bf2f(i1.w));
    *(ushort4*)(A_step + (size_t)n * 128 + q * 4) = ov;
}

// ---------------- LSTM GEMM + fused cell update ----------------
__global__ __launch_bounds__(256) void k_lstm(
    const u16* __restrict__ A_step_in, const u16* __restrict__ Wc_pad,
    const float* __restrict__ biasv, float* __restrict__ cbuf,
    u16* __restrict__ A_step_h, u16* __restrict__ feats, int t)
{
    int m0 = blockIdx.x * 64;
    f32x4 acc[16];
    gemm_direct<false>(A_step_in, Wc_pad, N_, 128, 2, m0, acc);

    const int tid = threadIdx.x, lane = tid & 63, wv = tid >> 6;
    const int col = lane & 15, quad = lane >> 4;
    int rowbase = m0 + wv * 16 + quad * 4;
    #pragma unroll
    for (int j = 0; j < 4; ++j) {
        int c = j * 16 + col;
        float bi = biasv[c], bf_ = biasv[64 + c], bg = biasv[128 + c], bo = biasv[192 + c];
        #pragma unroll
        for (int reg = 0; reg < 4; ++reg) {
            int row = rowbase + reg;
            if (row < N_) {
                float gi = acc[j][reg] + bi;
                float gf = acc[j + 4][reg] + bf_;
                float gg = acc[j + 8][reg] + bg;
                float go = acc[j + 12][reg] + bo;
                float cc = cbuf[(size_t)row * 64 + c];
                cc = sigm(gf) * cc + sigm(gi) * tanhf(gg);
                float hh = sigm(go) * tanhf(cc);
                cbuf[(size_t)row * 64 + c] = cc;
                A_step_h[(size_t)row * 128 + 64 + c] = f2bf(hh);
                feats[(size_t)row * 256 + t * 64 + c] = f2bf(hh);
            }
        }
    }
}

// ---------------- temporal causal MHA, fully fused, one wave per node ----------------
__global__ __launch_bounds__(256) void k_attn(
    const u16* __restrict__ feats, const float* __restrict__ pos_emb,
    const float* __restrict__ Wq, const float* __restrict__ Wk, const float* __restrict__ Wv,
    float* __restrict__ out)
{
    __shared__ u16 Wl[3 * 4096];
    __shared__ float scr[4][1088];
    int tid = threadIdx.x, lane = tid & 63, wv = tid >> 6;
    for (int i = tid; i < 4096; i += 256) {
        Wl[i] = f2bf(Wq[i]); Wl[4096 + i] = f2bf(Wk[i]); Wl[8192 + i] = f2bf(Wv[i]);
    }
    __syncthreads();
    int n = blockIdx.x * 4 + wv;
    float* ti = scr[wv];
    float* qs = ti + 256; float* ks_ = qs + 256; float* vs = ks_ + 256; float* as_ = vs + 256;

    #pragma unroll
    for (int t = 0; t < 4; ++t)
        ti[t * 64 + lane] = bf2f(feats[(size_t)n * 256 + t * 64 + lane]) + pos_emb[t * 64 + lane];
    __syncthreads();

    float aq[4] = {0,0,0,0}, ak[4] = {0,0,0,0}, av[4] = {0,0,0,0};
    for (int k = 0; k < 64; ++k) {
        float wq = bf2f(Wl[k * 64 + lane]);
        float wk = bf2f(Wl[4096 + k * 64 + lane]);
        float wvv = bf2f(Wl[8192 + k * 64 + lane]);
        #pragma unroll
        for (int t = 0; t < 4; ++t) {
            float tv = ti[t * 64 + k];
            aq[t] += tv * wq; ak[t] += tv * wk; av[t] += tv * wvv;
        }
    }
    #pragma unroll
    for (int t = 0; t < 4; ++t) {
        qs[t * 64 + lane] = aq[t]; ks_[t * 64 + lane] = ak[t]; vs[t * 64 + lane] = av[t];
    }
    __syncthreads();

    {
        int h = lane >> 4, tq = (lane >> 2) & 3, tk = lane & 3;
        float s = 0.f;
        #pragma unroll
        for (int j = 0; j < 16; ++j)
            s += qs[tq * 64 + h * 16 + j] * ks_[tk * 64 + h * 16 + j];
        s *= 0.5f;                       // 1/sqrt(T), T=4
        if (tk > tq) s = -4294967295.0f; // NEG_INF = -2^32+1
        float mx = fmaxf(s, __shfl_xor(s, 1)); mx = fmaxf(mx, __shfl_xor(mx, 2));
        float pv = __expf(s - mx);
        float sm = pv + __shfl_xor(pv, 1); sm += __shfl_xor(sm, 2);
        as_[lane] = pv / sm;
    }
    __syncthreads();

    int h = lane >> 4;
    #pragma unroll
    for (int t = 0; t < 4; ++t) {
        float o = 0.f;
        #pragma unroll
        for (int k2 = 0; k2 < 4; ++k2)
            o += as_[h * 16 + t * 4 + k2] * vs[k2 * 64 + lane];
        out[(size_t)n * 256 + t * 64 + lane] = o;
    }
}

// ---------------- launcher ----------------
extern "C" void kernel_launch(void* const* d_in, const int* in_sizes, int n_in,
                              void* d_out, int out_size, void* d_ws, size_t ws_size,
                              hipStream_t stream) {
    const float* x     = (const float*)d_in[0];
    const int* ei      = (const int*)d_in[1];
    const float* Wsrc  = (const float*)d_in[2];
    const float* Wdst  = (const float*)d_in[3];
    const float* att_src = (const float*)d_in[4];
    const float* att_dst = (const float*)d_in[5];
    const float* raW1  = (const float*)d_in[6];
    const float* rab1  = (const float*)d_in[7];
    const float* raW2  = (const float*)d_in[8];
    const float* Wih   = (const float*)d_in[9];
    const float* Whh   = (const float*)d_in[10];
    const float* bih   = (const float*)d_in[11];
    const float* bhh   = (const float*)d_in[12];
    const float* pos   = (const float*)d_in[13];
    const float* Wq    = (const float*)d_in[14];
    const float* Wk    = (const float*)d_in[15];
    const float* Wv    = (const float*)d_in[16];
    float* out = (float*)d_out;

    char* w = (char*)d_ws;
    size_t off = 0;
    auto alloc = [&](size_t bytes) -> char* {
        char* pp = w + off; off += (bytes + 255) & ~(size_t)255; return pp;
    };
    // ---- long-lived ----
    u16*   intra    = (u16*)  alloc((size_t)T_ * N_ * R_ * 64 * 2);  // 20.48 MB
    float* svals    = (float*)alloc((size_t)T_ * N_ * R_ * 4);       // 0.64 MB
    float* ssum     = (float*)alloc(256);
    float* beta     = (float*)alloc(256);
    float* wd       = (float*)alloc(2 * 64 * 4 * 4);
    float* biasv    = (float*)alloc(256 * 4);
    u16*   Wsrc_pad = (u16*)  alloc(2 * BPAD * 2);
    u16*   raW1_pad = (u16*)  alloc(BPAD * 2);
    u16*   Wc_pad   = (u16*)  alloc(2 * BPAD * 2);
    // ---- union region ----
    char*  ubase   = alloc(0);
    size_t uoff = 0;
    auto ualloc = [&](size_t bytes) -> char* {
        char* pp = ubase + uoff; uoff += (bytes + 255) & ~(size_t)255; return pp;
    };
    int*   counts  = (int*)  ualloc((size_t)P_ * N_ * 4);           // 0.64 MB
    int*   offsets = (int*)  ualloc((size_t)P_ * (N_ + 1) * 4);     // 0.64 MB
    u16*   csr     = (u16*)  ualloc((size_t)P_ * E_ * 2);           // 5.12 MB
    float* als_all = (float*)ualloc((size_t)P_ * N_ * 4 * 4);       // 2.56 MB
    float* ald_all = (float*)ualloc((size_t)P_ * N_ * 4 * 4);       // 2.56 MB
    u16*   hs_p    = (u16*)  ualloc((size_t)N_ * G_ * 2);           // 10.24 MB
    // rank overlays hs_p (rank is dead before the first k_proj writes hs_p)
    u16*   rank    = (u16*)  hs_p;                                   // 5.12 MB
    // phase 2 (overlays phase-1 sub-buffers dead after the k_agg loop)
    float* cbuf    = (float*)(ubase);                                // 5.12 MB
    u16*   A_step  = (u16*)  (ubase + 5300000);                      // 5.12 MB
    u16*   feats   = (u16*)  (ubase + 10600000);                     // 10.24 MB
    (void)ws_size; (void)in_sizes; (void)n_in; (void)out_size;

    hipMemsetAsync(counts, 0, (size_t)P_ * N_ * 4, stream);
    k_prep<<<72, 256, 0, stream>>>(Wdst, att_dst, Wih, Whh, bih, bhh, Wsrc, raW1,
                                   wd, biasv, Wsrc_pad, raW1_pad, Wc_pad);
    k_hist<<<dim3(1250, 8), 256, 0, stream>>>(ei, counts, rank);
    k_scan<<<8, 1024, 0, stream>>>(counts, offsets);
    k_scatter<<<dim3(1250, 8), 256, 0, stream>>>(ei, offsets, rank, csr);
    k_ald<<<dim3(313, 8), 256, 0, stream>>>(x, wd, ald_all);
    for (int p = 0; p < P_; ++p) {
        int t = p >> 1, r = p & 1;
        k_proj<<<313, 256, 0, stream>>>(x + (size_t)t * N_ * DIN, Wsrc_pad + (size_t)r * BPAD,
                                        att_src + r * G_, hs_p, als_all + (size_t)p * N_ * 4);
        k_agg<<<5000, 256, 0, stream>>>(offsets + (size_t)p * (N_ + 1), csr + (size_t)p * E_,
                                        als_all + (size_t)p * N_ * 4, ald_all + (size_t)p * N_ * 4,
                                        hs_p, intra, t, r);
    }
    k_relagg<<<2500, 256, 0, stream>>>(intra, raW1_pad, rab1, raW2, svals);
    k_betasum<<<8, 256, 0, stream>>>(svals, ssum);
    k_betafinal<<<1, 64, 0, stream>>>(ssum, beta);
    hipMemsetAsync(cbuf, 0, (size_t)N_ * 64 * 4, stream);
    hipMemsetAsync(A_step, 0, (size_t)N_ * 128 * 2, stream);
    for (int t = 0; t < T_; ++t) {
        k_assemble<<<1250, 256, 0, stream>>>(intra, beta, A_step, t);
        k_lstm<<<313, 256, 0, stream>>>(A_step, Wc_pad, biasv, cbuf, A_step, feats, t);
    }
    k_attn<<<5000, 256, 0, stream>>>(feats, pos, Wq, Wk, Wv, out);
}

// Round 5
// 837.549 us; speedup vs baseline: 1.4445x; 1.0147x over previous
//
#include <hip/hip_runtime.h>
#include <hip/hip_bf16.h>

#define T_ 4
#define N_ 20000
#define E_ 320000
#define R_ 2
#define DIN 64
#define G_ 256   // H*Dh
#define P_ 8     // T*R
#define BPAD 18432  // 256 * 72 padded B-table halves per 64-k chunk
#define NB_ 32      // CSR-build blocks per p
#define EPB_ 10000  // edges per CSR-build block

typedef unsigned short u16;
typedef __attribute__((ext_vector_type(8))) short bf16x8;
typedef __attribute__((ext_vector_type(4))) float f32x4;

__device__ __forceinline__ float bf2f(u16 u) {
    unsigned int i = ((unsigned int)u) << 16; float f;
    __builtin_memcpy(&f, &i, 4); return f;
}
__device__ __forceinline__ u16 f2bf(float f) {
    unsigned int i; __builtin_memcpy(&i, &f, 4);
    unsigned int r = i + 0x7fffu + ((i >> 16) & 1u);
    return (u16)(r >> 16);
}
__device__ __forceinline__ float sigm(float x) { return 1.f / (1.f + __expf(-x)); }

__device__ __forceinline__ bf16x8 load_a_f32(const float* p) {
    float4 f0 = *(const float4*)p;
    float4 f1 = *(const float4*)(p + 4);
    union { u16 h[8]; bf16x8 v; } u;
    u.h[0] = f2bf(f0.x); u.h[1] = f2bf(f0.y); u.h[2] = f2bf(f0.z); u.h[3] = f2bf(f0.w);
    u.h[4] = f2bf(f1.x); u.h[5] = f2bf(f1.y); u.h[6] = f2bf(f1.z); u.h[7] = f2bf(f1.w);
    return u.v;
}

// ---------------- LDS-free MFMA GEMM core ----------------
// C[m0+wv*16+row16, 0:256] = A[., 0:K] @ B[0:K, 0:256], K = kchunks*64.
// A read directly (wave-private rows); B from pre-padded table [n*72+kk] per chunk.
// C/D layout: col = lane&15, row = (lane>>4)*4 + reg.
template <bool AF32>
__device__ __forceinline__ void gemm_direct(
    const void* __restrict__ Av, const u16* __restrict__ Bpad,
    int M, int Astride, int kchunks, int m0, f32x4* acc)
{
    const int tid = threadIdx.x;
    const int lane = tid & 63, wv = tid >> 6;
    const int col = lane & 15, quad = lane >> 4;
    #pragma unroll
    for (int cf = 0; cf < 16; ++cf) { acc[cf][0]=0.f; acc[cf][1]=0.f; acc[cf][2]=0.f; acc[cf][3]=0.f; }

    int row = m0 + wv * 16 + col;
    int row_c = (row < M) ? row : (M - 1);

    for (int kc = 0; kc < kchunks; ++kc) {
        #pragma unroll
        for (int ks = 0; ks < 2; ++ks) {
            bf16x8 a;
            if (AF32) {
                const float* A = (const float*)Av + (size_t)row_c * Astride + kc * 64 + ks * 32 + quad * 8;
                a = load_a_f32(A);
            } else {
                a = *(const bf16x8*)((const u16*)Av + (size_t)row_c * Astride + kc * 64 + ks * 32 + quad * 8);
            }
            const u16* bb = Bpad + kc * BPAD + ks * 32 + quad * 8;
            #pragma unroll
            for (int cf = 0; cf < 16; ++cf) {
                bf16x8 b = *(const bf16x8*)(bb + (cf * 16 + col) * 72);
                acc[cf] = __builtin_amdgcn_mfma_f32_16x16x32_bf16(a, b, acc[cf], 0, 0, 0);
            }
        }
    }
}

// ---------------- GAT projection (per (t,r) slice) + als epilogue ----------------
__global__ __launch_bounds__(256) void k_proj(
    const float* __restrict__ x_t, const u16* __restrict__ Bpad, const float* __restrict__ att_src_r,
    u16* __restrict__ hs, float* __restrict__ als_p)
{
    int m0 = blockIdx.x * 64;
    f32x4 acc[16];
    gemm_direct<true>(x_t, Bpad, N_, DIN, 1, m0, acc);

    const int tid = threadIdx.x, lane = tid & 63, wv = tid >> 6;
    const int col = lane & 15, quad = lane >> 4;
    int rowbase = m0 + wv * 16 + quad * 4;

    float ap[4][4]; // [h][reg]
    #pragma unroll
    for (int h = 0; h < 4; ++h)
        #pragma unroll
        for (int reg = 0; reg < 4; ++reg) ap[h][reg] = 0.f;

    #pragma unroll
    for (int cf = 0; cf < 16; ++cf) {
        int gcol = cf * 16 + col;
        float av = att_src_r[gcol];
        int h = cf >> 2;
        #pragma unroll
        for (int reg = 0; reg < 4; ++reg) {
            float v = acc[cf][reg];
            int row = rowbase + reg;
            if (row < N_) hs[(size_t)row * G_ + gcol] = f2bf(v);
            ap[h][reg] += v * av;
        }
    }
    #pragma unroll
    for (int h = 0; h < 4; ++h)
        #pragma unroll
        for (int reg = 0; reg < 4; ++reg) {
            float v = ap[h][reg];
            v += __shfl_xor(v, 1); v += __shfl_xor(v, 2);
            v += __shfl_xor(v, 4); v += __shfl_xor(v, 8);
            ap[h][reg] = v;
        }
    if (col == 0) {
        #pragma unroll
        for (int reg = 0; reg < 4; ++reg) {
            int row = rowbase + reg;
            if (row < N_) {
                #pragma unroll
                for (int h = 0; h < 4; ++h)
                    als_p[(size_t)row * 4 + h] = ap[h][reg];
            }
        }
    }
}

// ---------------- ald via folded GEMV: 4 lanes cooperate per node ----------------
__global__ __launch_bounds__(256) void k_ald(
    const float* __restrict__ x, const float* __restrict__ wd, float* __restrict__ ald_all)
{
    int p = blockIdx.y, t = p >> 1, r = p & 1;
    int idx = blockIdx.x * 256 + threadIdx.x;
    if (idx >= N_ * 4) return;
    int n = idx >> 2, q = idx & 3;
    const float4* xr = (const float4*)(x + ((size_t)t * N_ + n) * 64 + q * 16);
    const float* wp = wd + r * 256 + q * 64;   // wd[(r*64+k)*4+h], k = q*16+kk
    float s0 = 0.f, s1 = 0.f, s2 = 0.f, s3 = 0.f;
    #pragma unroll
    for (int kk4 = 0; kk4 < 4; ++kk4) {
        float4 xv = xr[kk4];
        const float* w4 = wp + kk4 * 16;
        s0 += xv.x * w4[0]  + xv.y * w4[4]  + xv.z * w4[8]  + xv.w * w4[12];
        s1 += xv.x * w4[1]  + xv.y * w4[5]  + xv.z * w4[9]  + xv.w * w4[13];
        s2 += xv.x * w4[2]  + xv.y * w4[6]  + xv.z * w4[10] + xv.w * w4[14];
        s3 += xv.x * w4[3]  + xv.y * w4[7]  + xv.z * w4[11] + xv.w * w4[15];
    }
    s0 += __shfl_xor(s0, 1); s0 += __shfl_xor(s0, 2);
    s1 += __shfl_xor(s1, 1); s1 += __shfl_xor(s1, 2);
    s2 += __shfl_xor(s2, 1); s2 += __shfl_xor(s2, 2);
    s3 += __shfl_xor(s3, 1); s3 += __shfl_xor(s3, 2);
    if (q == 0)
        *(float4*)(ald_all + ((size_t)p * N_ + n) * 4) = make_float4(s0, s1, s2, s3);
}

// ---------------- prep: wd, padded B-tables (bf16), folded bias ----------------
__global__ void k_prep(const float* __restrict__ Wdst, const float* __restrict__ att_dst,
                       const float* __restrict__ Wih, const float* __restrict__ Whh,
                       const float* __restrict__ bih, const float* __restrict__ bhh,
                       const float* __restrict__ Wsrc, const float* __restrict__ raW1,
                       float* __restrict__ wd, float* __restrict__ biasv,
                       u16* __restrict__ Wsrc_pad, u16* __restrict__ raW1_pad,
                       u16* __restrict__ Wc_pad)
{
    int tid = threadIdx.x, bid = blockIdx.x;
    if (bid == 0) {
        for (int r = 0; r < 2; ++r) {
            int k = tid >> 2, h = tid & 3;
            float s = 0.f;
            for (int c = 0; c < 64; ++c)
                s += Wdst[((size_t)r * 64 + k) * 256 + h * 64 + c] * att_dst[r * 256 + h * 64 + c];
            wd[(r * 64 + k) * 4 + h] = s;
        }
        biasv[tid] = bih[tid] + bhh[tid];
    }
    // Wsrc_pad[r][n*72+kk] = Wsrc[r,kk,n]; raW1_pad[n*72+kk] = raW1[kk,n]
    for (int i = bid * 256 + tid; i < 3 * BPAD; i += gridDim.x * 256) {
        int r = i / BPAD, q = i % BPAD, n = q / 72, kk = q % 72;
        if (r < 2)
            Wsrc_pad[i] = (kk < 64) ? f2bf(Wsrc[(size_t)r * 64 * 256 + kk * 256 + n]) : (u16)0;
        else
            raW1_pad[q] = (kk < 64) ? f2bf(raW1[kk * 256 + n]) : (u16)0;
    }
    // Wc_pad[kc][n*72+kk] = (kc==0 ? Wih : Whh)[n,kk]
    for (int i = bid * 256 + tid; i < 2 * BPAD; i += gridDim.x * 256) {
        int kc = i / BPAD, q = i % BPAD, n = q / 72, kk = q % 72;
        const float* W = kc ? Whh : Wih;
        Wc_pad[i] = (kk < 64) ? f2bf(W[n * 64 + kk]) : (u16)0;
    }
}

// ---------------- CSR build: block-local LDS histogram (no global atomics) ----------------
__global__ __launch_bounds__(256) void k_hist(const int* __restrict__ ei,
                                              u16* __restrict__ rank, u16* __restrict__ partial)
{
    __shared__ unsigned int hist[N_ / 2];   // packed 2 x u16, 40 KB
    int b = blockIdx.x, p = blockIdx.y, tid = threadIdx.x;
    for (int i = tid; i < N_ / 2; i += 256) hist[i] = 0u;
    __syncthreads();
    const int* dsts = ei + ((size_t)p * 2 + 1) * E_ + b * EPB_;
    u16* rk = rank + (size_t)p * E_ + b * EPB_;
    for (int e = tid; e < EPB_; e += 256) {
        int dst = dsts[e];
        unsigned sh = (unsigned)(dst & 1) * 16u;
        unsigned old = atomicAdd(&hist[dst >> 1], 1u << sh);
        rk[e] = (u16)((old >> sh) & 0xffffu);
    }
    __syncthreads();
    u16* part = partial + ((size_t)p * NB_ + b) * N_;
    for (int n = tid; n < N_; n += 256) {
        unsigned hv = hist[n >> 1];
        part[n] = (u16)((hv >> ((unsigned)(n & 1) * 16u)) & 0xffffu);
    }
}

// ---------------- scan: in-place block-prefix of partials + node-level offsets ----------------
__global__ __launch_bounds__(1024) void k_scan(u16* __restrict__ partial, int* __restrict__ offsets)
{
    int p = blockIdx.x;
    __shared__ int wtot[16];
    int tid = threadIdx.x, lane = tid & 63, wid = tid >> 6;
    int carry = 0;
    u16* part = partial + (size_t)p * NB_ * N_;
    int* ofs = offsets + (size_t)p * (N_ + 1);
    for (int base = 0; base < N_; base += 1024) {
        int i = base + tid;
        int v = 0;
        if (i < N_) {
            int run = 0;
            #pragma unroll 4
            for (int b = 0; b < NB_; ++b) {
                int pv = part[b * N_ + i];
                part[b * N_ + i] = (u16)run;
                run += pv;
            }
            v = run;
        }
        int incl = v;
        for (int d = 1; d < 64; d <<= 1) { int u = __shfl_up(incl, d); if (lane >= d) incl += u; }
        if (lane == 63) wtot[wid] = incl;
        __syncthreads();
        if (tid < 16) {
            int iv = wtot[tid];
            for (int d = 1; d < 16; d <<= 1) { int u = __shfl_up(iv, d); if (tid >= d) iv += u; }
            wtot[tid] = iv;
        }
        __syncthreads();
        int woff = (wid > 0) ? wtot[wid - 1] : 0;
        int tot = wtot[15];
        int excl = carry + woff + incl - v;
        if (i < N_) ofs[i] = excl;
        carry += tot;
        __syncthreads();
    }
    if (tid == 0) ofs[N_] = carry;
}

__global__ void k_scatter(const int* __restrict__ ei, const int* __restrict__ offsets,
                          const u16* __restrict__ rank, const u16* __restrict__ partial,
                          u16* __restrict__ csr) {
    int p = blockIdx.y;
    int e = blockIdx.x * 256 + threadIdx.x;
    if (e >= E_) return;
    int src = ei[((size_t)p * 2 + 0) * E_ + e];
    int dst = ei[((size_t)p * 2 + 1) * E_ + e];
    int b = e / EPB_;
    int pos = offsets[p * (N_ + 1) + dst]
            + (int)partial[((size_t)p * NB_ + b) * N_ + dst]
            + (int)rank[(size_t)p * E_ + e];
    csr[(size_t)p * E_ + pos] = (u16)src;
}

// ---------------- GAT softmax-aggregation: one wave per dst node, single pass ----------------
__global__ __launch_bounds__(256) void k_agg(
    const int* __restrict__ off, const u16* __restrict__ srcs,
    const float* __restrict__ als, const float* __restrict__ ald,
    const u16* __restrict__ hs, u16* __restrict__ intra, int t, int r)
{
    int tid = threadIdx.x, lane = tid & 63, wv = tid >> 6;
    int n = blockIdx.x * 4 + wv;
    int h = lane >> 4, c4 = (lane & 15) * 4;
    int o0 = off[n], o1 = off[n + 1];
    float aldv = ald[(size_t)n * 4 + h];

    float den = 0.f, a0 = 0.f, a1 = 0.f, a2 = 0.f, a3 = 0.f;
    for (int base = o0; base < o1; base += 16) {
        int cnt = o1 - base; if (cnt > 16) cnt = 16;
        int idx = base + (lane & 15);
        int sv = (idx < o1) ? (int)srcs[idx] : 0;
        #pragma unroll
        for (int j = 0; j < 16; ++j) {
            if (j < cnt) {
                int s = __shfl(sv, j);
                float e = als[s * 4 + h] + aldv;
                e = (e > 0.f) ? e : 0.2f * e;
                float pv = __expf(e);
                ushort4 hv = *(const ushort4*)(hs + (size_t)s * G_ + h * 64 + c4);
                den += pv;
                a0 += pv * bf2f(hv.x); a1 += pv * bf2f(hv.y);
                a2 += pv * bf2f(hv.z); a3 += pv * bf2f(hv.w);
            }
        }
    }
    float sc = 0.25f / (den + 1e-16f);
    a0 *= sc; a1 *= sc; a2 *= sc; a3 *= sc;
    a0 += __shfl_xor(a0, 16); a0 += __shfl_xor(a0, 32);
    a1 += __shfl_xor(a1, 16); a1 += __shfl_xor(a1, 32);
    a2 += __shfl_xor(a2, 16); a2 += __shfl_xor(a2, 32);
    a3 += __shfl_xor(a3, 16); a3 += __shfl_xor(a3, 32);
    if (h == 0) {
        u16* op = intra + (((size_t)t * N_ + n) * 2 + r) * 64 + c4;
        ushort4 ov;
        ov.x = f2bf(a0); ov.y = f2bf(a1); ov.z = f2bf(a2); ov.w = f2bf(a3);
        *(ushort4*)op = ov;
    }
}

// ---------------- RelationAgg GEMM with fused tanh(.)@W2 epilogue ----------------
__global__ __launch_bounds__(256) void k_relagg(
    const u16* __restrict__ A, const u16* __restrict__ W1pad, const float* __restrict__ b1,
    const float* __restrict__ W2, float* __restrict__ svals)
{
    int m0 = blockIdx.x * 64;
    f32x4 acc[16];
    gemm_direct<false>(A, W1pad, T_ * N_ * R_, 64, 1, m0, acc);

    const int tid = threadIdx.x, lane = tid & 63, wv = tid >> 6;
    const int col = lane & 15, quad = lane >> 4;
    int rowbase = m0 + wv * 16 + quad * 4;
    float sp[4] = {0.f, 0.f, 0.f, 0.f};
    #pragma unroll
    for (int cf = 0; cf < 16; ++cf) {
        int gcol = cf * 16 + col;
        float bb = b1[gcol];
        float ww = W2[gcol];
        #pragma unroll
        for (int reg = 0; reg < 4; ++reg)
            sp[reg] += tanhf(acc[cf][reg] + bb) * ww;
    }
    #pragma unroll
    for (int reg = 0; reg < 4; ++reg) {
        float v = sp[reg];
        v += __shfl_xor(v, 1); v += __shfl_xor(v, 2);
        v += __shfl_xor(v, 4); v += __shfl_xor(v, 8);
        sp[reg] = v;
    }
    if (col == 0) {
        #pragma unroll
        for (int reg = 0; reg < 4; ++reg) {
            int row = rowbase + reg;
            if (row < T_ * N_ * R_) svals[row] = sp[reg];
        }
    }
}

__global__ void k_betasum(const float* __restrict__ svals, float* __restrict__ ssum) {
    int p = blockIdx.x, t = p >> 1, r = p & 1;
    __shared__ float red[256];
    float s = 0.f;
    for (int n = threadIdx.x; n < N_; n += 256)
        s += svals[((size_t)t * N_ + n) * 2 + r];
    red[threadIdx.x] = s;
    __syncthreads();
    for (int st = 128; st > 0; st >>= 1) {
        if (threadIdx.x < st) red[threadIdx.x] += red[threadIdx.x + st];
        __syncthreads();
    }
    if (threadIdx.x == 0) ssum[p] = red[0];
}

__global__ void k_betafinal(const float* __restrict__ ssum, float* __restrict__ beta) {
    int t = threadIdx.x;
    if (t >= 4) return;
    float s0 = ssum[t * 2] * (1.f / N_), s1 = ssum[t * 2 + 1] * (1.f / N_);
    float mx = fmaxf(s0, s1);
    float e0 = __expf(s0 - mx), e1 = __expf(s1 - mx);
    float inv = 1.f / (e0 + e1);
    beta[t * 2] = e0 * inv; beta[t * 2 + 1] = e1 * inv;
}

// ---------------- LSTM: assemble intra-half of A_step (vectorized x4) ----------------
__global__ void k_assemble(const u16* __restrict__ intra, const float* __restrict__ beta,
                           u16* __restrict__ A_step, int t)
{
    int idx = blockIdx.x * 256 + threadIdx.x;
    if (idx >= N_ * 16) return;
    int n = idx >> 4, q = idx & 15;
    float b0 = beta[t * 2], b1 = beta[t * 2 + 1];
    const u16* ib = intra + ((size_t)t * N_ + n) * 128;
    ushort4 i0 = *(const ushort4*)(ib + q * 4);
    ushort4 i1 = *(const ushort4*)(ib + 64 + q * 4);
    ushort4 ov;
    ov.x = f2bf(b0 * bf2f(i0.x) + b1 * bf2f(i1.x));
    ov.y = f2bf(b0 * bf2f(i0.y) + b1 * bf2f(i1.y));
    ov.z = f2bf(b0 * bf2f(i0.z) + b1 * bf2f(i1.z));
    ov.w = f2bf(b0 * bf2f(i0.w) + b1 * bf2f(i1.w));
    *(ushort4*)(A_step + (size_t)n * 128 + q * 4) = ov;
}

// ---------------- LSTM GEMM + fused cell update ----------------
__global__ __launch_bounds__(256) void k_lstm(
    const u16* __restrict__ A_step_in, const u16* __restrict__ Wc_pad,
    const float* __restrict__ biasv, float* __restrict__ cbuf,
    u16* __restrict__ A_step_h, u16* __restrict__ feats, int t)
{
    int m0 = blockIdx.x * 64;
    f32x4 acc[16];
    gemm_direct<false>(A_step_in, Wc_pad, N_, 128, 2, m0, acc);

    const int tid = threadIdx.x, lane = tid & 63, wv = tid >> 6;
    const int col = lane & 15, quad = lane >> 4;
    int rowbase = m0 + wv * 16 + quad * 4;
    #pragma unroll
    for (int j = 0; j < 4; ++j) {
        int c = j * 16 + col;
        float bi = biasv[c], bf_ = biasv[64 + c], bg = biasv[128 + c], bo = biasv[192 + c];
        #pragma unroll
        for (int reg = 0; reg < 4; ++reg) {
            int row = rowbase + reg;
            if (row < N_) {
                float gi = acc[j][reg] + bi;
                float gf = acc[j + 4][reg] + bf_;
                float gg = acc[j + 8][reg] + bg;
                float go = acc[j + 12][reg] + bo;
                float cc = cbuf[(size_t)row * 64 + c];
                cc = sigm(gf) * cc + sigm(gi) * tanhf(gg);
                float hh = sigm(go) * tanhf(cc);
                cbuf[(size_t)row * 64 + c] = cc;
                A_step_h[(size_t)row * 128 + 64 + c] = f2bf(hh);
                feats[(size_t)row * 256 + t * 64 + c] = f2bf(hh);
            }
        }
    }
}

// ---------------- temporal causal MHA, fully fused, one wave per node ----------------
__global__ __launch_bounds__(256) void k_attn(
    const u16* __restrict__ feats, const float* __restrict__ pos_emb,
    const float* __restrict__ Wq, const float* __restrict__ Wk, const float* __restrict__ Wv,
    float* __restrict__ out)
{
    __shared__ u16 Wl[3 * 4096];
    __shared__ float scr[4][1088];
    int tid = threadIdx.x, lane = tid & 63, wv = tid >> 6;
    for (int i = tid; i < 4096; i += 256) {
        Wl[i] = f2bf(Wq[i]); Wl[4096 + i] = f2bf(Wk[i]); Wl[8192 + i] = f2bf(Wv[i]);
    }
    __syncthreads();
    int n = blockIdx.x * 4 + wv;
    float* ti = scr[wv];
    float* qs = ti + 256; float* ks_ = qs + 256; float* vs = ks_ + 256; float* as_ = vs + 256;

    #pragma unroll
    for (int t = 0; t < 4; ++t)
        ti[t * 64 + lane] = bf2f(feats[(size_t)n * 256 + t * 64 + lane]) + pos_emb[t * 64 + lane];
    __syncthreads();

    float aq[4] = {0,0,0,0}, ak[4] = {0,0,0,0}, av[4] = {0,0,0,0};
    for (int k = 0; k < 64; ++k) {
        float wq = bf2f(Wl[k * 64 + lane]);
        float wk = bf2f(Wl[4096 + k * 64 + lane]);
        float wvv = bf2f(Wl[8192 + k * 64 + lane]);
        #pragma unroll
        for (int t = 0; t < 4; ++t) {
            float tv = ti[t * 64 + k];
            aq[t] += tv * wq; ak[t] += tv * wk; av[t] += tv * wvv;
        }
    }
    #pragma unroll
    for (int t = 0; t < 4; ++t) {
        qs[t * 64 + lane] = aq[t]; ks_[t * 64 + lane] = ak[t]; vs[t * 64 + lane] = av[t];
    }
    __syncthreads();

    {
        int h = lane >> 4, tq = (lane >> 2) & 3, tk = lane & 3;
        float s = 0.f;
        #pragma unroll
        for (int j = 0; j < 16; ++j)
            s += qs[tq * 64 + h * 16 + j] * ks_[tk * 64 + h * 16 + j];
        s *= 0.5f;                       // 1/sqrt(T), T=4
        if (tk > tq) s = -4294967295.0f; // NEG_INF = -2^32+1
        float mx = fmaxf(s, __shfl_xor(s, 1)); mx = fmaxf(mx, __shfl_xor(mx, 2));
        float pv = __expf(s - mx);
        float sm = pv + __shfl_xor(pv, 1); sm += __shfl_xor(sm, 2);
        as_[lane] = pv / sm;
    }
    __syncthreads();

    int h = lane >> 4;
    #pragma unroll
    for (int t = 0; t < 4; ++t) {
        float o = 0.f;
        #pragma unroll
        for (int k2 = 0; k2 < 4; ++k2)
            o += as_[h * 16 + t * 4 + k2] * vs[k2 * 64 + lane];
        out[(size_t)n * 256 + t * 64 + lane] = o;
    }
}

// ---------------- launcher ----------------
extern "C" void kernel_launch(void* const* d_in, const int* in_sizes, int n_in,
                              void* d_out, int out_size, void* d_ws, size_t ws_size,
                              hipStream_t stream) {
    const float* x     = (const float*)d_in[0];
    const int* ei      = (const int*)d_in[1];
    const float* Wsrc  = (const float*)d_in[2];
    const float* Wdst  = (const float*)d_in[3];
    const float* att_src = (const float*)d_in[4];
    const float* att_dst = (const float*)d_in[5];
    const float* raW1  = (const float*)d_in[6];
    const float* rab1  = (const float*)d_in[7];
    const float* raW2  = (const float*)d_in[8];
    const float* Wih   = (const float*)d_in[9];
    const float* Whh   = (const float*)d_in[10];
    const float* bih   = (const float*)d_in[11];
    const float* bhh   = (const float*)d_in[12];
    const float* pos   = (const float*)d_in[13];
    const float* Wq    = (const float*)d_in[14];
    const float* Wk    = (const float*)d_in[15];
    const float* Wv    = (const float*)d_in[16];
    float* out = (float*)d_out;

    char* w = (char*)d_ws;
    size_t off = 0;
    auto alloc = [&](size_t bytes) -> char* {
        char* pp = w + off; off += (bytes + 255) & ~(size_t)255; return pp;
    };
    // ---- long-lived ----
    u16*   intra    = (u16*)  alloc((size_t)T_ * N_ * R_ * 64 * 2);  // 20.48 MB
    float* svals    = (float*)alloc((size_t)T_ * N_ * R_ * 4);       // 0.64 MB
    float* ssum     = (float*)alloc(256);
    float* beta     = (float*)alloc(256);
    float* wd       = (float*)alloc(2 * 64 * 4 * 4);
    float* biasv    = (float*)alloc(256 * 4);
    u16*   Wsrc_pad = (u16*)  alloc(2 * BPAD * 2);
    u16*   raW1_pad = (u16*)  alloc(BPAD * 2);
    u16*   Wc_pad   = (u16*)  alloc(2 * BPAD * 2);
    // ---- union region ----
    char*  ubase   = alloc(0);
    size_t uoff = 0;
    auto ualloc = [&](size_t bytes) -> char* {
        char* pp = ubase + uoff; uoff += (bytes + 255) & ~(size_t)255; return pp;
    };
    int*   offsets = (int*)  ualloc((size_t)P_ * (N_ + 1) * 4);     // 0.64 MB
    u16*   csr     = (u16*)  ualloc((size_t)P_ * E_ * 2);           // 5.12 MB
    float* als_all = (float*)ualloc((size_t)P_ * N_ * 4 * 4);       // 2.56 MB
    float* ald_all = (float*)ualloc((size_t)P_ * N_ * 4 * 4);       // 2.56 MB
    u16*   hs_p    = (u16*)  ualloc((size_t)N_ * G_ * 2);           // 10.24 MB
    u16*   partial = (u16*)  ualloc((size_t)P_ * NB_ * N_ * 2);     // 10.24 MB
    // rank overlays hs_p (rank dead after k_scatter, before first k_proj)
    u16*   rank    = (u16*)  hs_p;                                   // 5.12 MB
    // phase 2 (overlays phase-1 sub-buffers dead after the k_agg loop)
    float* cbuf    = (float*)(ubase);                                // 5.12 MB
    u16*   A_step  = (u16*)  (ubase + 5300000);                      // 5.12 MB
    u16*   feats   = (u16*)  (ubase + 10600000);                     // 10.24 MB
    (void)ws_size; (void)in_sizes; (void)n_in; (void)out_size;

    k_prep<<<72, 256, 0, stream>>>(Wdst, att_dst, Wih, Whh, bih, bhh, Wsrc, raW1,
                                   wd, biasv, Wsrc_pad, raW1_pad, Wc_pad);
    k_hist<<<dim3(NB_, 8), 256, 0, stream>>>(ei, rank, partial);
    k_scan<<<8, 1024, 0, stream>>>(partial, offsets);
    k_scatter<<<dim3(1250, 8), 256, 0, stream>>>(ei, offsets, rank, partial, csr);
    k_ald<<<dim3(313, 8), 256, 0, stream>>>(x, wd, ald_all);
    for (int p = 0; p < P_; ++p) {
        int t = p >> 1, r = p & 1;
        k_proj<<<313, 256, 0, stream>>>(x + (size_t)t * N_ * DIN, Wsrc_pad + (size_t)r * BPAD,
                                        att_src + r * G_, hs_p, als_all + (size_t)p * N_ * 4);
        k_agg<<<5000, 256, 0, stream>>>(offsets + (size_t)p * (N_ + 1), csr + (size_t)p * E_,
                                        als_all + (size_t)p * N_ * 4, ald_all + (size_t)p * N_ * 4,
                                        hs_p, intra, t, r);
    }
    k_relagg<<<2500, 256, 0, stream>>>(intra, raW1_pad, rab1, raW2, svals);
    k_betasum<<<8, 256, 0, stream>>>(svals, ssum);
    k_betafinal<<<1, 64, 0, stream>>>(ssum, beta);
    hipMemsetAsync(cbuf, 0, (size_t)N_ * 64 * 4, stream);
    hipMemsetAsync(A_step, 0, (size_t)N_ * 128 * 2, stream);
    for (int t = 0; t < T_; ++t) {
        k_assemble<<<1250, 256, 0, stream>>>(intra, beta, A_step, t);
        k_lstm<<<313, 256, 0, stream>>>(A_step, Wc_pad, biasv, cbuf, A_step, feats, t);
    }
    k_attn<<<5000, 256, 0, stream>>>(feats, pos, Wq, Wk, Wv, out);
}

// Round 6
// 675.514 us; speedup vs baseline: 1.7910x; 1.2399x over previous
//
#include <hip/hip_runtime.h>
#include <hip/hip_bf16.h>

#define T_ 4
#define N_ 20000
#define E_ 320000
#define R_ 2
#define DIN 64
#define G_ 256   // H*Dh
#define P_ 8     // T*R
#define BPAD 18432  // 256 * 72 padded B-table halves per 64-k chunk
#define NB_ 32      // CSR-build blocks per p
#define EPB_ 10000  // edges per CSR-build block
#define CHN_ 625    // nodes per scan chunk (N_/32)

typedef unsigned short u16;
typedef __attribute__((ext_vector_type(8))) short bf16x8;
typedef __attribute__((ext_vector_type(4))) float f32x4;

__device__ __forceinline__ float bf2f(u16 u) {
    unsigned int i = ((unsigned int)u) << 16; float f;
    __builtin_memcpy(&f, &i, 4); return f;
}
__device__ __forceinline__ u16 f2bf(float f) {
    unsigned int i; __builtin_memcpy(&i, &f, 4);
    unsigned int r = i + 0x7fffu + ((i >> 16) & 1u);
    return (u16)(r >> 16);
}
__device__ __forceinline__ float sigm(float x) { return 1.f / (1.f + __expf(-x)); }

__device__ __forceinline__ bf16x8 load_a_f32(const float* p) {
    float4 f0 = *(const float4*)p;
    float4 f1 = *(const float4*)(p + 4);
    union { u16 h[8]; bf16x8 v; } u;
    u.h[0] = f2bf(f0.x); u.h[1] = f2bf(f0.y); u.h[2] = f2bf(f0.z); u.h[3] = f2bf(f0.w);
    u.h[4] = f2bf(f1.x); u.h[5] = f2bf(f1.y); u.h[6] = f2bf(f1.z); u.h[7] = f2bf(f1.w);
    return u.v;
}

// ---------------- LDS-free MFMA GEMM core ----------------
// C[m0+wv*16+row16, 0:256] = A[., 0:K] @ B[0:K, 0:256], K = kchunks*64.
// A read directly (wave-private rows); B from pre-padded table [n*72+kk] per chunk.
// C/D layout: col = lane&15, row = (lane>>4)*4 + reg.
template <bool AF32>
__device__ __forceinline__ void gemm_direct(
    const void* __restrict__ Av, const u16* __restrict__ Bpad,
    int M, int Astride, int kchunks, int m0, f32x4* acc)
{
    const int tid = threadIdx.x;
    const int lane = tid & 63, wv = tid >> 6;
    const int col = lane & 15, quad = lane >> 4;
    #pragma unroll
    for (int cf = 0; cf < 16; ++cf) { acc[cf][0]=0.f; acc[cf][1]=0.f; acc[cf][2]=0.f; acc[cf][3]=0.f; }

    int row = m0 + wv * 16 + col;
    int row_c = (row < M) ? row : (M - 1);

    for (int kc = 0; kc < kchunks; ++kc) {
        #pragma unroll
        for (int ks = 0; ks < 2; ++ks) {
            bf16x8 a;
            if (AF32) {
                const float* A = (const float*)Av + (size_t)row_c * Astride + kc * 64 + ks * 32 + quad * 8;
                a = load_a_f32(A);
            } else {
                a = *(const bf16x8*)((const u16*)Av + (size_t)row_c * Astride + kc * 64 + ks * 32 + quad * 8);
            }
            const u16* bb = Bpad + kc * BPAD + ks * 32 + quad * 8;
            #pragma unroll
            for (int cf = 0; cf < 16; ++cf) {
                bf16x8 b = *(const bf16x8*)(bb + (cf * 16 + col) * 72);
                acc[cf] = __builtin_amdgcn_mfma_f32_16x16x32_bf16(a, b, acc[cf], 0, 0, 0);
            }
        }
    }
}

// ---------------- GAT projection (per t, both r) + als epilogue ----------------
__global__ __launch_bounds__(256) void k_proj(
    const float* __restrict__ x_t, const u16* __restrict__ Wsrc_pad, const float* __restrict__ att_src,
    u16* __restrict__ hs_t, float* __restrict__ als_t)
{
    int r = blockIdx.y;
    int m0 = blockIdx.x * 64;
    f32x4 acc[16];
    gemm_direct<true>(x_t, Wsrc_pad + (size_t)r * BPAD, N_, DIN, 1, m0, acc);

    const int tid = threadIdx.x, lane = tid & 63, wv = tid >> 6;
    const int col = lane & 15, quad = lane >> 4;
    int rowbase = m0 + wv * 16 + quad * 4;
    u16* hs = hs_t + (size_t)r * N_ * G_;
    float* als_p = als_t + (size_t)r * N_ * 4;
    const float* att_src_r = att_src + r * G_;

    float ap[4][4]; // [h][reg]
    #pragma unroll
    for (int h = 0; h < 4; ++h)
        #pragma unroll
        for (int reg = 0; reg < 4; ++reg) ap[h][reg] = 0.f;

    #pragma unroll
    for (int cf = 0; cf < 16; ++cf) {
        int gcol = cf * 16 + col;
        float av = att_src_r[gcol];
        int h = cf >> 2;
        #pragma unroll
        for (int reg = 0; reg < 4; ++reg) {
            float v = acc[cf][reg];
            int row = rowbase + reg;
            if (row < N_) hs[(size_t)row * G_ + gcol] = f2bf(v);
            ap[h][reg] += v * av;
        }
    }
    #pragma unroll
    for (int h = 0; h < 4; ++h)
        #pragma unroll
        for (int reg = 0; reg < 4; ++reg) {
            float v = ap[h][reg];
            v += __shfl_xor(v, 1); v += __shfl_xor(v, 2);
            v += __shfl_xor(v, 4); v += __shfl_xor(v, 8);
            ap[h][reg] = v;
        }
    if (col == 0) {
        #pragma unroll
        for (int reg = 0; reg < 4; ++reg) {
            int row = rowbase + reg;
            if (row < N_) {
                #pragma unroll
                for (int h = 0; h < 4; ++h)
                    als_p[(size_t)row * 4 + h] = ap[h][reg];
            }
        }
    }
}

// ---------------- ald folded GEMV: both r per x-read, 4 lanes per node ----------------
__global__ __launch_bounds__(256) void k_ald(
    const float* __restrict__ x, const float* __restrict__ wd, float* __restrict__ ald_all)
{
    int t = blockIdx.y;
    int idx = blockIdx.x * 256 + threadIdx.x;
    if (idx >= N_ * 4) return;
    int n = idx >> 2, q = idx & 3;
    const float4* xr = (const float4*)(x + ((size_t)t * N_ + n) * 64 + q * 16);
    const float* w0 = wd + q * 64;          // r=0: wd[(0*64+k)*4+h], k=q*16+kk
    const float* w1 = wd + 256 + q * 64;    // r=1
    float a0=0.f,a1=0.f,a2=0.f,a3=0.f, b0=0.f,b1=0.f,b2=0.f,b3=0.f;
    #pragma unroll
    for (int kk4 = 0; kk4 < 4; ++kk4) {
        float4 xv = xr[kk4];
        const float* u4 = w0 + kk4 * 16;
        const float* v4 = w1 + kk4 * 16;
        a0 += xv.x*u4[0]  + xv.y*u4[4]  + xv.z*u4[8]  + xv.w*u4[12];
        a1 += xv.x*u4[1]  + xv.y*u4[5]  + xv.z*u4[9]  + xv.w*u4[13];
        a2 += xv.x*u4[2]  + xv.y*u4[6]  + xv.z*u4[10] + xv.w*u4[14];
        a3 += xv.x*u4[3]  + xv.y*u4[7]  + xv.z*u4[11] + xv.w*u4[15];
        b0 += xv.x*v4[0]  + xv.y*v4[4]  + xv.z*v4[8]  + xv.w*v4[12];
        b1 += xv.x*v4[1]  + xv.y*v4[5]  + xv.z*v4[9]  + xv.w*v4[13];
        b2 += xv.x*v4[2]  + xv.y*v4[6]  + xv.z*v4[10] + xv.w*v4[14];
        b3 += xv.x*v4[3]  + xv.y*v4[7]  + xv.z*v4[11] + xv.w*v4[15];
    }
    a0 += __shfl_xor(a0,1); a0 += __shfl_xor(a0,2);
    a1 += __shfl_xor(a1,1); a1 += __shfl_xor(a1,2);
    a2 += __shfl_xor(a2,1); a2 += __shfl_xor(a2,2);
    a3 += __shfl_xor(a3,1); a3 += __shfl_xor(a3,2);
    b0 += __shfl_xor(b0,1); b0 += __shfl_xor(b0,2);
    b1 += __shfl_xor(b1,1); b1 += __shfl_xor(b1,2);
    b2 += __shfl_xor(b2,1); b2 += __shfl_xor(b2,2);
    b3 += __shfl_xor(b3,1); b3 += __shfl_xor(b3,2);
    if (q == 0) {
        *(float4*)(ald_all + ((size_t)(t*2+0) * N_ + n) * 4) = make_float4(a0,a1,a2,a3);
        *(float4*)(ald_all + ((size_t)(t*2+1) * N_ + n) * 4) = make_float4(b0,b1,b2,b3);
    }
}

// ---------------- prep: wd, padded B-tables (bf16), folded bias ----------------
__global__ void k_prep(const float* __restrict__ Wdst, const float* __restrict__ att_dst,
                       const float* __restrict__ Wih, const float* __restrict__ Whh,
                       const float* __restrict__ bih, const float* __restrict__ bhh,
                       const float* __restrict__ Wsrc, const float* __restrict__ raW1,
                       float* __restrict__ wd, float* __restrict__ biasv,
                       u16* __restrict__ Wsrc_pad, u16* __restrict__ raW1_pad,
                       u16* __restrict__ Wc_pad)
{
    int tid = threadIdx.x, bid = blockIdx.x;
    if (bid == 0) {
        for (int r = 0; r < 2; ++r) {
            int k = tid >> 2, h = tid & 3;
            float s = 0.f;
            for (int c = 0; c < 64; ++c)
                s += Wdst[((size_t)r * 64 + k) * 256 + h * 64 + c] * att_dst[r * 256 + h * 64 + c];
            wd[(r * 64 + k) * 4 + h] = s;
        }
        biasv[tid] = bih[tid] + bhh[tid];
    }
    for (int i = bid * 256 + tid; i < 3 * BPAD; i += gridDim.x * 256) {
        int r = i / BPAD, q = i % BPAD, n = q / 72, kk = q % 72;
        if (r < 2)
            Wsrc_pad[i] = (kk < 64) ? f2bf(Wsrc[(size_t)r * 64 * 256 + kk * 256 + n]) : (u16)0;
        else
            raW1_pad[q] = (kk < 64) ? f2bf(raW1[kk * 256 + n]) : (u16)0;
    }
    for (int i = bid * 256 + tid; i < 2 * BPAD; i += gridDim.x * 256) {
        int kc = i / BPAD, q = i % BPAD, n = q / 72, kk = q % 72;
        const float* W = kc ? Whh : Wih;
        Wc_pad[i] = (kk < 64) ? f2bf(W[n * 64 + kk]) : (u16)0;
    }
}

// ---------------- CSR build: block-local LDS histogram (no global atomics) ----------------
__global__ __launch_bounds__(256) void k_hist(const int* __restrict__ ei,
                                              u16* __restrict__ rank, u16* __restrict__ partial)
{
    __shared__ unsigned int hist[N_ / 2];   // packed 2 x u16, 40 KB
    int b = blockIdx.x, p = blockIdx.y, tid = threadIdx.x;
    for (int i = tid; i < N_ / 2; i += 256) hist[i] = 0u;
    __syncthreads();
    const int* dsts = ei + ((size_t)p * 2 + 1) * E_ + b * EPB_;
    u16* rk = rank + (size_t)p * E_ + b * EPB_;
    for (int e = tid; e < EPB_; e += 256) {
        int dst = dsts[e];
        unsigned sh = (unsigned)(dst & 1) * 16u;
        unsigned old = atomicAdd(&hist[dst >> 1], 1u << sh);
        rk[e] = (u16)((old >> sh) & 0xffffu);
    }
    __syncthreads();
    u16* part = partial + ((size_t)p * NB_ + b) * N_;
    for (int n = tid; n < N_; n += 256) {
        unsigned hv = hist[n >> 1];
        part[n] = (u16)((hv >> ((unsigned)(n & 1) * 16u)) & 0xffffu);
    }
}

// ---------------- scan stage 1: per-chunk (625 nodes) ----------------
__global__ __launch_bounds__(256) void k_scan1(u16* __restrict__ partial,
                                               int* __restrict__ offsets, int* __restrict__ chunktot)
{
    int p = blockIdx.y, ch = blockIdx.x;
    int tid = threadIdx.x, lane = tid & 63, wid = tid >> 6;
    __shared__ int wtot[4];
    u16* part = partial + (size_t)p * NB_ * N_;
    int* ofs = offsets + (size_t)p * (N_ + 1);
    int n0 = ch * CHN_;
    int carry = 0;
    for (int rnd = 0; rnd < 3; ++rnd) {
        int i = rnd * 256 + tid;
        int n = n0 + i;
        int v = 0;
        if (i < CHN_) {
            int run = 0;
            #pragma unroll 8
            for (int b = 0; b < NB_; ++b) {
                int pv = part[b * N_ + n];
                part[b * N_ + n] = (u16)run;
                run += pv;
            }
            v = run;
        }
        int incl = v;
        for (int d = 1; d < 64; d <<= 1) { int u = __shfl_up(incl, d); if (lane >= d) incl += u; }
        if (lane == 63) wtot[wid] = incl;
        __syncthreads();
        if (tid < 4) {
            int iv = wtot[tid];
            for (int d = 1; d < 4; d <<= 1) { int u = __shfl_up(iv, d); if (tid >= d) iv += u; }
            wtot[tid] = iv;
        }
        __syncthreads();
        int woff = (wid > 0) ? wtot[wid - 1] : 0;
        int tot = wtot[3];
        int excl = carry + woff + incl - v;
        if (i < CHN_) ofs[n] = excl;   // chunk base added in k_scan3
        carry += tot;
        __syncthreads();
    }
    if (tid == 0) chunktot[p * NB_ + ch] = carry;
}

// ---------------- scan stage 2: chunk bases (tiny) ----------------
__global__ void k_scan2(const int* __restrict__ chunktot, int* __restrict__ chunkbase) {
    int tid = threadIdx.x;
    if (tid < P_) {
        int run = 0;
        for (int c = 0; c < NB_; ++c) {
            chunkbase[tid * NB_ + c] = run;
            run += chunktot[tid * NB_ + c];
        }
    }
}

// ---------------- scan stage 3: add chunk bases ----------------
__global__ void k_scan3(int* __restrict__ offsets, const int* __restrict__ chunkbase) {
    int p = blockIdx.y;
    int n = blockIdx.x * 256 + threadIdx.x;
    if (n < N_)
        offsets[(size_t)p * (N_ + 1) + n] += chunkbase[p * NB_ + n / CHN_];
    if (n == 0)
        offsets[(size_t)p * (N_ + 1) + N_] = E_;
}

__global__ void k_scatter(const int* __restrict__ ei, const int* __restrict__ offsets,
                          const u16* __restrict__ rank, const u16* __restrict__ partial,
                          u16* __restrict__ csr) {
    int p = blockIdx.y;
    int e = blockIdx.x * 256 + threadIdx.x;
    if (e >= E_) return;
    int src = ei[((size_t)p * 2 + 0) * E_ + e];
    int dst = ei[((size_t)p * 2 + 1) * E_ + e];
    int b = e / EPB_;
    int pos = offsets[p * (N_ + 1) + dst]
            + (int)partial[((size_t)p * NB_ + b) * N_ + dst]
            + (int)rank[(size_t)p * E_ + e];
    csr[(size_t)p * E_ + pos] = (u16)src;
}

// ---------------- GAT softmax-aggregation: one wave per dst node, single pass ----------------
__global__ __launch_bounds__(256) void k_agg(
    const int* __restrict__ offsets, const u16* __restrict__ csr,
    const float* __restrict__ als_t, const float* __restrict__ ald_t,
    const u16* __restrict__ hs_t, u16* __restrict__ intra, int t)
{
    int r = blockIdx.y;
    const int* off = offsets + (size_t)(t * 2 + r) * (N_ + 1);
    const u16* srcs = csr + (size_t)(t * 2 + r) * E_;
    const float* als = als_t + (size_t)r * N_ * 4;
    const float* ald = ald_t + (size_t)r * N_ * 4;
    const u16* hs = hs_t + (size_t)r * N_ * G_;

    int tid = threadIdx.x, lane = tid & 63, wv = tid >> 6;
    int n = blockIdx.x * 4 + wv;
    int h = lane >> 4, c4 = (lane & 15) * 4;
    int o0 = off[n], o1 = off[n + 1];
    float aldv = ald[(size_t)n * 4 + h];

    float den = 0.f, a0 = 0.f, a1 = 0.f, a2 = 0.f, a3 = 0.f;
    for (int base = o0; base < o1; base += 16) {
        int cnt = o1 - base; if (cnt > 16) cnt = 16;
        int idx = base + (lane & 15);
        int sv = (idx < o1) ? (int)srcs[idx] : 0;
        #pragma unroll
        for (int j = 0; j < 16; ++j) {
            if (j < cnt) {
                int s = __shfl(sv, j);
                float e = als[s * 4 + h] + aldv;
                e = (e > 0.f) ? e : 0.2f * e;
                float pv = __expf(e);
                ushort4 hv = *(const ushort4*)(hs + (size_t)s * G_ + h * 64 + c4);
                den += pv;
                a0 += pv * bf2f(hv.x); a1 += pv * bf2f(hv.y);
                a2 += pv * bf2f(hv.z); a3 += pv * bf2f(hv.w);
            }
        }
    }
    float sc = 0.25f / (den + 1e-16f);
    a0 *= sc; a1 *= sc; a2 *= sc; a3 *= sc;
    a0 += __shfl_xor(a0, 16); a0 += __shfl_xor(a0, 32);
    a1 += __shfl_xor(a1, 16); a1 += __shfl_xor(a1, 32);
    a2 += __shfl_xor(a2, 16); a2 += __shfl_xor(a2, 32);
    a3 += __shfl_xor(a3, 16); a3 += __shfl_xor(a3, 32);
    if (h == 0) {
        u16* op = intra + (((size_t)t * N_ + n) * 2 + r) * 64 + c4;
        ushort4 ov;
        ov.x = f2bf(a0); ov.y = f2bf(a1); ov.z = f2bf(a2); ov.w = f2bf(a3);
        *(ushort4*)op = ov;
    }
}

// ---------------- RelationAgg GEMM with fused tanh(.)@W2 epilogue ----------------
__global__ __launch_bounds__(256) void k_relagg(
    const u16* __restrict__ A, const u16* __restrict__ W1pad, const float* __restrict__ b1,
    const float* __restrict__ W2, float* __restrict__ svals)
{
    int m0 = blockIdx.x * 64;
    f32x4 acc[16];
    gemm_direct<false>(A, W1pad, T_ * N_ * R_, 64, 1, m0, acc);

    const int tid = threadIdx.x, lane = tid & 63, wv = tid >> 6;
    const int col = lane & 15, quad = lane >> 4;
    int rowbase = m0 + wv * 16 + quad * 4;
    float sp[4] = {0.f, 0.f, 0.f, 0.f};
    #pragma unroll
    for (int cf = 0; cf < 16; ++cf) {
        int gcol = cf * 16 + col;
        float bb = b1[gcol];
        float ww = W2[gcol];
        #pragma unroll
        for (int reg = 0; reg < 4; ++reg)
            sp[reg] += tanhf(acc[cf][reg] + bb) * ww;
    }
    #pragma unroll
    for (int reg = 0; reg < 4; ++reg) {
        float v = sp[reg];
        v += __shfl_xor(v, 1); v += __shfl_xor(v, 2);
        v += __shfl_xor(v, 4); v += __shfl_xor(v, 8);
        sp[reg] = v;
    }
    if (col == 0) {
        #pragma unroll
        for (int reg = 0; reg < 4; ++reg) {
            int row = rowbase + reg;
            if (row < T_ * N_ * R_) svals[row] = sp[reg];
        }
    }
}

__global__ void k_betasum(const float* __restrict__ svals, float* __restrict__ ssum) {
    int p = blockIdx.x, t = p >> 1, r = p & 1;
    __shared__ float red[256];
    float s = 0.f;
    for (int n = threadIdx.x; n < N_; n += 256)
        s += svals[((size_t)t * N_ + n) * 2 + r];
    red[threadIdx.x] = s;
    __syncthreads();
    for (int st = 128; st > 0; st >>= 1) {
        if (threadIdx.x < st) red[threadIdx.x] += red[threadIdx.x + st];
        __syncthreads();
    }
    if (threadIdx.x == 0) ssum[p] = red[0];
}

__global__ void k_betafinal(const float* __restrict__ ssum, float* __restrict__ beta) {
    int t = threadIdx.x;
    if (t >= 4) return;
    float s0 = ssum[t * 2] * (1.f / N_), s1 = ssum[t * 2 + 1] * (1.f / N_);
    float mx = fmaxf(s0, s1);
    float e0 = __expf(s0 - mx), e1 = __expf(s1 - mx);
    float inv = 1.f / (e0 + e1);
    beta[t * 2] = e0 * inv; beta[t * 2 + 1] = e1 * inv;
}

// ---------------- LSTM GEMM (A assembled on the fly) + fused cell update ----------------
// kc=0 A-fragment: beta-combined intra (both r); kc=1 A-fragment: previous h (hbuf_bf).
__global__ __launch_bounds__(256) void k_lstm(
    const u16* __restrict__ intra, const float* __restrict__ beta,
    const u16* __restrict__ Wc_pad, const float* __restrict__ biasv,
    float* __restrict__ cbuf, u16* __restrict__ hbuf_bf, u16* __restrict__ feats, int t)
{
    const int tid = threadIdx.x, lane = tid & 63, wv = tid >> 6;
    const int col = lane & 15, quad = lane >> 4;
    int m0 = blockIdx.x * 64;
    int row = m0 + wv * 16 + col;
    int row_c = (row < N_) ? row : (N_ - 1);
    float b0 = beta[t * 2], b1 = beta[t * 2 + 1];
    const u16* ib = intra + ((size_t)t * N_ + row_c) * 128;

    f32x4 acc[16];
    #pragma unroll
    for (int cf = 0; cf < 16; ++cf) { acc[cf][0]=0.f; acc[cf][1]=0.f; acc[cf][2]=0.f; acc[cf][3]=0.f; }

    #pragma unroll
    for (int kc = 0; kc < 2; ++kc) {
        #pragma unroll
        for (int ks = 0; ks < 2; ++ks) {
            bf16x8 a;
            if (kc == 0) {
                int coff = ks * 32 + quad * 8;
                bf16x8 i0 = *(const bf16x8*)(ib + coff);
                bf16x8 i1 = *(const bf16x8*)(ib + 64 + coff);
                union { u16 h[8]; bf16x8 v; } cv;
                #pragma unroll
                for (int j = 0; j < 8; ++j)
                    cv.h[j] = f2bf(b0 * bf2f((u16)i0[j]) + b1 * bf2f((u16)i1[j]));
                a = cv.v;
            } else {
                a = *(const bf16x8*)(hbuf_bf + (size_t)row_c * 64 + ks * 32 + quad * 8);
            }
            const u16* bb = Wc_pad + kc * BPAD + ks * 32 + quad * 8;
            #pragma unroll
            for (int cf = 0; cf < 16; ++cf) {
                bf16x8 b = *(const bf16x8*)(bb + (cf * 16 + col) * 72);
                acc[cf] = __builtin_amdgcn_mfma_f32_16x16x32_bf16(a, b, acc[cf], 0, 0, 0);
            }
        }
    }

    int rowbase = m0 + wv * 16 + quad * 4;
    #pragma unroll
    for (int j = 0; j < 4; ++j) {
        int c = j * 16 + col;
        float bi = biasv[c], bf_ = biasv[64 + c], bg = biasv[128 + c], bo = biasv[192 + c];
        #pragma unroll
        for (int reg = 0; reg < 4; ++reg) {
            int rr = rowbase + reg;
            if (rr < N_) {
                float gi = acc[j][reg] + bi;
                float gf = acc[j + 4][reg] + bf_;
                float gg = acc[j + 8][reg] + bg;
                float go = acc[j + 12][reg] + bo;
                float cc = cbuf[(size_t)rr * 64 + c];
                cc = sigm(gf) * cc + sigm(gi) * tanhf(gg);
                float hh = sigm(go) * tanhf(cc);
                cbuf[(size_t)rr * 64 + c] = cc;
                hbuf_bf[(size_t)rr * 64 + c] = f2bf(hh);
                feats[(size_t)rr * 256 + t * 64 + c] = f2bf(hh);
            }
        }
    }
}

// ---------------- temporal causal MHA, fully fused, one wave per node ----------------
__global__ __launch_bounds__(256) void k_attn(
    const u16* __restrict__ feats, const float* __restrict__ pos_emb,
    const float* __restrict__ Wq, const float* __restrict__ Wk, const float* __restrict__ Wv,
    float* __restrict__ out)
{
    __shared__ u16 Wl[3 * 4096];
    __shared__ float scr[4][1088];
    int tid = threadIdx.x, lane = tid & 63, wv = tid >> 6;
    for (int i = tid; i < 4096; i += 256) {
        Wl[i] = f2bf(Wq[i]); Wl[4096 + i] = f2bf(Wk[i]); Wl[8192 + i] = f2bf(Wv[i]);
    }
    __syncthreads();
    int n = blockIdx.x * 4 + wv;
    float* ti = scr[wv];
    float* qs = ti + 256; float* ks_ = qs + 256; float* vs = ks_ + 256; float* as_ = vs + 256;

    #pragma unroll
    for (int t = 0; t < 4; ++t)
        ti[t * 64 + lane] = bf2f(feats[(size_t)n * 256 + t * 64 + lane]) + pos_emb[t * 64 + lane];
    __syncthreads();

    float aq[4] = {0,0,0,0}, ak[4] = {0,0,0,0}, av[4] = {0,0,0,0};
    for (int k = 0; k < 64; ++k) {
        float wq = bf2f(Wl[k * 64 + lane]);
        float wk = bf2f(Wl[4096 + k * 64 + lane]);
        float wvv = bf2f(Wl[8192 + k * 64 + lane]);
        #pragma unroll
        for (int t = 0; t < 4; ++t) {
            float tv = ti[t * 64 + k];
            aq[t] += tv * wq; ak[t] += tv * wk; av[t] += tv * wvv;
        }
    }
    #pragma unroll
    for (int t = 0; t < 4; ++t) {
        qs[t * 64 + lane] = aq[t]; ks_[t * 64 + lane] = ak[t]; vs[t * 64 + lane] = av[t];
    }
    __syncthreads();

    {
        int h = lane >> 4, tq = (lane >> 2) & 3, tk = lane & 3;
        float s = 0.f;
        #pragma unroll
        for (int j = 0; j < 16; ++j)
            s += qs[tq * 64 + h * 16 + j] * ks_[tk * 64 + h * 16 + j];
        s *= 0.5f;                       // 1/sqrt(T), T=4
        if (tk > tq) s = -4294967295.0f; // NEG_INF = -2^32+1
        float mx = fmaxf(s, __shfl_xor(s, 1)); mx = fmaxf(mx, __shfl_xor(mx, 2));
        float pv = __expf(s - mx);
        float sm = pv + __shfl_xor(pv, 1); sm += __shfl_xor(sm, 2);
        as_[lane] = pv / sm;
    }
    __syncthreads();

    int h = lane >> 4;
    #pragma unroll
    for (int t = 0; t < 4; ++t) {
        float o = 0.f;
        #pragma unroll
        for (int k2 = 0; k2 < 4; ++k2)
            o += as_[h * 16 + t * 4 + k2] * vs[k2 * 64 + lane];
        out[(size_t)n * 256 + t * 64 + lane] = o;
    }
}

// ---------------- launcher ----------------
extern "C" void kernel_launch(void* const* d_in, const int* in_sizes, int n_in,
                              void* d_out, int out_size, void* d_ws, size_t ws_size,
                              hipStream_t stream) {
    const float* x     = (const float*)d_in[0];
    const int* ei      = (const int*)d_in[1];
    const float* Wsrc  = (const float*)d_in[2];
    const float* Wdst  = (const float*)d_in[3];
    const float* att_src = (const float*)d_in[4];
    const float* att_dst = (const float*)d_in[5];
    const float* raW1  = (const float*)d_in[6];
    const float* rab1  = (const float*)d_in[7];
    const float* raW2  = (const float*)d_in[8];
    const float* Wih   = (const float*)d_in[9];
    const float* Whh   = (const float*)d_in[10];
    const float* bih   = (const float*)d_in[11];
    const float* bhh   = (const float*)d_in[12];
    const float* pos   = (const float*)d_in[13];
    const float* Wq    = (const float*)d_in[14];
    const float* Wk    = (const float*)d_in[15];
    const float* Wv    = (const float*)d_in[16];
    float* out = (float*)d_out;

    char* w = (char*)d_ws;
    size_t off = 0;
    auto alloc = [&](size_t bytes) -> char* {
        char* pp = w + off; off += (bytes + 255) & ~(size_t)255; return pp;
    };
    // ---- long-lived ----
    u16*   intra     = (u16*)  alloc((size_t)T_ * N_ * R_ * 64 * 2);  // 20.48 MB
    float* svals     = (float*)alloc((size_t)T_ * N_ * R_ * 4);       // 0.64 MB
    float* ssum      = (float*)alloc(256);
    float* beta      = (float*)alloc(256);
    float* wd        = (float*)alloc(2 * 64 * 4 * 4);
    float* biasv     = (float*)alloc(256 * 4);
    u16*   Wsrc_pad  = (u16*)  alloc(2 * BPAD * 2);
    u16*   raW1_pad  = (u16*)  alloc(BPAD * 2);
    u16*   Wc_pad    = (u16*)  alloc(2 * BPAD * 2);
    int*   chunktot  = (int*)  alloc(P_ * NB_ * 4);
    int*   chunkbase = (int*)  alloc(P_ * NB_ * 4);
    // ---- union region ----
    char*  ubase   = alloc(0);
    size_t uoff = 0;
    auto ualloc = [&](size_t bytes) -> char* {
        char* pp = ubase + uoff; uoff += (bytes + 255) & ~(size_t)255; return pp;
    };
    int*   offsets = (int*)  ualloc((size_t)P_ * (N_ + 1) * 4);     // 0.64 MB
    u16*   csr     = (u16*)  ualloc((size_t)P_ * E_ * 2);           // 5.12 MB
    float* als_all = (float*)ualloc((size_t)P_ * N_ * 4 * 4);       // 2.56 MB
    float* ald_all = (float*)ualloc((size_t)P_ * N_ * 4 * 4);       // 2.56 MB
    u16*   partial = (u16*)  ualloc((size_t)P_ * NB_ * N_ * 2);     // 10.24 MB
    u16*   hs_t    = (u16*)  ualloc((size_t)R_ * N_ * G_ * 2);      // 20.48 MB
    // rank overlays hs_t (rank dead after k_scatter, before first k_proj)
    u16*   rank    = (u16*)  hs_t;                                   // 5.12 MB
    // phase 2 (overlays phase-1 sub-buffers dead after the k_agg loop)
    float* cbuf    = (float*)(ubase);                                // 5.12 MB
    u16*   hbuf_bf = (u16*)  (ubase + 5300000);                      // 2.56 MB
    u16*   feats   = (u16*)  (ubase + 8000000);                      // 10.24 MB
    (void)ws_size; (void)in_sizes; (void)n_in; (void)out_size;

    k_prep<<<72, 256, 0, stream>>>(Wdst, att_dst, Wih, Whh, bih, bhh, Wsrc, raW1,
                                   wd, biasv, Wsrc_pad, raW1_pad, Wc_pad);
    k_hist<<<dim3(NB_, 8), 256, 0, stream>>>(ei, rank, partial);
    k_scan1<<<dim3(NB_, 8), 256, 0, stream>>>(partial, offsets, chunktot);
    k_scan2<<<1, 64, 0, stream>>>(chunktot, chunkbase);
    k_scan3<<<dim3(79, 8), 256, 0, stream>>>(offsets, chunkbase);
    k_scatter<<<dim3(1250, 8), 256, 0, stream>>>(ei, offsets, rank, partial, csr);
    k_ald<<<dim3(313, 4), 256, 0, stream>>>(x, wd, ald_all);
    for (int t = 0; t < T_; ++t) {
        k_proj<<<dim3(313, 2), 256, 0, stream>>>(x + (size_t)t * N_ * DIN, Wsrc_pad,
                                                 att_src, hs_t, als_all + (size_t)t * 2 * N_ * 4);
        k_agg<<<dim3(5000, 2), 256, 0, stream>>>(offsets, csr,
                                                 als_all + (size_t)t * 2 * N_ * 4,
                                                 ald_all + (size_t)t * 2 * N_ * 4,
                                                 hs_t, intra, t);
    }
    k_relagg<<<2500, 256, 0, stream>>>(intra, raW1_pad, rab1, raW2, svals);
    k_betasum<<<8, 256, 0, stream>>>(svals, ssum);
    k_betafinal<<<1, 64, 0, stream>>>(ssum, beta);
    hipMemsetAsync(cbuf, 0, (size_t)N_ * 64 * 4, stream);
    hipMemsetAsync(hbuf_bf, 0, (size_t)N_ * 64 * 2, stream);
    for (int t = 0; t < T_; ++t)
        k_lstm<<<313, 256, 0, stream>>>(intra, beta, Wc_pad, biasv, cbuf, hbuf_bf, feats, t);
    k_attn<<<5000, 256, 0, stream>>>(feats, pos, Wq, Wk, Wv, out);
}

// Round 7
// 602.597 us; speedup vs baseline: 2.0077x; 1.1210x over previous
//
#include <hip/hip_runtime.h>
#include <hip/hip_bf16.h>

#define T_ 4
#define N_ 20000
#define E_ 320000
#define R_ 2
#define DIN 64
#define G_ 256   // H*Dh
#define P_ 8     // T*R
#define BPAD 18432  // 256 * 72 padded B-table halves per 64-k chunk
#define NB_ 32      // CSR-build blocks per p
#define EPB_ 10000  // edges per CSR-build block
#define CHN_ 625    // nodes per scan chunk (N_/32)

typedef unsigned short u16;
typedef __attribute__((ext_vector_type(8))) short bf16x8;
typedef __attribute__((ext_vector_type(4))) float f32x4;

__device__ __forceinline__ float bf2f(u16 u) {
    unsigned int i = ((unsigned int)u) << 16; float f;
    __builtin_memcpy(&f, &i, 4); return f;
}
__device__ __forceinline__ u16 f2bf(float f) {
    unsigned int i; __builtin_memcpy(&i, &f, 4);
    unsigned int r = i + 0x7fffu + ((i >> 16) & 1u);
    return (u16)(r >> 16);
}
__device__ __forceinline__ float sigm(float x) { return 1.f / (1.f + __expf(-x)); }

__device__ __forceinline__ bf16x8 load_a_f32(const float* p) {
    float4 f0 = *(const float4*)p;
    float4 f1 = *(const float4*)(p + 4);
    union { u16 h[8]; bf16x8 v; } u;
    u.h[0] = f2bf(f0.x); u.h[1] = f2bf(f0.y); u.h[2] = f2bf(f0.z); u.h[3] = f2bf(f0.w);
    u.h[4] = f2bf(f1.x); u.h[5] = f2bf(f1.y); u.h[6] = f2bf(f1.z); u.h[7] = f2bf(f1.w);
    return u.v;
}

// ---------------- LDS-free MFMA GEMM core ----------------
template <bool AF32>
__device__ __forceinline__ void gemm_direct(
    const void* __restrict__ Av, const u16* __restrict__ Bpad,
    int M, int Astride, int kchunks, int m0, f32x4* acc)
{
    const int tid = threadIdx.x;
    const int lane = tid & 63, wv = tid >> 6;
    const int col = lane & 15, quad = lane >> 4;
    #pragma unroll
    for (int cf = 0; cf < 16; ++cf) { acc[cf][0]=0.f; acc[cf][1]=0.f; acc[cf][2]=0.f; acc[cf][3]=0.f; }

    int row = m0 + wv * 16 + col;
    int row_c = (row < M) ? row : (M - 1);

    for (int kc = 0; kc < kchunks; ++kc) {
        #pragma unroll
        for (int ks = 0; ks < 2; ++ks) {
            bf16x8 a;
            if (AF32) {
                const float* A = (const float*)Av + (size_t)row_c * Astride + kc * 64 + ks * 32 + quad * 8;
                a = load_a_f32(A);
            } else {
                a = *(const bf16x8*)((const u16*)Av + (size_t)row_c * Astride + kc * 64 + ks * 32 + quad * 8);
            }
            const u16* bb = Bpad + kc * BPAD + ks * 32 + quad * 8;
            #pragma unroll
            for (int cf = 0; cf < 16; ++cf) {
                bf16x8 b = *(const bf16x8*)(bb + (cf * 16 + col) * 72);
                acc[cf] = __builtin_amdgcn_mfma_f32_16x16x32_bf16(a, b, acc[cf], 0, 0, 0);
            }
        }
    }
}

// ---------------- GAT projection (per t, both r) + als epilogue ----------------
__global__ __launch_bounds__(256) void k_proj(
    const float* __restrict__ x_t, const u16* __restrict__ Wsrc_pad, const float* __restrict__ att_src,
    u16* __restrict__ hs_t, float* __restrict__ als_t)
{
    int r = blockIdx.y;
    int m0 = blockIdx.x * 64;
    f32x4 acc[16];
    gemm_direct<true>(x_t, Wsrc_pad + (size_t)r * BPAD, N_, DIN, 1, m0, acc);

    const int tid = threadIdx.x, lane = tid & 63, wv = tid >> 6;
    const int col = lane & 15, quad = lane >> 4;
    int rowbase = m0 + wv * 16 + quad * 4;
    u16* hs = hs_t + (size_t)r * N_ * G_;
    float* als_p = als_t + (size_t)r * N_ * 4;
    const float* att_src_r = att_src + r * G_;

    float ap[4][4];
    #pragma unroll
    for (int h = 0; h < 4; ++h)
        #pragma unroll
        for (int reg = 0; reg < 4; ++reg) ap[h][reg] = 0.f;

    #pragma unroll
    for (int cf = 0; cf < 16; ++cf) {
        int gcol = cf * 16 + col;
        float av = att_src_r[gcol];
        int h = cf >> 2;
        #pragma unroll
        for (int reg = 0; reg < 4; ++reg) {
            float v = acc[cf][reg];
            int row = rowbase + reg;
            if (row < N_) hs[(size_t)row * G_ + gcol] = f2bf(v);
            ap[h][reg] += v * av;
        }
    }
    #pragma unroll
    for (int h = 0; h < 4; ++h)
        #pragma unroll
        for (int reg = 0; reg < 4; ++reg) {
            float v = ap[h][reg];
            v += __shfl_xor(v, 1); v += __shfl_xor(v, 2);
            v += __shfl_xor(v, 4); v += __shfl_xor(v, 8);
            ap[h][reg] = v;
        }
    if (col == 0) {
        #pragma unroll
        for (int reg = 0; reg < 4; ++reg) {
            int row = rowbase + reg;
            if (row < N_) {
                #pragma unroll
                for (int h = 0; h < 4; ++h)
                    als_p[(size_t)row * 4 + h] = ap[h][reg];
            }
        }
    }
}

// ---------------- ald folded GEMV: both r per x-read ----------------
__global__ __launch_bounds__(256) void k_ald(
    const float* __restrict__ x, const float* __restrict__ wd, float* __restrict__ ald_all)
{
    int t = blockIdx.y;
    int idx = blockIdx.x * 256 + threadIdx.x;
    if (idx >= N_ * 4) return;
    int n = idx >> 2, q = idx & 3;
    const float4* xr = (const float4*)(x + ((size_t)t * N_ + n) * 64 + q * 16);
    const float* w0 = wd + q * 64;
    const float* w1 = wd + 256 + q * 64;
    float a0=0.f,a1=0.f,a2=0.f,a3=0.f, b0=0.f,b1=0.f,b2=0.f,b3=0.f;
    #pragma unroll
    for (int kk4 = 0; kk4 < 4; ++kk4) {
        float4 xv = xr[kk4];
        const float* u4 = w0 + kk4 * 16;
        const float* v4 = w1 + kk4 * 16;
        a0 += xv.x*u4[0]  + xv.y*u4[4]  + xv.z*u4[8]  + xv.w*u4[12];
        a1 += xv.x*u4[1]  + xv.y*u4[5]  + xv.z*u4[9]  + xv.w*u4[13];
        a2 += xv.x*u4[2]  + xv.y*u4[6]  + xv.z*u4[10] + xv.w*u4[14];
        a3 += xv.x*u4[3]  + xv.y*u4[7]  + xv.z*u4[11] + xv.w*u4[15];
        b0 += xv.x*v4[0]  + xv.y*v4[4]  + xv.z*v4[8]  + xv.w*v4[12];
        b1 += xv.x*v4[1]  + xv.y*v4[5]  + xv.z*v4[9]  + xv.w*v4[13];
        b2 += xv.x*v4[2]  + xv.y*v4[6]  + xv.z*v4[10] + xv.w*v4[14];
        b3 += xv.x*v4[3]  + xv.y*v4[7]  + xv.z*v4[11] + xv.w*v4[15];
    }
    a0 += __shfl_xor(a0,1); a0 += __shfl_xor(a0,2);
    a1 += __shfl_xor(a1,1); a1 += __shfl_xor(a1,2);
    a2 += __shfl_xor(a2,1); a2 += __shfl_xor(a2,2);
    a3 += __shfl_xor(a3,1); a3 += __shfl_xor(a3,2);
    b0 += __shfl_xor(b0,1); b0 += __shfl_xor(b0,2);
    b1 += __shfl_xor(b1,1); b1 += __shfl_xor(b1,2);
    b2 += __shfl_xor(b2,1); b2 += __shfl_xor(b2,2);
    b3 += __shfl_xor(b3,1); b3 += __shfl_xor(b3,2);
    if (q == 0) {
        *(float4*)(ald_all + ((size_t)(t*2+0) * N_ + n) * 4) = make_float4(a0,a1,a2,a3);
        *(float4*)(ald_all + ((size_t)(t*2+1) * N_ + n) * 4) = make_float4(b0,b1,b2,b3);
    }
}

// ---------------- prep: wd, padded B-tables (bf16), folded bias ----------------
__global__ void k_prep(const float* __restrict__ Wdst, const float* __restrict__ att_dst,
                       const float* __restrict__ Wih, const float* __restrict__ Whh,
                       const float* __restrict__ bih, const float* __restrict__ bhh,
                       const float* __restrict__ Wsrc, const float* __restrict__ raW1,
                       const float* __restrict__ Wq, const float* __restrict__ Wk,
                       const float* __restrict__ Wv,
                       float* __restrict__ wd, float* __restrict__ biasv,
                       u16* __restrict__ Wsrc_pad, u16* __restrict__ raW1_pad,
                       u16* __restrict__ Wc_pad, u16* __restrict__ qkv_pad)
{
    int tid = threadIdx.x, bid = blockIdx.x;
    if (bid == 0) {
        for (int r = 0; r < 2; ++r) {
            int k = tid >> 2, h = tid & 3;
            float s = 0.f;
            for (int c = 0; c < 64; ++c)
                s += Wdst[((size_t)r * 64 + k) * 256 + h * 64 + c] * att_dst[r * 256 + h * 64 + c];
            wd[(r * 64 + k) * 4 + h] = s;
        }
        biasv[tid] = bih[tid] + bhh[tid];
    }
    for (int i = bid * 256 + tid; i < 3 * BPAD; i += gridDim.x * 256) {
        int r = i / BPAD, q = i % BPAD, n = q / 72, kk = q % 72;
        if (r < 2)
            Wsrc_pad[i] = (kk < 64) ? f2bf(Wsrc[(size_t)r * 64 * 256 + kk * 256 + n]) : (u16)0;
        else
            raW1_pad[q] = (kk < 64) ? f2bf(raW1[kk * 256 + n]) : (u16)0;
    }
    for (int i = bid * 256 + tid; i < 2 * BPAD; i += gridDim.x * 256) {
        int kc = i / BPAD, q = i % BPAD, n = q / 72, kk = q % 72;
        const float* W = kc ? Whh : Wih;
        Wc_pad[i] = (kk < 64) ? f2bf(W[n * 64 + kk]) : (u16)0;
    }
    // qkv_pad[g*72+kk] = [Wq|Wk|Wv][kk][g], g in [0,192)
    for (int i = bid * 256 + tid; i < 192 * 72; i += gridDim.x * 256) {
        int g = i / 72, kk = i % 72;
        int j = g >> 6, c = g & 63;
        const float* W = (j == 0) ? Wq : (j == 1) ? Wk : Wv;
        qkv_pad[i] = (kk < 64) ? f2bf(W[kk * 64 + c]) : (u16)0;
    }
}

// ---------------- CSR build ----------------
__global__ __launch_bounds__(256) void k_hist(const int* __restrict__ ei,
                                              u16* __restrict__ rank, u16* __restrict__ partial)
{
    __shared__ unsigned int hist[N_ / 2];
    int b = blockIdx.x, p = blockIdx.y, tid = threadIdx.x;
    for (int i = tid; i < N_ / 2; i += 256) hist[i] = 0u;
    __syncthreads();
    const int* dsts = ei + ((size_t)p * 2 + 1) * E_ + b * EPB_;
    u16* rk = rank + (size_t)p * E_ + b * EPB_;
    for (int e = tid; e < EPB_; e += 256) {
        int dst = dsts[e];
        unsigned sh = (unsigned)(dst & 1) * 16u;
        unsigned old = atomicAdd(&hist[dst >> 1], 1u << sh);
        rk[e] = (u16)((old >> sh) & 0xffffu);
    }
    __syncthreads();
    u16* part = partial + ((size_t)p * NB_ + b) * N_;
    for (int n = tid; n < N_; n += 256) {
        unsigned hv = hist[n >> 1];
        part[n] = (u16)((hv >> ((unsigned)(n & 1) * 16u)) & 0xffffu);
    }
}

__global__ __launch_bounds__(256) void k_scan1(u16* __restrict__ partial,
                                               int* __restrict__ offsets, int* __restrict__ chunktot)
{
    int p = blockIdx.y, ch = blockIdx.x;
    int tid = threadIdx.x, lane = tid & 63, wid = tid >> 6;
    __shared__ int wtot[4];
    u16* part = partial + (size_t)p * NB_ * N_;
    int* ofs = offsets + (size_t)p * (N_ + 1);
    int n0 = ch * CHN_;
    int carry = 0;
    for (int rnd = 0; rnd < 3; ++rnd) {
        int i = rnd * 256 + tid;
        int n = n0 + i;
        int v = 0;
        if (i < CHN_) {
            int run = 0;
            #pragma unroll 8
            for (int b = 0; b < NB_; ++b) {
                int pv = part[b * N_ + n];
                part[b * N_ + n] = (u16)run;
                run += pv;
            }
            v = run;
        }
        int incl = v;
        for (int d = 1; d < 64; d <<= 1) { int u = __shfl_up(incl, d); if (lane >= d) incl += u; }
        if (lane == 63) wtot[wid] = incl;
        __syncthreads();
        if (tid < 4) {
            int iv = wtot[tid];
            for (int d = 1; d < 4; d <<= 1) { int u = __shfl_up(iv, d); if (tid >= d) iv += u; }
            wtot[tid] = iv;
        }
        __syncthreads();
        int woff = (wid > 0) ? wtot[wid - 1] : 0;
        int tot = wtot[3];
        int excl = carry + woff + incl - v;
        if (i < CHN_) ofs[n] = excl;
        carry += tot;
        __syncthreads();
    }
    if (tid == 0) chunktot[p * NB_ + ch] = carry;
}

__global__ void k_scan2(const int* __restrict__ chunktot, int* __restrict__ chunkbase) {
    int tid = threadIdx.x;
    if (tid < P_) {
        int run = 0;
        for (int c = 0; c < NB_; ++c) {
            chunkbase[tid * NB_ + c] = run;
            run += chunktot[tid * NB_ + c];
        }
    }
}

__global__ void k_scan3(int* __restrict__ offsets, const int* __restrict__ chunkbase) {
    int p = blockIdx.y;
    int n = blockIdx.x * 256 + threadIdx.x;
    if (n < N_)
        offsets[(size_t)p * (N_ + 1) + n] += chunkbase[p * NB_ + n / CHN_];
    if (n == 0)
        offsets[(size_t)p * (N_ + 1) + N_] = E_;
}

__global__ void k_scatter(const int* __restrict__ ei, const int* __restrict__ offsets,
                          const u16* __restrict__ rank, const u16* __restrict__ partial,
                          u16* __restrict__ csr) {
    int p = blockIdx.y;
    int e = blockIdx.x * 256 + threadIdx.x;
    if (e >= E_) return;
    int src = ei[((size_t)p * 2 + 0) * E_ + e];
    int dst = ei[((size_t)p * 2 + 1) * E_ + e];
    int b = e / EPB_;
    int pos = offsets[p * (N_ + 1) + dst]
            + (int)partial[((size_t)p * NB_ + b) * N_ + dst]
            + (int)rank[(size_t)p * E_ + e];
    csr[(size_t)p * E_ + pos] = (u16)src;
}

// ---------------- GAT softmax-aggregation: one wave per dst node ----------------
#define AGG_EDGE(S)                                                              \
    {   int s = (S);                                                             \
        float e = als[s * 4 + h] + aldv;                                         \
        e = (e > 0.f) ? e : 0.2f * e;                                            \
        float pv = __expf(e);                                                    \
        ushort4 hv = *(const ushort4*)(hs + (size_t)s * G_ + h * 64 + c4);       \
        den += pv;                                                               \
        a0 += pv * bf2f(hv.x); a1 += pv * bf2f(hv.y);                            \
        a2 += pv * bf2f(hv.z); a3 += pv * bf2f(hv.w); }

__global__ __launch_bounds__(256) void k_agg(
    const int* __restrict__ offsets, const u16* __restrict__ csr,
    const float* __restrict__ als_t, const float* __restrict__ ald_t,
    const u16* __restrict__ hs_t, u16* __restrict__ intra, int t)
{
    int r = blockIdx.y;
    const int* off = offsets + (size_t)(t * 2 + r) * (N_ + 1);
    const u16* srcs = csr + (size_t)(t * 2 + r) * E_;
    const float* als = als_t + (size_t)r * N_ * 4;
    const float* ald = ald_t + (size_t)r * N_ * 4;
    const u16* hs = hs_t + (size_t)r * N_ * G_;

    int tid = threadIdx.x, lane = tid & 63, wv = tid >> 6;
    int n = blockIdx.x * 4 + wv;
    int h = lane >> 4, c4 = (lane & 15) * 4;
    int o0 = off[n], o1 = off[n + 1];
    float aldv = ald[(size_t)n * 4 + h];

    float den = 0.f, a0 = 0.f, a1 = 0.f, a2 = 0.f, a3 = 0.f;
    int base = o0;
    // branch-free full batches: all 16 gathers can be in flight
    for (; base + 16 <= o1; base += 16) {
        int sv = (int)srcs[base + (lane & 15)];
        #pragma unroll
        for (int j = 0; j < 16; ++j) AGG_EDGE(__shfl(sv, j))
    }
    if (base < o1) {
        int cnt = o1 - base;
        int idx = base + (lane & 15);
        int sv = (idx < o1) ? (int)srcs[idx] : 0;
        for (int j = 0; j < cnt; ++j) AGG_EDGE(__shfl(sv, j))
    }
    float sc = 0.25f / (den + 1e-16f);
    a0 *= sc; a1 *= sc; a2 *= sc; a3 *= sc;
    a0 += __shfl_xor(a0, 16); a0 += __shfl_xor(a0, 32);
    a1 += __shfl_xor(a1, 16); a1 += __shfl_xor(a1, 32);
    a2 += __shfl_xor(a2, 16); a2 += __shfl_xor(a2, 32);
    a3 += __shfl_xor(a3, 16); a3 += __shfl_xor(a3, 32);
    if (h == 0) {
        u16* op = intra + (((size_t)t * N_ + n) * 2 + r) * 64 + c4;
        ushort4 ov;
        ov.x = f2bf(a0); ov.y = f2bf(a1); ov.z = f2bf(a2); ov.w = f2bf(a3);
        *(ushort4*)op = ov;
    }
}

// ---------------- RelationAgg GEMM with fused tanh(.)@W2 epilogue ----------------
__global__ __launch_bounds__(256) void k_relagg(
    const u16* __restrict__ A, const u16* __restrict__ W1pad, const float* __restrict__ b1,
    const float* __restrict__ W2, float* __restrict__ svals)
{
    int m0 = blockIdx.x * 64;
    f32x4 acc[16];
    gemm_direct<false>(A, W1pad, T_ * N_ * R_, 64, 1, m0, acc);

    const int tid = threadIdx.x, lane = tid & 63, wv = tid >> 6;
    const int col = lane & 15, quad = lane >> 4;
    int rowbase = m0 + wv * 16 + quad * 4;
    float sp[4] = {0.f, 0.f, 0.f, 0.f};
    #pragma unroll
    for (int cf = 0; cf < 16; ++cf) {
        int gcol = cf * 16 + col;
        float bb = b1[gcol];
        float ww = W2[gcol];
        #pragma unroll
        for (int reg = 0; reg < 4; ++reg)
            sp[reg] += tanhf(acc[cf][reg] + bb) * ww;
    }
    #pragma unroll
    for (int reg = 0; reg < 4; ++reg) {
        float v = sp[reg];
        v += __shfl_xor(v, 1); v += __shfl_xor(v, 2);
        v += __shfl_xor(v, 4); v += __shfl_xor(v, 8);
        sp[reg] = v;
    }
    if (col == 0) {
        #pragma unroll
        for (int reg = 0; reg < 4; ++reg) {
            int row = rowbase + reg;
            if (row < T_ * N_ * R_) svals[row] = sp[reg];
        }
    }
}

__global__ void k_betasum(const float* __restrict__ svals, float* __restrict__ ssum) {
    int p = blockIdx.x, t = p >> 1, r = p & 1;
    __shared__ float red[256];
    float s = 0.f;
    for (int n = threadIdx.x; n < N_; n += 256)
        s += svals[((size_t)t * N_ + n) * 2 + r];
    red[threadIdx.x] = s;
    __syncthreads();
    for (int st = 128; st > 0; st >>= 1) {
        if (threadIdx.x < st) red[threadIdx.x] += red[threadIdx.x + st];
        __syncthreads();
    }
    if (threadIdx.x == 0) ssum[p] = red[0];
}

__global__ void k_betafinal(const float* __restrict__ ssum, float* __restrict__ beta) {
    int t = threadIdx.x;
    if (t >= 4) return;
    float s0 = ssum[t * 2] * (1.f / N_), s1 = ssum[t * 2 + 1] * (1.f / N_);
    float mx = fmaxf(s0, s1);
    float e0 = __expf(s0 - mx), e1 = __expf(s1 - mx);
    float inv = 1.f / (e0 + e1);
    beta[t * 2] = e0 * inv; beta[t * 2 + 1] = e1 * inv;
}

// ---------------- LSTM GEMM (A assembled on the fly) + fused cell update ----------------
__global__ __launch_bounds__(256) void k_lstm(
    const u16* __restrict__ intra, const float* __restrict__ beta,
    const u16* __restrict__ Wc_pad, const float* __restrict__ biasv,
    float* __restrict__ cbuf, u16* __restrict__ hbuf_bf, u16* __restrict__ feats, int t)
{
    const int tid = threadIdx.x, lane = tid & 63, wv = tid >> 6;
    const int col = lane & 15, quad = lane >> 4;
    int m0 = blockIdx.x * 64;
    int row = m0 + wv * 16 + col;
    int row_c = (row < N_) ? row : (N_ - 1);
    float b0 = beta[t * 2], b1 = beta[t * 2 + 1];
    const u16* ib = intra + ((size_t)t * N_ + row_c) * 128;

    f32x4 acc[16];
    #pragma unroll
    for (int cf = 0; cf < 16; ++cf) { acc[cf][0]=0.f; acc[cf][1]=0.f; acc[cf][2]=0.f; acc[cf][3]=0.f; }

    #pragma unroll
    for (int kc = 0; kc < 2; ++kc) {
        #pragma unroll
        for (int ks = 0; ks < 2; ++ks) {
            bf16x8 a;
            if (kc == 0) {
                int coff = ks * 32 + quad * 8;
                bf16x8 i0 = *(const bf16x8*)(ib + coff);
                bf16x8 i1 = *(const bf16x8*)(ib + 64 + coff);
                union { u16 h[8]; bf16x8 v; } cv;
                #pragma unroll
                for (int j = 0; j < 8; ++j)
                    cv.h[j] = f2bf(b0 * bf2f((u16)i0[j]) + b1 * bf2f((u16)i1[j]));
                a = cv.v;
            } else {
                a = *(const bf16x8*)(hbuf_bf + (size_t)row_c * 64 + ks * 32 + quad * 8);
            }
            const u16* bb = Wc_pad + kc * BPAD + ks * 32 + quad * 8;
            #pragma unroll
            for (int cf = 0; cf < 16; ++cf) {
                bf16x8 b = *(const bf16x8*)(bb + (cf * 16 + col) * 72);
                acc[cf] = __builtin_amdgcn_mfma_f32_16x16x32_bf16(a, b, acc[cf], 0, 0, 0);
            }
        }
    }

    int rowbase = m0 + wv * 16 + quad * 4;
    #pragma unroll
    for (int j = 0; j < 4; ++j) {
        int c = j * 16 + col;
        float bi = biasv[c], bf_ = biasv[64 + c], bg = biasv[128 + c], bo = biasv[192 + c];
        #pragma unroll
        for (int reg = 0; reg < 4; ++reg) {
            int rr = rowbase + reg;
            if (rr < N_) {
                float gi = acc[j][reg] + bi;
                float gf = acc[j + 4][reg] + bf_;
                float gg = acc[j + 8][reg] + bg;
                float go = acc[j + 12][reg] + bo;
                float cc = cbuf[(size_t)rr * 64 + c];
                cc = sigm(gf) * cc + sigm(gi) * tanhf(gg);
                float hh = sigm(go) * tanhf(cc);
                cbuf[(size_t)rr * 64 + c] = cc;
                hbuf_bf[(size_t)rr * 64 + c] = f2bf(hh);
                feats[(size_t)rr * 256 + t * 64 + c] = f2bf(hh);
            }
        }
    }
}

// ---------------- temporal causal MHA: MFMA QKV + per-lane attention ----------------
// Block = 16 nodes = 64 (n,t) rows. QKV = (feats+pos) @ [Wq|Wk|Wv] via MFMA -> LDS.
__global__ __launch_bounds__(256) void k_attn(
    const u16* __restrict__ feats, const float* __restrict__ pos_emb,
    const u16* __restrict__ qkv_pad, float* __restrict__ out)
{
    __shared__ float qkv_s[64 * 200];   // 51.2 KB, padded stride vs 192 bank pathology
    const int tid = threadIdx.x, lane = tid & 63, wv = tid >> 6;
    const int col = lane & 15, quad = lane >> 4;
    int m0 = blockIdx.x * 64;            // rows m = n*4+t
    int row = m0 + wv * 16 + col;        // wave-private row
    int trow = row & 3;

    // ---- QKV GEMM: 12 col-fragments (192 cols), K=64 ----
    f32x4 acc[12];
    #pragma unroll
    for (int cf = 0; cf < 12; ++cf) { acc[cf][0]=0.f; acc[cf][1]=0.f; acc[cf][2]=0.f; acc[cf][3]=0.f; }
    #pragma unroll
    for (int ks = 0; ks < 2; ++ks) {
        int coff = ks * 32 + quad * 8;
        bf16x8 fv = *(const bf16x8*)(feats + (size_t)row * 64 + coff);
        float4 p0 = *(const float4*)(pos_emb + trow * 64 + coff);
        float4 p1 = *(const float4*)(pos_emb + trow * 64 + coff + 4);
        union { u16 h[8]; bf16x8 v; } cv;
        cv.h[0] = f2bf(bf2f((u16)fv[0]) + p0.x); cv.h[1] = f2bf(bf2f((u16)fv[1]) + p0.y);
        cv.h[2] = f2bf(bf2f((u16)fv[2]) + p0.z); cv.h[3] = f2bf(bf2f((u16)fv[3]) + p0.w);
        cv.h[4] = f2bf(bf2f((u16)fv[4]) + p1.x); cv.h[5] = f2bf(bf2f((u16)fv[5]) + p1.y);
        cv.h[6] = f2bf(bf2f((u16)fv[6]) + p1.z); cv.h[7] = f2bf(bf2f((u16)fv[7]) + p1.w);
        bf16x8 a = cv.v;
        const u16* bb = qkv_pad + ks * 32 + quad * 8;
        #pragma unroll
        for (int cf = 0; cf < 12; ++cf) {
            bf16x8 b = *(const bf16x8*)(bb + (cf * 16 + col) * 72);
            acc[cf] = __builtin_amdgcn_mfma_f32_16x16x32_bf16(a, b, acc[cf], 0, 0, 0);
        }
    }
    // epilogue -> LDS (C layout: col=lane&15, row=quad*4+reg)
    #pragma unroll
    for (int cf = 0; cf < 12; ++cf) {
        int g = cf * 16 + col;
        #pragma unroll
        for (int reg = 0; reg < 4; ++reg) {
            int rl = wv * 16 + quad * 4 + reg;
            qkv_s[rl * 200 + g] = acc[cf][reg];
        }
    }
    __syncthreads();

    // ---- attention: lane = (node-in-group, h, tq) ----
    int nl = wv * 4 + (lane >> 4);       // node local [0,16)
    int sub = lane & 15;
    int h = sub >> 2, tq = sub & 3;
    const float* qrow = qkv_s + (nl * 4 + tq) * 200 + h * 16;

    float s[4];
    #pragma unroll
    for (int tk = 0; tk < 4; ++tk) {
        const float* krow = qkv_s + (nl * 4 + tk) * 200 + 64 + h * 16;
        float d = 0.f;
        #pragma unroll
        for (int j = 0; j < 16; ++j) d += qrow[j] * krow[j];
        s[tk] = (tk > tq) ? -4294967295.0f : d * 0.5f;  // 1/sqrt(T)=0.5; NEG_INF
    }
    float mx = fmaxf(fmaxf(s[0], s[1]), fmaxf(s[2], s[3]));
    float a0 = __expf(s[0]-mx), a1 = __expf(s[1]-mx), a2 = __expf(s[2]-mx), a3 = __expf(s[3]-mx);
    float inv = 1.f / (a0 + a1 + a2 + a3);
    a0 *= inv; a1 *= inv; a2 *= inv; a3 *= inv;

    int n = blockIdx.x * 16 + nl;
    const float* v0 = qkv_s + (nl * 4 + 0) * 200 + 128 + h * 16;
    const float* v1 = v0 + 200, *v2 = v0 + 400, *v3 = v0 + 600;
    #pragma unroll
    for (int cc4 = 0; cc4 < 4; ++cc4) {
        float4 o;
        o.x = a0*v0[cc4*4+0] + a1*v1[cc4*4+0] + a2*v2[cc4*4+0] + a3*v3[cc4*4+0];
        o.y = a0*v0[cc4*4+1] + a1*v1[cc4*4+1] + a2*v2[cc4*4+1] + a3*v3[cc4*4+1];
        o.z = a0*v0[cc4*4+2] + a1*v1[cc4*4+2] + a2*v2[cc4*4+2] + a3*v3[cc4*4+2];
        o.w = a0*v0[cc4*4+3] + a1*v1[cc4*4+3] + a2*v2[cc4*4+3] + a3*v3[cc4*4+3];
        *(float4*)(out + (size_t)n * 256 + tq * 64 + h * 16 + cc4 * 4) = o;
    }
}

// ---------------- launcher ----------------
extern "C" void kernel_launch(void* const* d_in, const int* in_sizes, int n_in,
                              void* d_out, int out_size, void* d_ws, size_t ws_size,
                              hipStream_t stream) {
    const float* x     = (const float*)d_in[0];
    const int* ei      = (const int*)d_in[1];
    const float* Wsrc  = (const float*)d_in[2];
    const float* Wdst  = (const float*)d_in[3];
    const float* att_src = (const float*)d_in[4];
    const float* att_dst = (const float*)d_in[5];
    const float* raW1  = (const float*)d_in[6];
    const float* rab1  = (const float*)d_in[7];
    const float* raW2  = (const float*)d_in[8];
    const float* Wih   = (const float*)d_in[9];
    const float* Whh   = (const float*)d_in[10];
    const float* bih   = (const float*)d_in[11];
    const float* bhh   = (const float*)d_in[12];
    const float* pos   = (const float*)d_in[13];
    const float* Wq    = (const float*)d_in[14];
    const float* Wk    = (const float*)d_in[15];
    const float* Wv    = (const float*)d_in[16];
    float* out = (float*)d_out;

    char* w = (char*)d_ws;
    size_t off = 0;
    auto alloc = [&](size_t bytes) -> char* {
        char* pp = w + off; off += (bytes + 255) & ~(size_t)255; return pp;
    };
    // ---- long-lived ----
    u16*   intra     = (u16*)  alloc((size_t)T_ * N_ * R_ * 64 * 2);
    float* svals     = (float*)alloc((size_t)T_ * N_ * R_ * 4);
    float* ssum      = (float*)alloc(256);
    float* beta      = (float*)alloc(256);
    float* wd        = (float*)alloc(2 * 64 * 4 * 4);
    float* biasv     = (float*)alloc(256 * 4);
    u16*   Wsrc_pad  = (u16*)  alloc(2 * BPAD * 2);
    u16*   raW1_pad  = (u16*)  alloc(BPAD * 2);
    u16*   Wc_pad    = (u16*)  alloc(2 * BPAD * 2);
    u16*   qkv_pad   = (u16*)  alloc(192 * 72 * 2);
    int*   chunktot  = (int*)  alloc(P_ * NB_ * 4);
    int*   chunkbase = (int*)  alloc(P_ * NB_ * 4);
    // ---- union region ----
    char*  ubase   = alloc(0);
    size_t uoff = 0;
    auto ualloc = [&](size_t bytes) -> char* {
        char* pp = ubase + uoff; uoff += (bytes + 255) & ~(size_t)255; return pp;
    };
    int*   offsets = (int*)  ualloc((size_t)P_ * (N_ + 1) * 4);
    u16*   csr     = (u16*)  ualloc((size_t)P_ * E_ * 2);
    float* als_all = (float*)ualloc((size_t)P_ * N_ * 4 * 4);
    float* ald_all = (float*)ualloc((size_t)P_ * N_ * 4 * 4);
    u16*   partial = (u16*)  ualloc((size_t)P_ * NB_ * N_ * 2);
    u16*   hs_t    = (u16*)  ualloc((size_t)R_ * N_ * G_ * 2);
    u16*   rank    = (u16*)  hs_t;   // overlay: rank dead before first k_proj
    // phase 2 overlay (phase-1 sub-buffers dead after the k_agg loop)
    float* cbuf    = (float*)(ubase);
    u16*   hbuf_bf = (u16*)  (ubase + 5300000);
    u16*   feats   = (u16*)  (ubase + 8000000);
    (void)ws_size; (void)in_sizes; (void)n_in; (void)out_size;

    k_prep<<<72, 256, 0, stream>>>(Wdst, att_dst, Wih, Whh, bih, bhh, Wsrc, raW1,
                                   Wq, Wk, Wv, wd, biasv, Wsrc_pad, raW1_pad, Wc_pad, qkv_pad);
    k_hist<<<dim3(NB_, 8), 256, 0, stream>>>(ei, rank, partial);
    k_scan1<<<dim3(NB_, 8), 256, 0, stream>>>(partial, offsets, chunktot);
    k_scan2<<<1, 64, 0, stream>>>(chunktot, chunkbase);
    k_scan3<<<dim3(79, 8), 256, 0, stream>>>(offsets, chunkbase);
    k_scatter<<<dim3(1250, 8), 256, 0, stream>>>(ei, offsets, rank, partial, csr);
    k_ald<<<dim3(313, 4), 256, 0, stream>>>(x, wd, ald_all);
    for (int t = 0; t < T_; ++t) {
        k_proj<<<dim3(313, 2), 256, 0, stream>>>(x + (size_t)t * N_ * DIN, Wsrc_pad,
                                                 att_src, hs_t, als_all + (size_t)t * 2 * N_ * 4);
        k_agg<<<dim3(5000, 2), 256, 0, stream>>>(offsets, csr,
                                                 als_all + (size_t)t * 2 * N_ * 4,
                                                 ald_all + (size_t)t * 2 * N_ * 4,
                                                 hs_t, intra, t);
    }
    k_relagg<<<2500, 256, 0, stream>>>(intra, raW1_pad, rab1, raW2, svals);
    k_betasum<<<8, 256, 0, stream>>>(svals, ssum);
    k_betafinal<<<1, 64, 0, stream>>>(ssum, beta);
    hipMemsetAsync(cbuf, 0, (size_t)N_ * 64 * 4, stream);
    hipMemsetAsync(hbuf_bf, 0, (size_t)N_ * 64 * 2, stream);
    for (int t = 0; t < T_; ++t)
        k_lstm<<<313, 256, 0, stream>>>(intra, beta, Wc_pad, biasv, cbuf, hbuf_bf, feats, t);
    k_attn<<<1250, 256, 0, stream>>>(feats, pos, qkv_pad, out);
}

// Round 8
// 591.259 us; speedup vs baseline: 2.0462x; 1.0192x over previous
//
#include <hip/hip_runtime.h>
#include <hip/hip_bf16.h>

#define T_ 4
#define N_ 20000
#define E_ 320000
#define R_ 2
#define DIN 64
#define G_ 256   // H*Dh
#define P_ 8     // T*R
#define BPAD 18432  // 256 * 72 padded B-table halves per 64-k chunk
#define NB_ 32      // CSR-build blocks per p
#define EPB_ 10000  // edges per CSR-build block
#define CHN_ 625    // nodes per scan chunk (N_/32)

typedef unsigned short u16;
typedef __attribute__((ext_vector_type(8))) short bf16x8;
typedef __attribute__((ext_vector_type(4))) float f32x4;

__device__ __forceinline__ float bf2f(u16 u) {
    unsigned int i = ((unsigned int)u) << 16; float f;
    __builtin_memcpy(&f, &i, 4); return f;
}
__device__ __forceinline__ u16 f2bf(float f) {
    unsigned int i; __builtin_memcpy(&i, &f, 4);
    unsigned int r = i + 0x7fffu + ((i >> 16) & 1u);
    return (u16)(r >> 16);
}
__device__ __forceinline__ float sigm(float x) { return 1.f / (1.f + __expf(-x)); }

// ---------------- LDS-free MFMA GEMM core (bf16 A) ----------------
__device__ __forceinline__ void gemm_direct(
    const u16* __restrict__ A, const u16* __restrict__ Bpad,
    int M, int Astride, int kchunks, int m0, f32x4* acc)
{
    const int tid = threadIdx.x;
    const int lane = tid & 63, wv = tid >> 6;
    const int col = lane & 15, quad = lane >> 4;
    #pragma unroll
    for (int cf = 0; cf < 16; ++cf) { acc[cf][0]=0.f; acc[cf][1]=0.f; acc[cf][2]=0.f; acc[cf][3]=0.f; }

    int row = m0 + wv * 16 + col;
    int row_c = (row < M) ? row : (M - 1);

    for (int kc = 0; kc < kchunks; ++kc) {
        #pragma unroll
        for (int ks = 0; ks < 2; ++ks) {
            bf16x8 a = *(const bf16x8*)(A + (size_t)row_c * Astride + kc * 64 + ks * 32 + quad * 8);
            const u16* bb = Bpad + kc * BPAD + ks * 32 + quad * 8;
            #pragma unroll
            for (int cf = 0; cf < 16; ++cf) {
                bf16x8 b = *(const bf16x8*)(bb + (cf * 16 + col) * 72);
                acc[cf] = __builtin_amdgcn_mfma_f32_16x16x32_bf16(a, b, acc[cf], 0, 0, 0);
            }
        }
    }
}

// ---------------- fold: als/ald GEMVs + x->bf16 cast, 4 lanes per node ----------------
// wdall: [0]=als_r0 [256]=als_r1 [512]=ald_r0 [768]=ald_r1, each [k*4+h]
__global__ __launch_bounds__(256) void k_fold(
    const float* __restrict__ x, const float* __restrict__ wdall,
    float* __restrict__ als_all, float* __restrict__ ald_all, u16* __restrict__ x_bf)
{
    int t = blockIdx.y;
    int idx = blockIdx.x * 256 + threadIdx.x;
    if (idx >= N_ * 4) return;
    int n = idx >> 2, q = idx & 3;
    const float* xr = x + ((size_t)t * N_ + n) * 64 + q * 16;
    float4 xv[4];
    #pragma unroll
    for (int i = 0; i < 4; ++i) xv[i] = *(const float4*)(xr + i * 4);

    // x_bf write (16 halves per lane)
    {
        union { u16 h[16]; ushort4 s4[4]; } cv;
        #pragma unroll
        for (int i = 0; i < 4; ++i) {
            cv.h[i*4+0] = f2bf(xv[i].x); cv.h[i*4+1] = f2bf(xv[i].y);
            cv.h[i*4+2] = f2bf(xv[i].z); cv.h[i*4+3] = f2bf(xv[i].w);
        }
        u16* xo = x_bf + ((size_t)t * N_ + n) * 64 + q * 16;
        #pragma unroll
        for (int i = 0; i < 4; ++i) *(ushort4*)(xo + i * 4) = cv.s4[i];
    }

    float s[16];
    #pragma unroll
    for (int i = 0; i < 16; ++i) s[i] = 0.f;
    #pragma unroll
    for (int i = 0; i < 4; ++i) {
        float xe[4] = {xv[i].x, xv[i].y, xv[i].z, xv[i].w};
        #pragma unroll
        for (int e = 0; e < 4; ++e) {
            int k = q * 16 + i * 4 + e;
            float xk = xe[e];
            #pragma unroll
            for (int tb = 0; tb < 4; ++tb) {
                float4 w = *(const float4*)(wdall + tb * 256 + k * 4);
                s[tb*4+0] += xk * w.x; s[tb*4+1] += xk * w.y;
                s[tb*4+2] += xk * w.z; s[tb*4+3] += xk * w.w;
            }
        }
    }
    #pragma unroll
    for (int i = 0; i < 16; ++i) {
        s[i] += __shfl_xor(s[i], 1);
        s[i] += __shfl_xor(s[i], 2);
    }
    if (q == 0) {
        *(float4*)(als_all + ((size_t)(t*2+0) * N_ + n) * 4) = make_float4(s[0], s[1], s[2], s[3]);
        *(float4*)(als_all + ((size_t)(t*2+1) * N_ + n) * 4) = make_float4(s[4], s[5], s[6], s[7]);
        *(float4*)(ald_all + ((size_t)(t*2+0) * N_ + n) * 4) = make_float4(s[8], s[9], s[10], s[11]);
        *(float4*)(ald_all + ((size_t)(t*2+1) * N_ + n) * 4) = make_float4(s[12], s[13], s[14], s[15]);
    }
}

// ---------------- prep: folded GEMV tables, padded B-tables, folded bias ----------------
__global__ void k_prep(const float* __restrict__ Wdst, const float* __restrict__ att_dst,
                       const float* __restrict__ Wih, const float* __restrict__ Whh,
                       const float* __restrict__ bih, const float* __restrict__ bhh,
                       const float* __restrict__ Wsrc, const float* __restrict__ att_src,
                       const float* __restrict__ raW1,
                       const float* __restrict__ Wq, const float* __restrict__ Wk,
                       const float* __restrict__ Wv,
                       float* __restrict__ wdall, float* __restrict__ biasv,
                       u16* __restrict__ raW1_pad, u16* __restrict__ Wc_pad,
                       u16* __restrict__ qkv_pad, u16* __restrict__ postB_pad)
{
    int tid = threadIdx.x, bid = blockIdx.x;
    if (bid == 0) {
        int k = tid >> 2, h = tid & 3;
        for (int r = 0; r < 2; ++r) {
            float ss = 0.f, sd = 0.f;
            for (int c = 0; c < 64; ++c) {
                ss += Wsrc[((size_t)r * 64 + k) * 256 + h * 64 + c] * att_src[r * 256 + h * 64 + c];
                sd += Wdst[((size_t)r * 64 + k) * 256 + h * 64 + c] * att_dst[r * 256 + h * 64 + c];
            }
            wdall[r * 256 + k * 4 + h] = ss;
            wdall[512 + r * 256 + k * 4 + h] = sd;
        }
        biasv[tid] = bih[tid] + bhh[tid];
    }
    // raW1_pad[n*72+kk] = raW1[kk,n]
    for (int i = bid * 256 + tid; i < BPAD; i += gridDim.x * 256) {
        int n = i / 72, kk = i % 72;
        raW1_pad[i] = (kk < 64) ? f2bf(raW1[kk * 256 + n]) : (u16)0;
    }
    // Wc_pad[kc][n*72+kk] = (kc==0 ? Wih : Whh)[n,kk]
    for (int i = bid * 256 + tid; i < 2 * BPAD; i += gridDim.x * 256) {
        int kc = i / BPAD, q = i % BPAD, n = q / 72, kk = q % 72;
        const float* W = kc ? Whh : Wih;
        Wc_pad[i] = (kk < 64) ? f2bf(W[n * 64 + kk]) : (u16)0;
    }
    // qkv_pad[g*72+kk] = [Wq|Wk|Wv][kk][g]
    for (int i = bid * 256 + tid; i < 192 * 72; i += gridDim.x * 256) {
        int g = i / 72, kk = i % 72;
        int j = g >> 6, c = g & 63;
        const float* W = (j == 0) ? Wq : (j == 1) ? Wk : Wv;
        qkv_pad[i] = (kk < 64) ? f2bf(W[kk * 64 + c]) : (u16)0;
    }
    // postB_pad[r][kc][c*72+kk] = Wsrc[r][kk, kc*64+c]
    for (int i = bid * 256 + tid; i < 2 * 4 * 4608; i += gridDim.x * 256) {
        int r = i / 18432, q = i % 18432, kc = q / 4608, qq = q % 4608;
        int c = qq / 72, kk = qq % 72;
        postB_pad[i] = (kk < 64) ? f2bf(Wsrc[(size_t)r * 16384 + kk * 256 + kc * 64 + c]) : (u16)0;
    }
}

// ---------------- CSR build ----------------
__global__ __launch_bounds__(256) void k_hist(const int* __restrict__ ei,
                                              u16* __restrict__ rank, u16* __restrict__ partial)
{
    __shared__ unsigned int hist[N_ / 2];
    int b = blockIdx.x, p = blockIdx.y, tid = threadIdx.x;
    for (int i = tid; i < N_ / 2; i += 256) hist[i] = 0u;
    __syncthreads();
    const int* dsts = ei + ((size_t)p * 2 + 1) * E_ + b * EPB_;
    u16* rk = rank + (size_t)p * E_ + b * EPB_;
    for (int e = tid; e < EPB_; e += 256) {
        int dst = dsts[e];
        unsigned sh = (unsigned)(dst & 1) * 16u;
        unsigned old = atomicAdd(&hist[dst >> 1], 1u << sh);
        rk[e] = (u16)((old >> sh) & 0xffffu);
    }
    __syncthreads();
    u16* part = partial + ((size_t)p * NB_ + b) * N_;
    for (int n = tid; n < N_; n += 256) {
        unsigned hv = hist[n >> 1];
        part[n] = (u16)((hv >> ((unsigned)(n & 1) * 16u)) & 0xffffu);
    }
}

__global__ __launch_bounds__(256) void k_scan1(u16* __restrict__ partial,
                                               int* __restrict__ offsets, int* __restrict__ chunktot)
{
    int p = blockIdx.y, ch = blockIdx.x;
    int tid = threadIdx.x, lane = tid & 63, wid = tid >> 6;
    __shared__ int wtot[4];
    u16* part = partial + (size_t)p * NB_ * N_;
    int* ofs = offsets + (size_t)p * (N_ + 1);
    int n0 = ch * CHN_;
    int carry = 0;
    for (int rnd = 0; rnd < 3; ++rnd) {
        int i = rnd * 256 + tid;
        int n = n0 + i;
        int v = 0;
        if (i < CHN_) {
            int run = 0;
            #pragma unroll 8
            for (int b = 0; b < NB_; ++b) {
                int pv = part[b * N_ + n];
                part[b * N_ + n] = (u16)run;
                run += pv;
            }
            v = run;
        }
        int incl = v;
        for (int d = 1; d < 64; d <<= 1) { int u = __shfl_up(incl, d); if (lane >= d) incl += u; }
        if (lane == 63) wtot[wid] = incl;
        __syncthreads();
        if (tid < 4) {
            int iv = wtot[tid];
            for (int d = 1; d < 4; d <<= 1) { int u = __shfl_up(iv, d); if (tid >= d) iv += u; }
            wtot[tid] = iv;
        }
        __syncthreads();
        int woff = (wid > 0) ? wtot[wid - 1] : 0;
        int tot = wtot[3];
        int excl = carry + woff + incl - v;
        if (i < CHN_) ofs[n] = excl;
        carry += tot;
        __syncthreads();
    }
    if (tid == 0) chunktot[p * NB_ + ch] = carry;
}

__global__ void k_scan2(const int* __restrict__ chunktot, int* __restrict__ chunkbase) {
    int tid = threadIdx.x;
    if (tid < P_) {
        int run = 0;
        for (int c = 0; c < NB_; ++c) {
            chunkbase[tid * NB_ + c] = run;
            run += chunktot[tid * NB_ + c];
        }
    }
}

__global__ void k_scan3(int* __restrict__ offsets, const int* __restrict__ chunkbase) {
    int p = blockIdx.y;
    int n = blockIdx.x * 256 + threadIdx.x;
    if (n < N_)
        offsets[(size_t)p * (N_ + 1) + n] += chunkbase[p * NB_ + n / CHN_];
    if (n == 0)
        offsets[(size_t)p * (N_ + 1) + N_] = E_;
}

__global__ void k_scatter(const int* __restrict__ ei, const int* __restrict__ offsets,
                          const u16* __restrict__ rank, const u16* __restrict__ partial,
                          u16* __restrict__ csr) {
    int p = blockIdx.y;
    int e = blockIdx.x * 256 + threadIdx.x;
    if (e >= E_) return;
    int src = ei[((size_t)p * 2 + 0) * E_ + e];
    int dst = ei[((size_t)p * 2 + 1) * E_ + e];
    int b = e / EPB_;
    int pos = offsets[p * (N_ + 1) + dst]
            + (int)partial[((size_t)p * NB_ + b) * N_ + dst]
            + (int)rank[(size_t)p * E_ + e];
    csr[(size_t)p * E_ + pos] = (u16)src;
}

// ---------------- GAT aggregation over x (projection commuted out) ----------------
// Wave per dst node. Load phase: lane (h', j) computes pv for (edge j, head h').
// Accum phase: lane (h, c4) sums pv_h * x_bf[s, c4..c4+3].
#define AGG_BODY(J)                                                              \
    {   int s = __shfl(sv, (J));                                                 \
        float pj = __shfl(pv, base48 + (J));                                     \
        ushort4 xv = *(const ushort4*)(xb + (size_t)s * 64 + c4);                \
        a0 += pj * bf2f(xv.x); a1 += pj * bf2f(xv.y);                            \
        a2 += pj * bf2f(xv.z); a3 += pj * bf2f(xv.w); }

__global__ __launch_bounds__(256) void k_agg(
    const int* __restrict__ offsets, const u16* __restrict__ csr,
    const float* __restrict__ als_t, const float* __restrict__ ald_t,
    const u16* __restrict__ xb, u16* __restrict__ xagg, int t)
{
    int r = blockIdx.y;
    const int* off = offsets + (size_t)(t * 2 + r) * (N_ + 1);
    const u16* srcs = csr + (size_t)(t * 2 + r) * E_;
    const float* als = als_t + (size_t)r * N_ * 4;
    const float* ald = ald_t + (size_t)r * N_ * 4;

    int tid = threadIdx.x, lane = tid & 63, wv = tid >> 6;
    int n = blockIdx.x * 4 + wv;
    int h = lane >> 4, j16 = lane & 15, c4 = j16 * 4;
    int base48 = lane & 48;
    int o0 = off[n], o1 = off[n + 1];
    float aldv = ald[(size_t)n * 4 + h];

    float den = 0.f, a0 = 0.f, a1 = 0.f, a2 = 0.f, a3 = 0.f;
    for (int base = o0; base < o1; base += 16) {
        int idx = base + j16;
        int sv = 0; float pv = 0.f;
        if (idx < o1) {
            sv = (int)srcs[idx];
            float e = als[sv * 4 + h] + aldv;
            e = (e > 0.f) ? e : 0.2f * e;
            pv = __expf(e);
        }
        den += pv;
        int cnt = o1 - base;
        if (cnt >= 16) {
            #pragma unroll
            for (int j = 0; j < 16; ++j) AGG_BODY(j)
        } else {
            for (int j = 0; j < cnt; ++j) AGG_BODY(j)
        }
    }
    den += __shfl_xor(den, 1); den += __shfl_xor(den, 2);
    den += __shfl_xor(den, 4); den += __shfl_xor(den, 8);
    float sc = 0.25f / (den + 1e-16f);
    ushort4 ov;
    ov.x = f2bf(a0 * sc); ov.y = f2bf(a1 * sc);
    ov.z = f2bf(a2 * sc); ov.w = f2bf(a3 * sc);
    *(ushort4*)(xagg + ((size_t)r * N_ + n) * 256 + h * 64 + c4) = ov;
}

// ---------------- post-projection: intra = xagg @ B~  ([N,256]@[256,64]) ----------------
__global__ __launch_bounds__(256) void k_post(
    const u16* __restrict__ xagg, const u16* __restrict__ postB_pad,
    u16* __restrict__ intra, int t)
{
    int r = blockIdx.y;
    const u16* A = xagg + (size_t)r * N_ * 256;
    const u16* Bp = postB_pad + (size_t)r * 4 * 4608;
    const int tid = threadIdx.x, lane = tid & 63, wv = tid >> 6;
    const int col = lane & 15, quad = lane >> 4;
    int m0 = blockIdx.x * 64;
    int row = m0 + wv * 16 + col;
    int row_c = (row < N_) ? row : (N_ - 1);

    f32x4 acc[4];
    #pragma unroll
    for (int cf = 0; cf < 4; ++cf) { acc[cf][0]=0.f; acc[cf][1]=0.f; acc[cf][2]=0.f; acc[cf][3]=0.f; }
    #pragma unroll
    for (int kc = 0; kc < 4; ++kc) {
        #pragma unroll
        for (int ks = 0; ks < 2; ++ks) {
            bf16x8 a = *(const bf16x8*)(A + (size_t)row_c * 256 + kc * 64 + ks * 32 + quad * 8);
            const u16* bb = Bp + kc * 4608 + ks * 32 + quad * 8;
            #pragma unroll
            for (int cf = 0; cf < 4; ++cf) {
                bf16x8 b = *(const bf16x8*)(bb + (cf * 16 + col) * 72);
                acc[cf] = __builtin_amdgcn_mfma_f32_16x16x32_bf16(a, b, acc[cf], 0, 0, 0);
            }
        }
    }
    int rowbase = m0 + wv * 16 + quad * 4;
    #pragma unroll
    for (int cf = 0; cf < 4; ++cf) {
        int c = cf * 16 + col;
        #pragma unroll
        for (int reg = 0; reg < 4; ++reg) {
            int rr = rowbase + reg;
            if (rr < N_)
                intra[(((size_t)t * N_ + rr) * 2 + r) * 64 + c] = f2bf(acc[cf][reg]);
        }
    }
}

// ---------------- RelationAgg GEMM with fused tanh(.)@W2 epilogue ----------------
__global__ __launch_bounds__(256) void k_relagg(
    const u16* __restrict__ A, const u16* __restrict__ W1pad, const float* __restrict__ b1,
    const float* __restrict__ W2, float* __restrict__ svals)
{
    int m0 = blockIdx.x * 64;
    f32x4 acc[16];
    gemm_direct(A, W1pad, T_ * N_ * R_, 64, 1, m0, acc);

    const int tid = threadIdx.x, lane = tid & 63, wv = tid >> 6;
    const int col = lane & 15, quad = lane >> 4;
    int rowbase = m0 + wv * 16 + quad * 4;
    float sp[4] = {0.f, 0.f, 0.f, 0.f};
    #pragma unroll
    for (int cf = 0; cf < 16; ++cf) {
        int gcol = cf * 16 + col;
        float bb = b1[gcol];
        float ww = W2[gcol];
        #pragma unroll
        for (int reg = 0; reg < 4; ++reg)
            sp[reg] += tanhf(acc[cf][reg] + bb) * ww;
    }
    #pragma unroll
    for (int reg = 0; reg < 4; ++reg) {
        float v = sp[reg];
        v += __shfl_xor(v, 1); v += __shfl_xor(v, 2);
        v += __shfl_xor(v, 4); v += __shfl_xor(v, 8);
        sp[reg] = v;
    }
    if (col == 0) {
        #pragma unroll
        for (int reg = 0; reg < 4; ++reg) {
            int row = rowbase + reg;
            if (row < T_ * N_ * R_) svals[row] = sp[reg];
        }
    }
}

__global__ void k_betasum(const float* __restrict__ svals, float* __restrict__ ssum) {
    int p = blockIdx.x, t = p >> 1, r = p & 1;
    __shared__ float red[256];
    float s = 0.f;
    for (int n = threadIdx.x; n < N_; n += 256)
        s += svals[((size_t)t * N_ + n) * 2 + r];
    red[threadIdx.x] = s;
    __syncthreads();
    for (int st = 128; st > 0; st >>= 1) {
        if (threadIdx.x < st) red[threadIdx.x] += red[threadIdx.x + st];
        __syncthreads();
    }
    if (threadIdx.x == 0) ssum[p] = red[0];
}

__global__ void k_betafinal(const float* __restrict__ ssum, float* __restrict__ beta) {
    int t = threadIdx.x;
    if (t >= 4) return;
    float s0 = ssum[t * 2] * (1.f / N_), s1 = ssum[t * 2 + 1] * (1.f / N_);
    float mx = fmaxf(s0, s1);
    float e0 = __expf(s0 - mx), e1 = __expf(s1 - mx);
    float inv = 1.f / (e0 + e1);
    beta[t * 2] = e0 * inv; beta[t * 2 + 1] = e1 * inv;
}

// ---------------- LSTM GEMM (A assembled on the fly) + fused cell update ----------------
__global__ __launch_bounds__(256) void k_lstm(
    const u16* __restrict__ intra, const float* __restrict__ beta,
    const u16* __restrict__ Wc_pad, const float* __restrict__ biasv,
    float* __restrict__ cbuf, u16* __restrict__ hbuf_bf, u16* __restrict__ feats, int t)
{
    const int tid = threadIdx.x, lane = tid & 63, wv = tid >> 6;
    const int col = lane & 15, quad = lane >> 4;
    int m0 = blockIdx.x * 64;
    int row = m0 + wv * 16 + col;
    int row_c = (row < N_) ? row : (N_ - 1);
    float b0 = beta[t * 2], b1 = beta[t * 2 + 1];
    const u16* ib = intra + ((size_t)t * N_ + row_c) * 128;

    f32x4 acc[16];
    #pragma unroll
    for (int cf = 0; cf < 16; ++cf) { acc[cf][0]=0.f; acc[cf][1]=0.f; acc[cf][2]=0.f; acc[cf][3]=0.f; }

    #pragma unroll
    for (int kc = 0; kc < 2; ++kc) {
        #pragma unroll
        for (int ks = 0; ks < 2; ++ks) {
            bf16x8 a;
            if (kc == 0) {
                int coff = ks * 32 + quad * 8;
                bf16x8 i0 = *(const bf16x8*)(ib + coff);
                bf16x8 i1 = *(const bf16x8*)(ib + 64 + coff);
                union { u16 h[8]; bf16x8 v; } cv;
                #pragma unroll
                for (int j = 0; j < 8; ++j)
                    cv.h[j] = f2bf(b0 * bf2f((u16)i0[j]) + b1 * bf2f((u16)i1[j]));
                a = cv.v;
            } else {
                a = *(const bf16x8*)(hbuf_bf + (size_t)row_c * 64 + ks * 32 + quad * 8);
            }
            const u16* bb = Wc_pad + kc * BPAD + ks * 32 + quad * 8;
            #pragma unroll
            for (int cf = 0; cf < 16; ++cf) {
                bf16x8 b = *(const bf16x8*)(bb + (cf * 16 + col) * 72);
                acc[cf] = __builtin_amdgcn_mfma_f32_16x16x32_bf16(a, b, acc[cf], 0, 0, 0);
            }
        }
    }

    int rowbase = m0 + wv * 16 + quad * 4;
    #pragma unroll
    for (int j = 0; j < 4; ++j) {
        int c = j * 16 + col;
        float bi = biasv[c], bf_ = biasv[64 + c], bg = biasv[128 + c], bo = biasv[192 + c];
        #pragma unroll
        for (int reg = 0; reg < 4; ++reg) {
            int rr = rowbase + reg;
            if (rr < N_) {
                float gi = acc[j][reg] + bi;
                float gf = acc[j + 4][reg] + bf_;
                float gg = acc[j + 8][reg] + bg;
                float go = acc[j + 12][reg] + bo;
                float cc = cbuf[(size_t)rr * 64 + c];
                cc = sigm(gf) * cc + sigm(gi) * tanhf(gg);
                float hh = sigm(go) * tanhf(cc);
                cbuf[(size_t)rr * 64 + c] = cc;
                hbuf_bf[(size_t)rr * 64 + c] = f2bf(hh);
                feats[(size_t)rr * 256 + t * 64 + c] = f2bf(hh);
            }
        }
    }
}

// ---------------- temporal causal MHA: MFMA QKV + per-lane attention ----------------
__global__ __launch_bounds__(256) void k_attn(
    const u16* __restrict__ feats, const float* __restrict__ pos_emb,
    const u16* __restrict__ qkv_pad, float* __restrict__ out)
{
    __shared__ float qkv_s[64 * 200];
    const int tid = threadIdx.x, lane = tid & 63, wv = tid >> 6;
    const int col = lane & 15, quad = lane >> 4;
    int m0 = blockIdx.x * 64;
    int row = m0 + wv * 16 + col;
    int trow = row & 3;

    f32x4 acc[12];
    #pragma unroll
    for (int cf = 0; cf < 12; ++cf) { acc[cf][0]=0.f; acc[cf][1]=0.f; acc[cf][2]=0.f; acc[cf][3]=0.f; }
    #pragma unroll
    for (int ks = 0; ks < 2; ++ks) {
        int coff = ks * 32 + quad * 8;
        bf16x8 fv = *(const bf16x8*)(feats + (size_t)row * 64 + coff);
        float4 p0 = *(const float4*)(pos_emb + trow * 64 + coff);
        float4 p1 = *(const float4*)(pos_emb + trow * 64 + coff + 4);
        union { u16 h[8]; bf16x8 v; } cv;
        cv.h[0] = f2bf(bf2f((u16)fv[0]) + p0.x); cv.h[1] = f2bf(bf2f((u16)fv[1]) + p0.y);
        cv.h[2] = f2bf(bf2f((u16)fv[2]) + p0.z); cv.h[3] = f2bf(bf2f((u16)fv[3]) + p0.w);
        cv.h[4] = f2bf(bf2f((u16)fv[4]) + p1.x); cv.h[5] = f2bf(bf2f((u16)fv[5]) + p1.y);
        cv.h[6] = f2bf(bf2f((u16)fv[6]) + p1.z); cv.h[7] = f2bf(bf2f((u16)fv[7]) + p1.w);
        bf16x8 a = cv.v;
        const u16* bb = qkv_pad + ks * 32 + quad * 8;
        #pragma unroll
        for (int cf = 0; cf < 12; ++cf) {
            bf16x8 b = *(const bf16x8*)(bb + (cf * 16 + col) * 72);
            acc[cf] = __builtin_amdgcn_mfma_f32_16x16x32_bf16(a, b, acc[cf], 0, 0, 0);
        }
    }
    #pragma unroll
    for (int cf = 0; cf < 12; ++cf) {
        int g = cf * 16 + col;
        #pragma unroll
        for (int reg = 0; reg < 4; ++reg) {
            int rl = wv * 16 + quad * 4 + reg;
            qkv_s[rl * 200 + g] = acc[cf][reg];
        }
    }
    __syncthreads();

    int nl = wv * 4 + (lane >> 4);
    int sub = lane & 15;
    int h = sub >> 2, tq = sub & 3;
    const float* qrow = qkv_s + (nl * 4 + tq) * 200 + h * 16;

    float s[4];
    #pragma unroll
    for (int tk = 0; tk < 4; ++tk) {
        const float* krow = qkv_s + (nl * 4 + tk) * 200 + 64 + h * 16;
        float d = 0.f;
        #pragma unroll
        for (int j = 0; j < 16; ++j) d += qrow[j] * krow[j];
        s[tk] = (tk > tq) ? -4294967295.0f : d * 0.5f;
    }
    float mx = fmaxf(fmaxf(s[0], s[1]), fmaxf(s[2], s[3]));
    float a0 = __expf(s[0]-mx), a1 = __expf(s[1]-mx), a2 = __expf(s[2]-mx), a3 = __expf(s[3]-mx);
    float inv = 1.f / (a0 + a1 + a2 + a3);
    a0 *= inv; a1 *= inv; a2 *= inv; a3 *= inv;

    int n = blockIdx.x * 16 + nl;
    const float* v0 = qkv_s + (nl * 4 + 0) * 200 + 128 + h * 16;
    const float* v1 = v0 + 200, *v2 = v0 + 400, *v3 = v0 + 600;
    #pragma unroll
    for (int cc4 = 0; cc4 < 4; ++cc4) {
        float4 o;
        o.x = a0*v0[cc4*4+0] + a1*v1[cc4*4+0] + a2*v2[cc4*4+0] + a3*v3[cc4*4+0];
        o.y = a0*v0[cc4*4+1] + a1*v1[cc4*4+1] + a2*v2[cc4*4+1] + a3*v3[cc4*4+1];
        o.z = a0*v0[cc4*4+2] + a1*v1[cc4*4+2] + a2*v2[cc4*4+2] + a3*v3[cc4*4+2];
        o.w = a0*v0[cc4*4+3] + a1*v1[cc4*4+3] + a2*v2[cc4*4+3] + a3*v3[cc4*4+3];
        *(float4*)(out + (size_t)n * 256 + tq * 64 + h * 16 + cc4 * 4) = o;
    }
}

// ---------------- launcher ----------------
extern "C" void kernel_launch(void* const* d_in, const int* in_sizes, int n_in,
                              void* d_out, int out_size, void* d_ws, size_t ws_size,
                              hipStream_t stream) {
    const float* x     = (const float*)d_in[0];
    const int* ei      = (const int*)d_in[1];
    const float* Wsrc  = (const float*)d_in[2];
    const float* Wdst  = (const float*)d_in[3];
    const float* att_src = (const float*)d_in[4];
    const float* att_dst = (const float*)d_in[5];
    const float* raW1  = (const float*)d_in[6];
    const float* rab1  = (const float*)d_in[7];
    const float* raW2  = (const float*)d_in[8];
    const float* Wih   = (const float*)d_in[9];
    const float* Whh   = (const float*)d_in[10];
    const float* bih   = (const float*)d_in[11];
    const float* bhh   = (const float*)d_in[12];
    const float* pos   = (const float*)d_in[13];
    const float* Wq    = (const float*)d_in[14];
    const float* Wk    = (const float*)d_in[15];
    const float* Wv    = (const float*)d_in[16];
    float* out = (float*)d_out;

    char* w = (char*)d_ws;
    size_t off = 0;
    auto alloc = [&](size_t bytes) -> char* {
        char* pp = w + off; off += (bytes + 255) & ~(size_t)255; return pp;
    };
    // ---- long-lived ----
    u16*   intra     = (u16*)  alloc((size_t)T_ * N_ * R_ * 64 * 2);  // 20.48 MB
    u16*   x_bf      = (u16*)  alloc((size_t)T_ * N_ * 64 * 2);       // 10.24 MB
    float* svals     = (float*)alloc((size_t)T_ * N_ * R_ * 4);
    float* ssum      = (float*)alloc(256);
    float* beta      = (float*)alloc(256);
    float* wdall     = (float*)alloc(1024 * 4);
    float* biasv     = (float*)alloc(256 * 4);
    u16*   raW1_pad  = (u16*)  alloc(BPAD * 2);
    u16*   Wc_pad    = (u16*)  alloc(2 * BPAD * 2);
    u16*   qkv_pad   = (u16*)  alloc(192 * 72 * 2);
    u16*   postB_pad = (u16*)  alloc(2 * 4 * 4608 * 2);
    int*   chunktot  = (int*)  alloc(P_ * NB_ * 4);
    int*   chunkbase = (int*)  alloc(P_ * NB_ * 4);
    // ---- union region ----
    char*  ubase   = alloc(0);
    size_t uoff = 0;
    auto ualloc = [&](size_t bytes) -> char* {
        char* pp = ubase + uoff; uoff += (bytes + 255) & ~(size_t)255; return pp;
    };
    int*   offsets = (int*)  ualloc((size_t)P_ * (N_ + 1) * 4);
    u16*   csr     = (u16*)  ualloc((size_t)P_ * E_ * 2);
    float* als_all = (float*)ualloc((size_t)P_ * N_ * 4 * 4);
    float* ald_all = (float*)ualloc((size_t)P_ * N_ * 4 * 4);
    u16*   partial = (u16*)  ualloc((size_t)P_ * NB_ * N_ * 2);
    u16*   xagg    = (u16*)  ualloc((size_t)R_ * N_ * 256 * 2);   // 20.48 MB
    u16*   rank    = (u16*)  xagg;   // overlay: rank dead before first k_agg
    // phase 2 overlay (phase-1 sub-buffers dead after the k_agg loop)
    float* cbuf    = (float*)(ubase);
    u16*   hbuf_bf = (u16*)  (ubase + 5300000);
    u16*   feats   = (u16*)  (ubase + 8000000);
    (void)ws_size; (void)in_sizes; (void)n_in; (void)out_size;

    k_prep<<<72, 256, 0, stream>>>(Wdst, att_dst, Wih, Whh, bih, bhh, Wsrc, att_src, raW1,
                                   Wq, Wk, Wv, wdall, biasv, raW1_pad, Wc_pad, qkv_pad, postB_pad);
    k_hist<<<dim3(NB_, 8), 256, 0, stream>>>(ei, rank, partial);
    k_scan1<<<dim3(NB_, 8), 256, 0, stream>>>(partial, offsets, chunktot);
    k_scan2<<<1, 64, 0, stream>>>(chunktot, chunkbase);
    k_scan3<<<dim3(79, 8), 256, 0, stream>>>(offsets, chunkbase);
    k_scatter<<<dim3(1250, 8), 256, 0, stream>>>(ei, offsets, rank, partial, csr);
    k_fold<<<dim3(313, 4), 256, 0, stream>>>(x, wdall, als_all, ald_all, x_bf);
    for (int t = 0; t < T_; ++t) {
        k_agg<<<dim3(5000, 2), 256, 0, stream>>>(offsets, csr,
                                                 als_all + (size_t)t * 2 * N_ * 4,
                                                 ald_all + (size_t)t * 2 * N_ * 4,
                                                 x_bf + (size_t)t * N_ * 64, xagg, t);
        k_post<<<dim3(313, 2), 256, 0, stream>>>(xagg, postB_pad, intra, t);
    }
    k_relagg<<<2500, 256, 0, stream>>>(intra, raW1_pad, rab1, raW2, svals);
    k_betasum<<<8, 256, 0, stream>>>(svals, ssum);
    k_betafinal<<<1, 64, 0, stream>>>(ssum, beta);
    hipMemsetAsync(cbuf, 0, (size_t)N_ * 64 * 4, stream);
    hipMemsetAsync(hbuf_bf, 0, (size_t)N_ * 64 * 2, stream);
    for (int t = 0; t < T_; ++t)
        k_lstm<<<313, 256, 0, stream>>>(intra, beta, Wc_pad, biasv, cbuf, hbuf_bf, feats, t);
    k_attn<<<1250, 256, 0, stream>>>(feats, pos, qkv_pad, out);
}

// Round 9
// 576.868 us; speedup vs baseline: 2.0972x; 1.0249x over previous
//
#include <hip/hip_runtime.h>
#include <hip/hip_bf16.h>

#define T_ 4
#define N_ 20000
#define E_ 320000
#define R_ 2
#define DIN 64
#define G_ 256   // H*Dh
#define P_ 8     // T*R
#define BPAD 18432  // 256 * 72 padded B-table halves per 64-k chunk
#define NB_ 32      // CSR-build blocks per p
#define EPB_ 10000  // edges per CSR-build block
#define CHN_ 625    // nodes per scan chunk (N_/32)

typedef unsigned short u16;
typedef __attribute__((ext_vector_type(8))) short bf16x8;
typedef __attribute__((ext_vector_type(4))) float f32x4;

__device__ __forceinline__ float bf2f(u16 u) {
    unsigned int i = ((unsigned int)u) << 16; float f;
    __builtin_memcpy(&f, &i, 4); return f;
}
__device__ __forceinline__ u16 f2bf(float f) {
    unsigned int i; __builtin_memcpy(&i, &f, 4);
    unsigned int r = i + 0x7fffu + ((i >> 16) & 1u);
    return (u16)(r >> 16);
}
__device__ __forceinline__ float sigm(float x) { return 1.f / (1.f + __expf(-x)); }
// fast tanh: 1 - 2/(exp(2x)+1); hardware v_exp_f32, correct saturation at +-inf
__device__ __forceinline__ float ftanh(float x) { return 1.f - 2.f / (__expf(2.f * x) + 1.f); }

// ---------------- LDS-free MFMA GEMM core (bf16 A) ----------------
__device__ __forceinline__ void gemm_direct(
    const u16* __restrict__ A, const u16* __restrict__ Bpad,
    int M, int Astride, int kchunks, int m0, f32x4* acc)
{
    const int tid = threadIdx.x;
    const int lane = tid & 63, wv = tid >> 6;
    const int col = lane & 15, quad = lane >> 4;
    #pragma unroll
    for (int cf = 0; cf < 16; ++cf) { acc[cf][0]=0.f; acc[cf][1]=0.f; acc[cf][2]=0.f; acc[cf][3]=0.f; }

    int row = m0 + wv * 16 + col;
    int row_c = (row < M) ? row : (M - 1);

    for (int kc = 0; kc < kchunks; ++kc) {
        #pragma unroll
        for (int ks = 0; ks < 2; ++ks) {
            bf16x8 a = *(const bf16x8*)(A + (size_t)row_c * Astride + kc * 64 + ks * 32 + quad * 8);
            const u16* bb = Bpad + kc * BPAD + ks * 32 + quad * 8;
            #pragma unroll
            for (int cf = 0; cf < 16; ++cf) {
                bf16x8 b = *(const bf16x8*)(bb + (cf * 16 + col) * 72);
                acc[cf] = __builtin_amdgcn_mfma_f32_16x16x32_bf16(a, b, acc[cf], 0, 0, 0);
            }
        }
    }
}

// ---------------- fold: als/ald GEMVs + x->bf16 cast, 4 lanes per node ----------------
__global__ __launch_bounds__(256) void k_fold(
    const float* __restrict__ x, const float* __restrict__ wdall,
    float* __restrict__ als_all, float* __restrict__ ald_all, u16* __restrict__ x_bf)
{
    int t = blockIdx.y;
    int idx = blockIdx.x * 256 + threadIdx.x;
    if (idx >= N_ * 4) return;
    int n = idx >> 2, q = idx & 3;
    const float* xr = x + ((size_t)t * N_ + n) * 64 + q * 16;
    float4 xv[4];
    #pragma unroll
    for (int i = 0; i < 4; ++i) xv[i] = *(const float4*)(xr + i * 4);

    {
        union { u16 h[16]; ushort4 s4[4]; } cv;
        #pragma unroll
        for (int i = 0; i < 4; ++i) {
            cv.h[i*4+0] = f2bf(xv[i].x); cv.h[i*4+1] = f2bf(xv[i].y);
            cv.h[i*4+2] = f2bf(xv[i].z); cv.h[i*4+3] = f2bf(xv[i].w);
        }
        u16* xo = x_bf + ((size_t)t * N_ + n) * 64 + q * 16;
        #pragma unroll
        for (int i = 0; i < 4; ++i) *(ushort4*)(xo + i * 4) = cv.s4[i];
    }

    float s[16];
    #pragma unroll
    for (int i = 0; i < 16; ++i) s[i] = 0.f;
    #pragma unroll
    for (int i = 0; i < 4; ++i) {
        float xe[4] = {xv[i].x, xv[i].y, xv[i].z, xv[i].w};
        #pragma unroll
        for (int e = 0; e < 4; ++e) {
            int k = q * 16 + i * 4 + e;
            float xk = xe[e];
            #pragma unroll
            for (int tb = 0; tb < 4; ++tb) {
                float4 w = *(const float4*)(wdall + tb * 256 + k * 4);
                s[tb*4+0] += xk * w.x; s[tb*4+1] += xk * w.y;
                s[tb*4+2] += xk * w.z; s[tb*4+3] += xk * w.w;
            }
        }
    }
    #pragma unroll
    for (int i = 0; i < 16; ++i) {
        s[i] += __shfl_xor(s[i], 1);
        s[i] += __shfl_xor(s[i], 2);
    }
    if (q == 0) {
        *(float4*)(als_all + ((size_t)(t*2+0) * N_ + n) * 4) = make_float4(s[0], s[1], s[2], s[3]);
        *(float4*)(als_all + ((size_t)(t*2+1) * N_ + n) * 4) = make_float4(s[4], s[5], s[6], s[7]);
        *(float4*)(ald_all + ((size_t)(t*2+0) * N_ + n) * 4) = make_float4(s[8], s[9], s[10], s[11]);
        *(float4*)(ald_all + ((size_t)(t*2+1) * N_ + n) * 4) = make_float4(s[12], s[13], s[14], s[15]);
    }
}

// ---------------- prep: folded GEMV tables, padded B-tables, folded bias ----------------
__global__ void k_prep(const float* __restrict__ Wdst, const float* __restrict__ att_dst,
                       const float* __restrict__ Wih, const float* __restrict__ Whh,
                       const float* __restrict__ bih, const float* __restrict__ bhh,
                       const float* __restrict__ Wsrc, const float* __restrict__ att_src,
                       const float* __restrict__ raW1,
                       const float* __restrict__ Wq, const float* __restrict__ Wk,
                       const float* __restrict__ Wv,
                       float* __restrict__ wdall, float* __restrict__ biasv,
                       u16* __restrict__ raW1_pad, u16* __restrict__ Wc_pad,
                       u16* __restrict__ qkv_pad, u16* __restrict__ postB_pad)
{
    int tid = threadIdx.x, bid = blockIdx.x;
    if (bid == 0) {
        int k = tid >> 2, h = tid & 3;
        for (int r = 0; r < 2; ++r) {
            float ss = 0.f, sd = 0.f;
            for (int c = 0; c < 64; ++c) {
                ss += Wsrc[((size_t)r * 64 + k) * 256 + h * 64 + c] * att_src[r * 256 + h * 64 + c];
                sd += Wdst[((size_t)r * 64 + k) * 256 + h * 64 + c] * att_dst[r * 256 + h * 64 + c];
            }
            wdall[r * 256 + k * 4 + h] = ss;
            wdall[512 + r * 256 + k * 4 + h] = sd;
        }
        biasv[tid] = bih[tid] + bhh[tid];
    }
    for (int i = bid * 256 + tid; i < BPAD; i += gridDim.x * 256) {
        int n = i / 72, kk = i % 72;
        raW1_pad[i] = (kk < 64) ? f2bf(raW1[kk * 256 + n]) : (u16)0;
    }
    for (int i = bid * 256 + tid; i < 2 * BPAD; i += gridDim.x * 256) {
        int kc = i / BPAD, q = i % BPAD, n = q / 72, kk = q % 72;
        const float* W = kc ? Whh : Wih;
        Wc_pad[i] = (kk < 64) ? f2bf(W[n * 64 + kk]) : (u16)0;
    }
    for (int i = bid * 256 + tid; i < 192 * 72; i += gridDim.x * 256) {
        int g = i / 72, kk = i % 72;
        int j = g >> 6, c = g & 63;
        const float* W = (j == 0) ? Wq : (j == 1) ? Wk : Wv;
        qkv_pad[i] = (kk < 64) ? f2bf(W[kk * 64 + c]) : (u16)0;
    }
    for (int i = bid * 256 + tid; i < 2 * 4 * 4608; i += gridDim.x * 256) {
        int r = i / 18432, q = i % 18432, kc = q / 4608, qq = q % 4608;
        int c = qq / 72, kk = qq % 72;
        postB_pad[i] = (kk < 64) ? f2bf(Wsrc[(size_t)r * 16384 + kk * 256 + kc * 64 + c]) : (u16)0;
    }
}

// ---------------- CSR build ----------------
__global__ __launch_bounds__(256) void k_hist(const int* __restrict__ ei,
                                              u16* __restrict__ rank, u16* __restrict__ partial)
{
    __shared__ unsigned int hist[N_ / 2];
    int b = blockIdx.x, p = blockIdx.y, tid = threadIdx.x;
    for (int i = tid; i < N_ / 2; i += 256) hist[i] = 0u;
    __syncthreads();
    const int* dsts = ei + ((size_t)p * 2 + 1) * E_ + b * EPB_;
    u16* rk = rank + (size_t)p * E_ + b * EPB_;
    for (int e = tid; e < EPB_; e += 256) {
        int dst = dsts[e];
        unsigned sh = (unsigned)(dst & 1) * 16u;
        unsigned old = atomicAdd(&hist[dst >> 1], 1u << sh);
        rk[e] = (u16)((old >> sh) & 0xffffu);
    }
    __syncthreads();
    u16* part = partial + ((size_t)p * NB_ + b) * N_;
    for (int n = tid; n < N_; n += 256) {
        unsigned hv = hist[n >> 1];
        part[n] = (u16)((hv >> ((unsigned)(n & 1) * 16u)) & 0xffffu);
    }
}

__global__ __launch_bounds__(256) void k_scan1(u16* __restrict__ partial,
                                               int* __restrict__ offsets, int* __restrict__ chunktot)
{
    int p = blockIdx.y, ch = blockIdx.x;
    int tid = threadIdx.x, lane = tid & 63, wid = tid >> 6;
    __shared__ int wtot[4];
    u16* part = partial + (size_t)p * NB_ * N_;
    int* ofs = offsets + (size_t)p * (N_ + 1);
    int n0 = ch * CHN_;
    int carry = 0;
    for (int rnd = 0; rnd < 3; ++rnd) {
        int i = rnd * 256 + tid;
        int n = n0 + i;
        int v = 0;
        if (i < CHN_) {
            int run = 0;
            #pragma unroll 8
            for (int b = 0; b < NB_; ++b) {
                int pv = part[b * N_ + n];
                part[b * N_ + n] = (u16)run;
                run += pv;
            }
            v = run;
        }
        int incl = v;
        for (int d = 1; d < 64; d <<= 1) { int u = __shfl_up(incl, d); if (lane >= d) incl += u; }
        if (lane == 63) wtot[wid] = incl;
        __syncthreads();
        if (tid < 4) {
            int iv = wtot[tid];
            for (int d = 1; d < 4; d <<= 1) { int u = __shfl_up(iv, d); if (tid >= d) iv += u; }
            wtot[tid] = iv;
        }
        __syncthreads();
        int woff = (wid > 0) ? wtot[wid - 1] : 0;
        int tot = wtot[3];
        int excl = carry + woff + incl - v;
        if (i < CHN_) ofs[n] = excl;
        carry += tot;
        __syncthreads();
    }
    if (tid == 0) chunktot[p * NB_ + ch] = carry;
}

__global__ void k_scan2(const int* __restrict__ chunktot, int* __restrict__ chunkbase) {
    int tid = threadIdx.x;
    if (tid < P_) {
        int run = 0;
        for (int c = 0; c < NB_; ++c) {
            chunkbase[tid * NB_ + c] = run;
            run += chunktot[tid * NB_ + c];
        }
    }
}

__global__ void k_scan3(int* __restrict__ offsets, const int* __restrict__ chunkbase) {
    int p = blockIdx.y;
    int n = blockIdx.x * 256 + threadIdx.x;
    if (n < N_)
        offsets[(size_t)p * (N_ + 1) + n] += chunkbase[p * NB_ + n / CHN_];
    if (n == 0)
        offsets[(size_t)p * (N_ + 1) + N_] = E_;
}

__global__ void k_scatter(const int* __restrict__ ei, const int* __restrict__ offsets,
                          const u16* __restrict__ rank, const u16* __restrict__ partial,
                          u16* __restrict__ csr) {
    int p = blockIdx.y;
    int e = blockIdx.x * 256 + threadIdx.x;
    if (e >= E_) return;
    int src = ei[((size_t)p * 2 + 0) * E_ + e];
    int dst = ei[((size_t)p * 2 + 1) * E_ + e];
    int b = e / EPB_;
    int pos = offsets[p * (N_ + 1) + dst]
            + (int)partial[((size_t)p * NB_ + b) * N_ + dst]
            + (int)rank[(size_t)p * E_ + e];
    csr[(size_t)p * E_ + pos] = (u16)src;
}

// ---------------- GAT aggregation over x (projection commuted out) ----------------
#define AGG_BODY(J)                                                              \
    {   int s = __shfl(sv, (J));                                                 \
        float pj = __shfl(pv, base48 + (J));                                     \
        ushort4 xv = *(const ushort4*)(xb + (size_t)s * 64 + c4);                \
        a0 += pj * bf2f(xv.x); a1 += pj * bf2f(xv.y);                            \
        a2 += pj * bf2f(xv.z); a3 += pj * bf2f(xv.w); }

__global__ __launch_bounds__(256) void k_agg(
    const int* __restrict__ offsets, const u16* __restrict__ csr,
    const float* __restrict__ als_t, const float* __restrict__ ald_t,
    const u16* __restrict__ xb, u16* __restrict__ xagg, int t)
{
    int r = blockIdx.y;
    const int* off = offsets + (size_t)(t * 2 + r) * (N_ + 1);
    const u16* srcs = csr + (size_t)(t * 2 + r) * E_;
    const float* als = als_t + (size_t)r * N_ * 4;
    const float* ald = ald_t + (size_t)r * N_ * 4;

    int tid = threadIdx.x, lane = tid & 63, wv = tid >> 6;
    int n = blockIdx.x * 4 + wv;
    int h = lane >> 4, j16 = lane & 15, c4 = j16 * 4;
    int base48 = lane & 48;
    int o0 = off[n], o1 = off[n + 1];
    float aldv = ald[(size_t)n * 4 + h];

    float den = 0.f, a0 = 0.f, a1 = 0.f, a2 = 0.f, a3 = 0.f;
    for (int base = o0; base < o1; base += 16) {
        int idx = base + j16;
        int sv = 0; float pv = 0.f;
        if (idx < o1) {
            sv = (int)srcs[idx];
            float e = als[sv * 4 + h] + aldv;
            e = (e > 0.f) ? e : 0.2f * e;
            pv = __expf(e);
        }
        den += pv;
        int cnt = o1 - base;
        if (cnt >= 16) {
            #pragma unroll
            for (int j = 0; j < 16; ++j) AGG_BODY(j)
        } else {
            for (int j = 0; j < cnt; ++j) AGG_BODY(j)
        }
    }
    den += __shfl_xor(den, 1); den += __shfl_xor(den, 2);
    den += __shfl_xor(den, 4); den += __shfl_xor(den, 8);
    float sc = 0.25f / (den + 1e-16f);
    ushort4 ov;
    ov.x = f2bf(a0 * sc); ov.y = f2bf(a1 * sc);
    ov.z = f2bf(a2 * sc); ov.w = f2bf(a3 * sc);
    *(ushort4*)(xagg + ((size_t)r * N_ + n) * 256 + h * 64 + c4) = ov;
}

// ---------------- post-projection: intra = xagg @ B~ ----------------
__global__ __launch_bounds__(256) void k_post(
    const u16* __restrict__ xagg, const u16* __restrict__ postB_pad,
    u16* __restrict__ intra, int t)
{
    int r = blockIdx.y;
    const u16* A = xagg + (size_t)r * N_ * 256;
    const u16* Bp = postB_pad + (size_t)r * 4 * 4608;
    const int tid = threadIdx.x, lane = tid & 63, wv = tid >> 6;
    const int col = lane & 15, quad = lane >> 4;
    int m0 = blockIdx.x * 64;
    int row = m0 + wv * 16 + col;
    int row_c = (row < N_) ? row : (N_ - 1);

    f32x4 acc[4];
    #pragma unroll
    for (int cf = 0; cf < 4; ++cf) { acc[cf][0]=0.f; acc[cf][1]=0.f; acc[cf][2]=0.f; acc[cf][3]=0.f; }
    #pragma unroll
    for (int kc = 0; kc < 4; ++kc) {
        #pragma unroll
        for (int ks = 0; ks < 2; ++ks) {
            bf16x8 a = *(const bf16x8*)(A + (size_t)row_c * 256 + kc * 64 + ks * 32 + quad * 8);
            const u16* bb = Bp + kc * 4608 + ks * 32 + quad * 8;
            #pragma unroll
            for (int cf = 0; cf < 4; ++cf) {
                bf16x8 b = *(const bf16x8*)(bb + (cf * 16 + col) * 72);
                acc[cf] = __builtin_amdgcn_mfma_f32_16x16x32_bf16(a, b, acc[cf], 0, 0, 0);
            }
        }
    }
    int rowbase = m0 + wv * 16 + quad * 4;
    #pragma unroll
    for (int cf = 0; cf < 4; ++cf) {
        int c = cf * 16 + col;
        #pragma unroll
        for (int reg = 0; reg < 4; ++reg) {
            int rr = rowbase + reg;
            if (rr < N_)
                intra[(((size_t)t * N_ + rr) * 2 + r) * 64 + c] = f2bf(acc[cf][reg]);
        }
    }
}

// ---------------- RelationAgg GEMM with fused ftanh(.)@W2 epilogue ----------------
__global__ __launch_bounds__(256) void k_relagg(
    const u16* __restrict__ A, const u16* __restrict__ W1pad, const float* __restrict__ b1,
    const float* __restrict__ W2, float* __restrict__ svals)
{
    int m0 = blockIdx.x * 64;
    f32x4 acc[16];
    gemm_direct(A, W1pad, T_ * N_ * R_, 64, 1, m0, acc);

    const int tid = threadIdx.x, lane = tid & 63, wv = tid >> 6;
    const int col = lane & 15, quad = lane >> 4;
    int rowbase = m0 + wv * 16 + quad * 4;
    float sp[4] = {0.f, 0.f, 0.f, 0.f};
    #pragma unroll
    for (int cf = 0; cf < 16; ++cf) {
        int gcol = cf * 16 + col;
        float bb = b1[gcol];
        float ww = W2[gcol];
        #pragma unroll
        for (int reg = 0; reg < 4; ++reg)
            sp[reg] += ftanh(acc[cf][reg] + bb) * ww;
    }
    #pragma unroll
    for (int reg = 0; reg < 4; ++reg) {
        float v = sp[reg];
        v += __shfl_xor(v, 1); v += __shfl_xor(v, 2);
        v += __shfl_xor(v, 4); v += __shfl_xor(v, 8);
        sp[reg] = v;
    }
    if (col == 0) {
        #pragma unroll
        for (int reg = 0; reg < 4; ++reg) {
            int row = rowbase + reg;
            if (row < T_ * N_ * R_) svals[row] = sp[reg];
        }
    }
}

__global__ void k_betasum(const float* __restrict__ svals, float* __restrict__ ssum) {
    int p = blockIdx.x, t = p >> 1, r = p & 1;
    __shared__ float red[256];
    float s = 0.f;
    for (int n = threadIdx.x; n < N_; n += 256)
        s += svals[((size_t)t * N_ + n) * 2 + r];
    red[threadIdx.x] = s;
    __syncthreads();
    for (int st = 128; st > 0; st >>= 1) {
        if (threadIdx.x < st) red[threadIdx.x] += red[threadIdx.x + st];
        __syncthreads();
    }
    if (threadIdx.x == 0) ssum[p] = red[0];
}

__global__ void k_betafinal(const float* __restrict__ ssum, float* __restrict__ beta) {
    int t = threadIdx.x;
    if (t >= 4) return;
    float s0 = ssum[t * 2] * (1.f / N_), s1 = ssum[t * 2 + 1] * (1.f / N_);
    float mx = fmaxf(s0, s1);
    float e0 = __expf(s0 - mx), e1 = __expf(s1 - mx);
    float inv = 1.f / (e0 + e1);
    beta[t * 2] = e0 * inv; beta[t * 2 + 1] = e1 * inv;
}

// ---------------- LSTM GEMM (A assembled on the fly) + fused cell update ----------------
__global__ __launch_bounds__(256) void k_lstm(
    const u16* __restrict__ intra, const float* __restrict__ beta,
    const u16* __restrict__ Wc_pad, const float* __restrict__ biasv,
    float* __restrict__ cbuf, u16* __restrict__ hbuf_bf, u16* __restrict__ feats, int t)
{
    const int tid = threadIdx.x, lane = tid & 63, wv = tid >> 6;
    const int col = lane & 15, quad = lane >> 4;
    int m0 = blockIdx.x * 64;
    int row = m0 + wv * 16 + col;
    int row_c = (row < N_) ? row : (N_ - 1);
    float b0 = beta[t * 2], b1 = beta[t * 2 + 1];
    const u16* ib = intra + ((size_t)t * N_ + row_c) * 128;

    f32x4 acc[16];
    #pragma unroll
    for (int cf = 0; cf < 16; ++cf) { acc[cf][0]=0.f; acc[cf][1]=0.f; acc[cf][2]=0.f; acc[cf][3]=0.f; }

    #pragma unroll
    for (int kc = 0; kc < 2; ++kc) {
        #pragma unroll
        for (int ks = 0; ks < 2; ++ks) {
            bf16x8 a;
            if (kc == 0) {
                int coff = ks * 32 + quad * 8;
                bf16x8 i0 = *(const bf16x8*)(ib + coff);
                bf16x8 i1 = *(const bf16x8*)(ib + 64 + coff);
                union { u16 h[8]; bf16x8 v; } cv;
                #pragma unroll
                for (int j = 0; j < 8; ++j)
                    cv.h[j] = f2bf(b0 * bf2f((u16)i0[j]) + b1 * bf2f((u16)i1[j]));
                a = cv.v;
            } else {
                a = *(const bf16x8*)(hbuf_bf + (size_t)row_c * 64 + ks * 32 + quad * 8);
            }
            const u16* bb = Wc_pad + kc * BPAD + ks * 32 + quad * 8;
            #pragma unroll
            for (int cf = 0; cf < 16; ++cf) {
                bf16x8 b = *(const bf16x8*)(bb + (cf * 16 + col) * 72);
                acc[cf] = __builtin_amdgcn_mfma_f32_16x16x32_bf16(a, b, acc[cf], 0, 0, 0);
            }
        }
    }

    int rowbase = m0 + wv * 16 + quad * 4;
    #pragma unroll
    for (int j = 0; j < 4; ++j) {
        int c = j * 16 + col;
        float bi = biasv[c], bf_ = biasv[64 + c], bg = biasv[128 + c], bo = biasv[192 + c];
        #pragma unroll
        for (int reg = 0; reg < 4; ++reg) {
            int rr = rowbase + reg;
            if (rr < N_) {
                float gi = acc[j][reg] + bi;
                float gf = acc[j + 4][reg] + bf_;
                float gg = acc[j + 8][reg] + bg;
                float go = acc[j + 12][reg] + bo;
                float cc = cbuf[(size_t)rr * 64 + c];
                cc = sigm(gf) * cc + sigm(gi) * ftanh(gg);
                float hh = sigm(go) * ftanh(cc);
                cbuf[(size_t)rr * 64 + c] = cc;
                hbuf_bf[(size_t)rr * 64 + c] = f2bf(hh);
                feats[(size_t)rr * 256 + t * 64 + c] = f2bf(hh);
            }
        }
    }
}

// ---------------- temporal causal MHA: MFMA QKV + per-lane attention ----------------
__global__ __launch_bounds__(256) void k_attn(
    const u16* __restrict__ feats, const float* __restrict__ pos_emb,
    const u16* __restrict__ qkv_pad, float* __restrict__ out)
{
    __shared__ float qkv_s[64 * 200];
    const int tid = threadIdx.x, lane = tid & 63, wv = tid >> 6;
    const int col = lane & 15, quad = lane >> 4;
    int m0 = blockIdx.x * 64;
    int row = m0 + wv * 16 + col;
    int trow = row & 3;

    f32x4 acc[12];
    #pragma unroll
    for (int cf = 0; cf < 12; ++cf) { acc[cf][0]=0.f; acc[cf][1]=0.f; acc[cf][2]=0.f; acc[cf][3]=0.f; }
    #pragma unroll
    for (int ks = 0; ks < 2; ++ks) {
        int coff = ks * 32 + quad * 8;
        bf16x8 fv = *(const bf16x8*)(feats + (size_t)row * 64 + coff);
        float4 p0 = *(const float4*)(pos_emb + trow * 64 + coff);
        float4 p1 = *(const float4*)(pos_emb + trow * 64 + coff + 4);
        union { u16 h[8]; bf16x8 v; } cv;
        cv.h[0] = f2bf(bf2f((u16)fv[0]) + p0.x); cv.h[1] = f2bf(bf2f((u16)fv[1]) + p0.y);
        cv.h[2] = f2bf(bf2f((u16)fv[2]) + p0.z); cv.h[3] = f2bf(bf2f((u16)fv[3]) + p0.w);
        cv.h[4] = f2bf(bf2f((u16)fv[4]) + p1.x); cv.h[5] = f2bf(bf2f((u16)fv[5]) + p1.y);
        cv.h[6] = f2bf(bf2f((u16)fv[6]) + p1.z); cv.h[7] = f2bf(bf2f((u16)fv[7]) + p1.w);
        bf16x8 a = cv.v;
        const u16* bb = qkv_pad + ks * 32 + quad * 8;
        #pragma unroll
        for (int cf = 0; cf < 12; ++cf) {
            bf16x8 b = *(const bf16x8*)(bb + (cf * 16 + col) * 72);
            acc[cf] = __builtin_amdgcn_mfma_f32_16x16x32_bf16(a, b, acc[cf], 0, 0, 0);
        }
    }
    #pragma unroll
    for (int cf = 0; cf < 12; ++cf) {
        int g = cf * 16 + col;
        #pragma unroll
        for (int reg = 0; reg < 4; ++reg) {
            int rl = wv * 16 + quad * 4 + reg;
            qkv_s[rl * 200 + g] = acc[cf][reg];
        }
    }
    __syncthreads();

    int nl = wv * 4 + (lane >> 4);
    int sub = lane & 15;
    int h = sub >> 2, tq = sub & 3;
    const float* qrow = qkv_s + (nl * 4 + tq) * 200 + h * 16;

    float s[4];
    #pragma unroll
    for (int tk = 0; tk < 4; ++tk) {
        const float* krow = qkv_s + (nl * 4 + tk) * 200 + 64 + h * 16;
        float d = 0.f;
        #pragma unroll
        for (int j = 0; j < 16; ++j) d += qrow[j] * krow[j];
        s[tk] = (tk > tq) ? -4294967295.0f : d * 0.5f;
    }
    float mx = fmaxf(fmaxf(s[0], s[1]), fmaxf(s[2], s[3]));
    float a0 = __expf(s[0]-mx), a1 = __expf(s[1]-mx), a2 = __expf(s[2]-mx), a3 = __expf(s[3]-mx);
    float inv = 1.f / (a0 + a1 + a2 + a3);
    a0 *= inv; a1 *= inv; a2 *= inv; a3 *= inv;

    int n = blockIdx.x * 16 + nl;
    const float* v0 = qkv_s + (nl * 4 + 0) * 200 + 128 + h * 16;
    const float* v1 = v0 + 200, *v2 = v0 + 400, *v3 = v0 + 600;
    #pragma unroll
    for (int cc4 = 0; cc4 < 4; ++cc4) {
        float4 o;
        o.x = a0*v0[cc4*4+0] + a1*v1[cc4*4+0] + a2*v2[cc4*4+0] + a3*v3[cc4*4+0];
        o.y = a0*v0[cc4*4+1] + a1*v1[cc4*4+1] + a2*v2[cc4*4+1] + a3*v3[cc4*4+1];
        o.z = a0*v0[cc4*4+2] + a1*v1[cc4*4+2] + a2*v2[cc4*4+2] + a3*v3[cc4*4+2];
        o.w = a0*v0[cc4*4+3] + a1*v1[cc4*4+3] + a2*v2[cc4*4+3] + a3*v3[cc4*4+3];
        *(float4*)(out + (size_t)n * 256 + tq * 64 + h * 16 + cc4 * 4) = o;
    }
}

// ---------------- launcher ----------------
extern "C" void kernel_launch(void* const* d_in, const int* in_sizes, int n_in,
                              void* d_out, int out_size, void* d_ws, size_t ws_size,
                              hipStream_t stream) {
    const float* x     = (const float*)d_in[0];
    const int* ei      = (const int*)d_in[1];
    const float* Wsrc  = (const float*)d_in[2];
    const float* Wdst  = (const float*)d_in[3];
    const float* att_src = (const float*)d_in[4];
    const float* att_dst = (const float*)d_in[5];
    const float* raW1  = (const float*)d_in[6];
    const float* rab1  = (const float*)d_in[7];
    const float* raW2  = (const float*)d_in[8];
    const float* Wih   = (const float*)d_in[9];
    const float* Whh   = (const float*)d_in[10];
    const float* bih   = (const float*)d_in[11];
    const float* bhh   = (const float*)d_in[12];
    const float* pos   = (const float*)d_in[13];
    const float* Wq    = (const float*)d_in[14];
    const float* Wk    = (const float*)d_in[15];
    const float* Wv    = (const float*)d_in[16];
    float* out = (float*)d_out;

    char* w = (char*)d_ws;
    size_t off = 0;
    auto alloc = [&](size_t bytes) -> char* {
        char* pp = w + off; off += (bytes + 255) & ~(size_t)255; return pp;
    };
    // ---- long-lived ----
    u16*   intra     = (u16*)  alloc((size_t)T_ * N_ * R_ * 64 * 2);  // 20.48 MB
    u16*   x_bf      = (u16*)  alloc((size_t)T_ * N_ * 64 * 2);       // 10.24 MB
    float* svals     = (float*)alloc((size_t)T_ * N_ * R_ * 4);
    float* ssum      = (float*)alloc(256);
    float* beta      = (float*)alloc(256);
    float* wdall     = (float*)alloc(1024 * 4);
    float* biasv     = (float*)alloc(256 * 4);
    u16*   raW1_pad  = (u16*)  alloc(BPAD * 2);
    u16*   Wc_pad    = (u16*)  alloc(2 * BPAD * 2);
    u16*   qkv_pad   = (u16*)  alloc(192 * 72 * 2);
    u16*   postB_pad = (u16*)  alloc(2 * 4 * 4608 * 2);
    int*   chunktot  = (int*)  alloc(P_ * NB_ * 4);
    int*   chunkbase = (int*)  alloc(P_ * NB_ * 4);
    // ---- union region ----
    char*  ubase   = alloc(0);
    size_t uoff = 0;
    auto ualloc = [&](size_t bytes) -> char* {
        char* pp = ubase + uoff; uoff += (bytes + 255) & ~(size_t)255; return pp;
    };
    int*   offsets = (int*)  ualloc((size_t)P_ * (N_ + 1) * 4);
    u16*   csr     = (u16*)  ualloc((size_t)P_ * E_ * 2);
    float* als_all = (float*)ualloc((size_t)P_ * N_ * 4 * 4);
    float* ald_all = (float*)ualloc((size_t)P_ * N_ * 4 * 4);
    u16*   partial = (u16*)  ualloc((size_t)P_ * NB_ * N_ * 2);
    u16*   xagg    = (u16*)  ualloc((size_t)R_ * N_ * 256 * 2);   // 20.48 MB
    u16*   rank    = (u16*)  xagg;   // overlay: rank dead before first k_agg
    // phase 2 overlay (phase-1 sub-buffers dead after the k_agg loop)
    float* cbuf    = (float*)(ubase);
    u16*   hbuf_bf = (u16*)  (ubase + 5300000);
    u16*   feats   = (u16*)  (ubase + 8000000);
    (void)ws_size; (void)in_sizes; (void)n_in; (void)out_size;

    k_prep<<<72, 256, 0, stream>>>(Wdst, att_dst, Wih, Whh, bih, bhh, Wsrc, att_src, raW1,
                                   Wq, Wk, Wv, wdall, biasv, raW1_pad, Wc_pad, qkv_pad, postB_pad);
    k_hist<<<dim3(NB_, 8), 256, 0, stream>>>(ei, rank, partial);
    k_scan1<<<dim3(NB_, 8), 256, 0, stream>>>(partial, offsets, chunktot);
    k_scan2<<<1, 64, 0, stream>>>(chunktot, chunkbase);
    k_scan3<<<dim3(79, 8), 256, 0, stream>>>(offsets, chunkbase);
    k_scatter<<<dim3(1250, 8), 256, 0, stream>>>(ei, offsets, rank, partial, csr);
    k_fold<<<dim3(313, 4), 256, 0, stream>>>(x, wdall, als_all, ald_all, x_bf);
    for (int t = 0; t < T_; ++t) {
        k_agg<<<dim3(5000, 2), 256, 0, stream>>>(offsets, csr,
                                                 als_all + (size_t)t * 2 * N_ * 4,
                                                 ald_all + (size_t)t * 2 * N_ * 4,
                                                 x_bf + (size_t)t * N_ * 64, xagg, t);
        k_post<<<dim3(313, 2), 256, 0, stream>>>(xagg, postB_pad, intra, t);
    }
    k_relagg<<<2500, 256, 0, stream>>>(intra, raW1_pad, rab1, raW2, svals);
    k_betasum<<<8, 256, 0, stream>>>(svals, ssum);
    k_betafinal<<<1, 64, 0, stream>>>(ssum, beta);
    hipMemsetAsync(cbuf, 0, (size_t)N_ * 64 * 4, stream);
    hipMemsetAsync(hbuf_bf, 0, (size_t)N_ * 64 * 2, stream);
    for (int t = 0; t < T_; ++t)
        k_lstm<<<313, 256, 0, stream>>>(intra, beta, Wc_pad, biasv, cbuf, hbuf_bf, feats, t);
    k_attn<<<1250, 256, 0, stream>>>(feats, pos, qkv_pad, out);
}

// Round 10
// 564.827 us; speedup vs baseline: 2.1419x; 1.0213x over previous
//
#include <hip/hip_runtime.h>
#include <hip/hip_bf16.h>

#define T_ 4
#define N_ 20000
#define E_ 320000
#define R_ 2
#define DIN 64
#define G_ 256   // H*Dh
#define P_ 8     // T*R
#define BPAD 18432  // 256 * 72 padded B-table halves per 64-k chunk
#define NB_ 32      // CSR-build blocks per p
#define EPB_ 10000  // edges per CSR-build block
#define CHN_ 625    // nodes per scan chunk (N_/32)

typedef unsigned short u16;
typedef __attribute__((ext_vector_type(8))) short bf16x8;
typedef __attribute__((ext_vector_type(4))) float f32x4;

__device__ __forceinline__ float bf2f(u16 u) {
    unsigned int i = ((unsigned int)u) << 16; float f;
    __builtin_memcpy(&f, &i, 4); return f;
}
__device__ __forceinline__ u16 f2bf(float f) {
    unsigned int i; __builtin_memcpy(&i, &f, 4);
    unsigned int r = i + 0x7fffu + ((i >> 16) & 1u);
    return (u16)(r >> 16);
}
__device__ __forceinline__ float sigm(float x) { return 1.f / (1.f + __expf(-x)); }
// fast tanh: 1 - 2/(exp(2x)+1); hardware v_exp_f32, correct saturation at +-inf
__device__ __forceinline__ float ftanh(float x) { return 1.f - 2.f / (__expf(2.f * x) + 1.f); }

// ---------------- LDS-free MFMA GEMM core (bf16 A) ----------------
__device__ __forceinline__ void gemm_direct(
    const u16* __restrict__ A, const u16* __restrict__ Bpad,
    int M, int Astride, int kchunks, int m0, f32x4* acc)
{
    const int tid = threadIdx.x;
    const int lane = tid & 63, wv = tid >> 6;
    const int col = lane & 15, quad = lane >> 4;
    #pragma unroll
    for (int cf = 0; cf < 16; ++cf) { acc[cf][0]=0.f; acc[cf][1]=0.f; acc[cf][2]=0.f; acc[cf][3]=0.f; }

    int row = m0 + wv * 16 + col;
    int row_c = (row < M) ? row : (M - 1);

    for (int kc = 0; kc < kchunks; ++kc) {
        #pragma unroll
        for (int ks = 0; ks < 2; ++ks) {
            bf16x8 a = *(const bf16x8*)(A + (size_t)row_c * Astride + kc * 64 + ks * 32 + quad * 8);
            const u16* bb = Bpad + kc * BPAD + ks * 32 + quad * 8;
            #pragma unroll
            for (int cf = 0; cf < 16; ++cf) {
                bf16x8 b = *(const bf16x8*)(bb + (cf * 16 + col) * 72);
                acc[cf] = __builtin_amdgcn_mfma_f32_16x16x32_bf16(a, b, acc[cf], 0, 0, 0);
            }
        }
    }
}

// ---------------- fold: als/ald GEMVs + x->bf16 cast, 4 lanes per node ----------------
__global__ __launch_bounds__(256) void k_fold(
    const float* __restrict__ x, const float* __restrict__ wdall,
    float* __restrict__ als_all, float* __restrict__ ald_all, u16* __restrict__ x_bf)
{
    int t = blockIdx.y;
    int idx = blockIdx.x * 256 + threadIdx.x;
    if (idx >= N_ * 4) return;
    int n = idx >> 2, q = idx & 3;
    const float* xr = x + ((size_t)t * N_ + n) * 64 + q * 16;
    float4 xv[4];
    #pragma unroll
    for (int i = 0; i < 4; ++i) xv[i] = *(const float4*)(xr + i * 4);

    {
        union { u16 h[16]; ushort4 s4[4]; } cv;
        #pragma unroll
        for (int i = 0; i < 4; ++i) {
            cv.h[i*4+0] = f2bf(xv[i].x); cv.h[i*4+1] = f2bf(xv[i].y);
            cv.h[i*4+2] = f2bf(xv[i].z); cv.h[i*4+3] = f2bf(xv[i].w);
        }
        u16* xo = x_bf + ((size_t)t * N_ + n) * 64 + q * 16;
        #pragma unroll
        for (int i = 0; i < 4; ++i) *(ushort4*)(xo + i * 4) = cv.s4[i];
    }

    float s[16];
    #pragma unroll
    for (int i = 0; i < 16; ++i) s[i] = 0.f;
    #pragma unroll
    for (int i = 0; i < 4; ++i) {
        float xe[4] = {xv[i].x, xv[i].y, xv[i].z, xv[i].w};
        #pragma unroll
        for (int e = 0; e < 4; ++e) {
            int k = q * 16 + i * 4 + e;
            float xk = xe[e];
            #pragma unroll
            for (int tb = 0; tb < 4; ++tb) {
                float4 w = *(const float4*)(wdall + tb * 256 + k * 4);
                s[tb*4+0] += xk * w.x; s[tb*4+1] += xk * w.y;
                s[tb*4+2] += xk * w.z; s[tb*4+3] += xk * w.w;
            }
        }
    }
    #pragma unroll
    for (int i = 0; i < 16; ++i) {
        s[i] += __shfl_xor(s[i], 1);
        s[i] += __shfl_xor(s[i], 2);
    }
    if (q == 0) {
        *(float4*)(als_all + ((size_t)(t*2+0) * N_ + n) * 4) = make_float4(s[0], s[1], s[2], s[3]);
        *(float4*)(als_all + ((size_t)(t*2+1) * N_ + n) * 4) = make_float4(s[4], s[5], s[6], s[7]);
        *(float4*)(ald_all + ((size_t)(t*2+0) * N_ + n) * 4) = make_float4(s[8], s[9], s[10], s[11]);
        *(float4*)(ald_all + ((size_t)(t*2+1) * N_ + n) * 4) = make_float4(s[12], s[13], s[14], s[15]);
    }
}

// ---------------- prep: folded GEMV tables, padded B-tables, folded bias ----------------
__global__ void k_prep(const float* __restrict__ Wdst, const float* __restrict__ att_dst,
                       const float* __restrict__ Wih, const float* __restrict__ Whh,
                       const float* __restrict__ bih, const float* __restrict__ bhh,
                       const float* __restrict__ Wsrc, const float* __restrict__ att_src,
                       const float* __restrict__ raW1,
                       const float* __restrict__ Wq, const float* __restrict__ Wk,
                       const float* __restrict__ Wv,
                       float* __restrict__ wdall, float* __restrict__ biasv,
                       u16* __restrict__ raW1_pad, u16* __restrict__ Wc_pad,
                       u16* __restrict__ qkv_pad, u16* __restrict__ postB_pad)
{
    int tid = threadIdx.x, bid = blockIdx.x;
    if (bid == 0) {
        int k = tid >> 2, h = tid & 3;
        for (int r = 0; r < 2; ++r) {
            float ss = 0.f, sd = 0.f;
            for (int c = 0; c < 64; ++c) {
                ss += Wsrc[((size_t)r * 64 + k) * 256 + h * 64 + c] * att_src[r * 256 + h * 64 + c];
                sd += Wdst[((size_t)r * 64 + k) * 256 + h * 64 + c] * att_dst[r * 256 + h * 64 + c];
            }
            wdall[r * 256 + k * 4 + h] = ss;
            wdall[512 + r * 256 + k * 4 + h] = sd;
        }
        biasv[tid] = bih[tid] + bhh[tid];
    }
    for (int i = bid * 256 + tid; i < BPAD; i += gridDim.x * 256) {
        int n = i / 72, kk = i % 72;
        raW1_pad[i] = (kk < 64) ? f2bf(raW1[kk * 256 + n]) : (u16)0;
    }
    for (int i = bid * 256 + tid; i < 2 * BPAD; i += gridDim.x * 256) {
        int kc = i / BPAD, q = i % BPAD, n = q / 72, kk = q % 72;
        const float* W = kc ? Whh : Wih;
        Wc_pad[i] = (kk < 64) ? f2bf(W[n * 64 + kk]) : (u16)0;
    }
    for (int i = bid * 256 + tid; i < 192 * 72; i += gridDim.x * 256) {
        int g = i / 72, kk = i % 72;
        int j = g >> 6, c = g & 63;
        const float* W = (j == 0) ? Wq : (j == 1) ? Wk : Wv;
        qkv_pad[i] = (kk < 64) ? f2bf(W[kk * 64 + c]) : (u16)0;
    }
    for (int i = bid * 256 + tid; i < 2 * 4 * 4608; i += gridDim.x * 256) {
        int r = i / 18432, q = i % 18432, kc = q / 4608, qq = q % 4608;
        int c = qq / 72, kk = qq % 72;
        postB_pad[i] = (kk < 64) ? f2bf(Wsrc[(size_t)r * 16384 + kk * 256 + kc * 64 + c]) : (u16)0;
    }
}

// ---------------- CSR build ----------------
__global__ __launch_bounds__(256) void k_hist(const int* __restrict__ ei,
                                              u16* __restrict__ rank, u16* __restrict__ partial)
{
    __shared__ unsigned int hist[N_ / 2];
    int b = blockIdx.x, p = blockIdx.y, tid = threadIdx.x;
    for (int i = tid; i < N_ / 2; i += 256) hist[i] = 0u;
    __syncthreads();
    const int* dsts = ei + ((size_t)p * 2 + 1) * E_ + b * EPB_;
    u16* rk = rank + (size_t)p * E_ + b * EPB_;
    for (int e = tid; e < EPB_; e += 256) {
        int dst = dsts[e];
        unsigned sh = (unsigned)(dst & 1) * 16u;
        unsigned old = atomicAdd(&hist[dst >> 1], 1u << sh);
        rk[e] = (u16)((old >> sh) & 0xffffu);
    }
    __syncthreads();
    u16* part = partial + ((size_t)p * NB_ + b) * N_;
    for (int n = tid; n < N_; n += 256) {
        unsigned hv = hist[n >> 1];
        part[n] = (u16)((hv >> ((unsigned)(n & 1) * 16u)) & 0xffffu);
    }
}

__global__ __launch_bounds__(256) void k_scan1(u16* __restrict__ partial,
                                               int* __restrict__ offsets, int* __restrict__ chunktot)
{
    int p = blockIdx.y, ch = blockIdx.x;
    int tid = threadIdx.x, lane = tid & 63, wid = tid >> 6;
    __shared__ int wtot[4];
    u16* part = partial + (size_t)p * NB_ * N_;
    int* ofs = offsets + (size_t)p * (N_ + 1);
    int n0 = ch * CHN_;
    int carry = 0;
    for (int rnd = 0; rnd < 3; ++rnd) {
        int i = rnd * 256 + tid;
        int n = n0 + i;
        int v = 0;
        if (i < CHN_) {
            int run = 0;
            #pragma unroll 8
            for (int b = 0; b < NB_; ++b) {
                int pv = part[b * N_ + n];
                part[b * N_ + n] = (u16)run;
                run += pv;
            }
            v = run;
        }
        int incl = v;
        for (int d = 1; d < 64; d <<= 1) { int u = __shfl_up(incl, d); if (lane >= d) incl += u; }
        if (lane == 63) wtot[wid] = incl;
        __syncthreads();
        if (tid < 4) {
            int iv = wtot[tid];
            for (int d = 1; d < 4; d <<= 1) { int u = __shfl_up(iv, d); if (tid >= d) iv += u; }
            wtot[tid] = iv;
        }
        __syncthreads();
        int woff = (wid > 0) ? wtot[wid - 1] : 0;
        int tot = wtot[3];
        int excl = carry + woff + incl - v;
        if (i < CHN_) ofs[n] = excl;
        carry += tot;
        __syncthreads();
    }
    if (tid == 0) chunktot[p * NB_ + ch] = carry;
}

__global__ void k_scan2(const int* __restrict__ chunktot, int* __restrict__ chunkbase) {
    int tid = threadIdx.x;
    if (tid < P_) {
        int run = 0;
        for (int c = 0; c < NB_; ++c) {
            chunkbase[tid * NB_ + c] = run;
            run += chunktot[tid * NB_ + c];
        }
    }
}

__global__ void k_scan3(int* __restrict__ offsets, const int* __restrict__ chunkbase) {
    int p = blockIdx.y;
    int n = blockIdx.x * 256 + threadIdx.x;
    if (n < N_)
        offsets[(size_t)p * (N_ + 1) + n] += chunkbase[p * NB_ + n / CHN_];
    if (n == 0)
        offsets[(size_t)p * (N_ + 1) + N_] = E_;
}

__global__ void k_scatter(const int* __restrict__ ei, const int* __restrict__ offsets,
                          const u16* __restrict__ rank, const u16* __restrict__ partial,
                          u16* __restrict__ csr) {
    int p = blockIdx.y;
    int e = blockIdx.x * 256 + threadIdx.x;
    if (e >= E_) return;
    int src = ei[((size_t)p * 2 + 0) * E_ + e];
    int dst = ei[((size_t)p * 2 + 1) * E_ + e];
    int b = e / EPB_;
    int pos = offsets[p * (N_ + 1) + dst]
            + (int)partial[((size_t)p * NB_ + b) * N_ + dst]
            + (int)rank[(size_t)p * E_ + e];
    csr[(size_t)p * E_ + pos] = (u16)src;
}

// ---------------- GAT aggregation over x: hoisted-gather batches ----------------
// Wave per dst node. Load phase: lane (h', j) computes pv for (edge j, head h').
// Full batches: phase-1 issues all 16 gathers (registers), phase-2 accumulates.
__global__ __launch_bounds__(256) void k_agg(
    const int* __restrict__ offsets, const u16* __restrict__ csr,
    const float* __restrict__ als_t, const float* __restrict__ ald_t,
    const u16* __restrict__ xb, u16* __restrict__ xagg, int t)
{
    int r = blockIdx.y;
    const int* off = offsets + (size_t)(t * 2 + r) * (N_ + 1);
    const u16* srcs = csr + (size_t)(t * 2 + r) * E_;
    const float* als = als_t + (size_t)r * N_ * 4;
    const float* ald = ald_t + (size_t)r * N_ * 4;

    int tid = threadIdx.x, lane = tid & 63, wv = tid >> 6;
    int n = blockIdx.x * 4 + wv;
    int h = lane >> 4, j16 = lane & 15, c4 = j16 * 4;
    int base48 = lane & 48;
    int o0 = off[n], o1 = off[n + 1];
    float aldv = ald[(size_t)n * 4 + h];

    float den = 0.f, a0 = 0.f, a1 = 0.f, a2 = 0.f, a3 = 0.f;
    for (int base = o0; base < o1; base += 16) {
        int idx = base + j16;
        int sv = 0; float pv = 0.f;
        if (idx < o1) {
            sv = (int)srcs[idx];
            float e = als[sv * 4 + h] + aldv;
            e = (e > 0.f) ? e : 0.2f * e;
            pv = __expf(e);
        }
        den += pv;
        int cnt = o1 - base;
        if (cnt >= 16) {
            // phase 1: all 16 gathers in flight
            ushort4 xr[16];
            #pragma unroll
            for (int j = 0; j < 16; ++j) {
                int s = __shfl(sv, j);
                xr[j] = *(const ushort4*)(xb + (size_t)s * 64 + c4);
            }
            // phase 2: weighted accumulation
            #pragma unroll
            for (int j = 0; j < 16; ++j) {
                float pj = __shfl(pv, base48 + j);
                a0 += pj * bf2f(xr[j].x); a1 += pj * bf2f(xr[j].y);
                a2 += pj * bf2f(xr[j].z); a3 += pj * bf2f(xr[j].w);
            }
        } else {
            for (int j = 0; j < cnt; ++j) {
                int s = __shfl(sv, j);
                float pj = __shfl(pv, base48 + j);
                ushort4 xv = *(const ushort4*)(xb + (size_t)s * 64 + c4);
                a0 += pj * bf2f(xv.x); a1 += pj * bf2f(xv.y);
                a2 += pj * bf2f(xv.z); a3 += pj * bf2f(xv.w);
            }
        }
    }
    den += __shfl_xor(den, 1); den += __shfl_xor(den, 2);
    den += __shfl_xor(den, 4); den += __shfl_xor(den, 8);
    float sc = 0.25f / (den + 1e-16f);
    ushort4 ov;
    ov.x = f2bf(a0 * sc); ov.y = f2bf(a1 * sc);
    ov.z = f2bf(a2 * sc); ov.w = f2bf(a3 * sc);
    *(ushort4*)(xagg + ((size_t)r * N_ + n) * 256 + h * 64 + c4) = ov;
}

// ---------------- post-projection: intra = xagg @ B~ ----------------
__global__ __launch_bounds__(256) void k_post(
    const u16* __restrict__ xagg, const u16* __restrict__ postB_pad,
    u16* __restrict__ intra, int t)
{
    int r = blockIdx.y;
    const u16* A = xagg + (size_t)r * N_ * 256;
    const u16* Bp = postB_pad + (size_t)r * 4 * 4608;
    const int tid = threadIdx.x, lane = tid & 63, wv = tid >> 6;
    const int col = lane & 15, quad = lane >> 4;
    int m0 = blockIdx.x * 64;
    int row = m0 + wv * 16 + col;
    int row_c = (row < N_) ? row : (N_ - 1);

    f32x4 acc[4];
    #pragma unroll
    for (int cf = 0; cf < 4; ++cf) { acc[cf][0]=0.f; acc[cf][1]=0.f; acc[cf][2]=0.f; acc[cf][3]=0.f; }
    #pragma unroll
    for (int kc = 0; kc < 4; ++kc) {
        #pragma unroll
        for (int ks = 0; ks < 2; ++ks) {
            bf16x8 a = *(const bf16x8*)(A + (size_t)row_c * 256 + kc * 64 + ks * 32 + quad * 8);
            const u16* bb = Bp + kc * 4608 + ks * 32 + quad * 8;
            #pragma unroll
            for (int cf = 0; cf < 4; ++cf) {
                bf16x8 b = *(const bf16x8*)(bb + (cf * 16 + col) * 72);
                acc[cf] = __builtin_amdgcn_mfma_f32_16x16x32_bf16(a, b, acc[cf], 0, 0, 0);
            }
        }
    }
    int rowbase = m0 + wv * 16 + quad * 4;
    #pragma unroll
    for (int cf = 0; cf < 4; ++cf) {
        int c = cf * 16 + col;
        #pragma unroll
        for (int reg = 0; reg < 4; ++reg) {
            int rr = rowbase + reg;
            if (rr < N_)
                intra[(((size_t)t * N_ + rr) * 2 + r) * 64 + c] = f2bf(acc[cf][reg]);
        }
    }
}

// ---------------- RelationAgg GEMM with fused ftanh(.)@W2 epilogue ----------------
__global__ __launch_bounds__(256) void k_relagg(
    const u16* __restrict__ A, const u16* __restrict__ W1pad, const float* __restrict__ b1,
    const float* __restrict__ W2, float* __restrict__ svals)
{
    int m0 = blockIdx.x * 64;
    f32x4 acc[16];
    gemm_direct(A, W1pad, T_ * N_ * R_, 64, 1, m0, acc);

    const int tid = threadIdx.x, lane = tid & 63, wv = tid >> 6;
    const int col = lane & 15, quad = lane >> 4;
    int rowbase = m0 + wv * 16 + quad * 4;
    float sp[4] = {0.f, 0.f, 0.f, 0.f};
    #pragma unroll
    for (int cf = 0; cf < 16; ++cf) {
        int gcol = cf * 16 + col;
        float bb = b1[gcol];
        float ww = W2[gcol];
        #pragma unroll
        for (int reg = 0; reg < 4; ++reg)
            sp[reg] += ftanh(acc[cf][reg] + bb) * ww;
    }
    #pragma unroll
    for (int reg = 0; reg < 4; ++reg) {
        float v = sp[reg];
        v += __shfl_xor(v, 1); v += __shfl_xor(v, 2);
        v += __shfl_xor(v, 4); v += __shfl_xor(v, 8);
        sp[reg] = v;
    }
    if (col == 0) {
        #pragma unroll
        for (int reg = 0; reg < 4; ++reg) {
            int row = rowbase + reg;
            if (row < T_ * N_ * R_) svals[row] = sp[reg];
        }
    }
}

__global__ void k_betasum(const float* __restrict__ svals, float* __restrict__ ssum) {
    int p = blockIdx.x, t = p >> 1, r = p & 1;
    __shared__ float red[256];
    float s = 0.f;
    for (int n = threadIdx.x; n < N_; n += 256)
        s += svals[((size_t)t * N_ + n) * 2 + r];
    red[threadIdx.x] = s;
    __syncthreads();
    for (int st = 128; st > 0; st >>= 1) {
        if (threadIdx.x < st) red[threadIdx.x] += red[threadIdx.x + st];
        __syncthreads();
    }
    if (threadIdx.x == 0) ssum[p] = red[0];
}

__global__ void k_betafinal(const float* __restrict__ ssum, float* __restrict__ beta) {
    int t = threadIdx.x;
    if (t >= 4) return;
    float s0 = ssum[t * 2] * (1.f / N_), s1 = ssum[t * 2 + 1] * (1.f / N_);
    float mx = fmaxf(s0, s1);
    float e0 = __expf(s0 - mx), e1 = __expf(s1 - mx);
    float inv = 1.f / (e0 + e1);
    beta[t * 2] = e0 * inv; beta[t * 2 + 1] = e1 * inv;
}

// ---------------- LSTM GEMM (A assembled on the fly) + fused cell update ----------------
__global__ __launch_bounds__(256) void k_lstm(
    const u16* __restrict__ intra, const float* __restrict__ beta,
    const u16* __restrict__ Wc_pad, const float* __restrict__ biasv,
    float* __restrict__ cbuf, u16* __restrict__ hbuf_bf, u16* __restrict__ feats, int t)
{
    const int tid = threadIdx.x, lane = tid & 63, wv = tid >> 6;
    const int col = lane & 15, quad = lane >> 4;
    int m0 = blockIdx.x * 64;
    int row = m0 + wv * 16 + col;
    int row_c = (row < N_) ? row : (N_ - 1);
    float b0 = beta[t * 2], b1 = beta[t * 2 + 1];
    const u16* ib = intra + ((size_t)t * N_ + row_c) * 128;

    f32x4 acc[16];
    #pragma unroll
    for (int cf = 0; cf < 16; ++cf) { acc[cf][0]=0.f; acc[cf][1]=0.f; acc[cf][2]=0.f; acc[cf][3]=0.f; }

    #pragma unroll
    for (int kc = 0; kc < 2; ++kc) {
        #pragma unroll
        for (int ks = 0; ks < 2; ++ks) {
            bf16x8 a;
            if (kc == 0) {
                int coff = ks * 32 + quad * 8;
                bf16x8 i0 = *(const bf16x8*)(ib + coff);
                bf16x8 i1 = *(const bf16x8*)(ib + 64 + coff);
                union { u16 h[8]; bf16x8 v; } cv;
                #pragma unroll
                for (int j = 0; j < 8; ++j)
                    cv.h[j] = f2bf(b0 * bf2f((u16)i0[j]) + b1 * bf2f((u16)i1[j]));
                a = cv.v;
            } else {
                a = *(const bf16x8*)(hbuf_bf + (size_t)row_c * 64 + ks * 32 + quad * 8);
            }
            const u16* bb = Wc_pad + kc * BPAD + ks * 32 + quad * 8;
            #pragma unroll
            for (int cf = 0; cf < 16; ++cf) {
                bf16x8 b = *(const bf16x8*)(bb + (cf * 16 + col) * 72);
                acc[cf] = __builtin_amdgcn_mfma_f32_16x16x32_bf16(a, b, acc[cf], 0, 0, 0);
            }
        }
    }

    int rowbase = m0 + wv * 16 + quad * 4;
    #pragma unroll
    for (int j = 0; j < 4; ++j) {
        int c = j * 16 + col;
        float bi = biasv[c], bf_ = biasv[64 + c], bg = biasv[128 + c], bo = biasv[192 + c];
        #pragma unroll
        for (int reg = 0; reg < 4; ++reg) {
            int rr = rowbase + reg;
            if (rr < N_) {
                float gi = acc[j][reg] + bi;
                float gf = acc[j + 4][reg] + bf_;
                float gg = acc[j + 8][reg] + bg;
                float go = acc[j + 12][reg] + bo;
                float cc = cbuf[(size_t)rr * 64 + c];
                cc = sigm(gf) * cc + sigm(gi) * ftanh(gg);
                float hh = sigm(go) * ftanh(cc);
                cbuf[(size_t)rr * 64 + c] = cc;
                hbuf_bf[(size_t)rr * 64 + c] = f2bf(hh);
                feats[(size_t)rr * 256 + t * 64 + c] = f2bf(hh);
            }
        }
    }
}

// ---------------- temporal causal MHA: MFMA QKV + per-lane attention ----------------
__global__ __launch_bounds__(256) void k_attn(
    const u16* __restrict__ feats, const float* __restrict__ pos_emb,
    const u16* __restrict__ qkv_pad, float* __restrict__ out)
{
    __shared__ float qkv_s[64 * 200];
    const int tid = threadIdx.x, lane = tid & 63, wv = tid >> 6;
    const int col = lane & 15, quad = lane >> 4;
    int m0 = blockIdx.x * 64;
    int row = m0 + wv * 16 + col;
    int trow = row & 3;

    f32x4 acc[12];
    #pragma unroll
    for (int cf = 0; cf < 12; ++cf) { acc[cf][0]=0.f; acc[cf][1]=0.f; acc[cf][2]=0.f; acc[cf][3]=0.f; }
    #pragma unroll
    for (int ks = 0; ks < 2; ++ks) {
        int coff = ks * 32 + quad * 8;
        bf16x8 fv = *(const bf16x8*)(feats + (size_t)row * 64 + coff);
        float4 p0 = *(const float4*)(pos_emb + trow * 64 + coff);
        float4 p1 = *(const float4*)(pos_emb + trow * 64 + coff + 4);
        union { u16 h[8]; bf16x8 v; } cv;
        cv.h[0] = f2bf(bf2f((u16)fv[0]) + p0.x); cv.h[1] = f2bf(bf2f((u16)fv[1]) + p0.y);
        cv.h[2] = f2bf(bf2f((u16)fv[2]) + p0.z); cv.h[3] = f2bf(bf2f((u16)fv[3]) + p0.w);
        cv.h[4] = f2bf(bf2f((u16)fv[4]) + p1.x); cv.h[5] = f2bf(bf2f((u16)fv[5]) + p1.y);
        cv.h[6] = f2bf(bf2f((u16)fv[6]) + p1.z); cv.h[7] = f2bf(bf2f((u16)fv[7]) + p1.w);
        bf16x8 a = cv.v;
        const u16* bb = qkv_pad + ks * 32 + quad * 8;
        #pragma unroll
        for (int cf = 0; cf < 12; ++cf) {
            bf16x8 b = *(const bf16x8*)(bb + (cf * 16 + col) * 72);
            acc[cf] = __builtin_amdgcn_mfma_f32_16x16x32_bf16(a, b, acc[cf], 0, 0, 0);
        }
    }
    #pragma unroll
    for (int cf = 0; cf < 12; ++cf) {
        int g = cf * 16 + col;
        #pragma unroll
        for (int reg = 0; reg < 4; ++reg) {
            int rl = wv * 16 + quad * 4 + reg;
            qkv_s[rl * 200 + g] = acc[cf][reg];
        }
    }
    __syncthreads();

    int nl = wv * 4 + (lane >> 4);
    int sub = lane & 15;
    int h = sub >> 2, tq = sub & 3;
    const float* qrow = qkv_s + (nl * 4 + tq) * 200 + h * 16;

    float s[4];
    #pragma unroll
    for (int tk = 0; tk < 4; ++tk) {
        const float* krow = qkv_s + (nl * 4 + tk) * 200 + 64 + h * 16;
        float d = 0.f;
        #pragma unroll
        for (int j = 0; j < 16; ++j) d += qrow[j] * krow[j];
        s[tk] = (tk > tq) ? -4294967295.0f : d * 0.5f;
    }
    float mx = fmaxf(fmaxf(s[0], s[1]), fmaxf(s[2], s[3]));
    float a0 = __expf(s[0]-mx), a1 = __expf(s[1]-mx), a2 = __expf(s[2]-mx), a3 = __expf(s[3]-mx);
    float inv = 1.f / (a0 + a1 + a2 + a3);
    a0 *= inv; a1 *= inv; a2 *= inv; a3 *= inv;

    int n = blockIdx.x * 16 + nl;
    const float* v0 = qkv_s + (nl * 4 + 0) * 200 + 128 + h * 16;
    const float* v1 = v0 + 200, *v2 = v0 + 400, *v3 = v0 + 600;
    #pragma unroll
    for (int cc4 = 0; cc4 < 4; ++cc4) {
        float4 o;
        o.x = a0*v0[cc4*4+0] + a1*v1[cc4*4+0] + a2*v2[cc4*4+0] + a3*v3[cc4*4+0];
        o.y = a0*v0[cc4*4+1] + a1*v1[cc4*4+1] + a2*v2[cc4*4+1] + a3*v3[cc4*4+1];
        o.z = a0*v0[cc4*4+2] + a1*v1[cc4*4+2] + a2*v2[cc4*4+2] + a3*v3[cc4*4+2];
        o.w = a0*v0[cc4*4+3] + a1*v1[cc4*4+3] + a2*v2[cc4*4+3] + a3*v3[cc4*4+3];
        *(float4*)(out + (size_t)n * 256 + tq * 64 + h * 16 + cc4 * 4) = o;
    }
}

// ---------------- launcher ----------------
extern "C" void kernel_launch(void* const* d_in, const int* in_sizes, int n_in,
                              void* d_out, int out_size, void* d_ws, size_t ws_size,
                              hipStream_t stream) {
    const float* x     = (const float*)d_in[0];
    const int* ei      = (const int*)d_in[1];
    const float* Wsrc  = (const float*)d_in[2];
    const float* Wdst  = (const float*)d_in[3];
    const float* att_src = (const float*)d_in[4];
    const float* att_dst = (const float*)d_in[5];
    const float* raW1  = (const float*)d_in[6];
    const float* rab1  = (const float*)d_in[7];
    const float* raW2  = (const float*)d_in[8];
    const float* Wih   = (const float*)d_in[9];
    const float* Whh   = (const float*)d_in[10];
    const float* bih   = (const float*)d_in[11];
    const float* bhh   = (const float*)d_in[12];
    const float* pos   = (const float*)d_in[13];
    const float* Wq    = (const float*)d_in[14];
    const float* Wk    = (const float*)d_in[15];
    const float* Wv    = (const float*)d_in[16];
    float* out = (float*)d_out;

    char* w = (char*)d_ws;
    size_t off = 0;
    auto alloc = [&](size_t bytes) -> char* {
        char* pp = w + off; off += (bytes + 255) & ~(size_t)255; return pp;
    };
    // ---- long-lived ----
    u16*   intra     = (u16*)  alloc((size_t)T_ * N_ * R_ * 64 * 2);  // 20.48 MB
    u16*   x_bf      = (u16*)  alloc((size_t)T_ * N_ * 64 * 2);       // 10.24 MB
    float* svals     = (float*)alloc((size_t)T_ * N_ * R_ * 4);
    float* ssum      = (float*)alloc(256);
    float* beta      = (float*)alloc(256);
    float* wdall     = (float*)alloc(1024 * 4);
    float* biasv     = (float*)alloc(256 * 4);
    u16*   raW1_pad  = (u16*)  alloc(BPAD * 2);
    u16*   Wc_pad    = (u16*)  alloc(2 * BPAD * 2);
    u16*   qkv_pad   = (u16*)  alloc(192 * 72 * 2);
    u16*   postB_pad = (u16*)  alloc(2 * 4 * 4608 * 2);
    int*   chunktot  = (int*)  alloc(P_ * NB_ * 4);
    int*   chunkbase = (int*)  alloc(P_ * NB_ * 4);
    // ---- union region ----
    char*  ubase   = alloc(0);
    size_t uoff = 0;
    auto ualloc = [&](size_t bytes) -> char* {
        char* pp = ubase + uoff; uoff += (bytes + 255) & ~(size_t)255; return pp;
    };
    int*   offsets = (int*)  ualloc((size_t)P_ * (N_ + 1) * 4);
    u16*   csr     = (u16*)  ualloc((size_t)P_ * E_ * 2);
    float* als_all = (float*)ualloc((size_t)P_ * N_ * 4 * 4);
    float* ald_all = (float*)ualloc((size_t)P_ * N_ * 4 * 4);
    u16*   partial = (u16*)  ualloc((size_t)P_ * NB_ * N_ * 2);
    u16*   xagg    = (u16*)  ualloc((size_t)R_ * N_ * 256 * 2);   // 20.48 MB
    u16*   rank    = (u16*)  xagg;   // overlay: rank dead before first k_agg
    // phase 2 overlay (phase-1 sub-buffers dead after the k_agg loop)
    float* cbuf    = (float*)(ubase);
    u16*   hbuf_bf = (u16*)  (ubase + 5300000);
    u16*   feats   = (u16*)  (ubase + 8000000);
    (void)ws_size; (void)in_sizes; (void)n_in; (void)out_size;

    k_prep<<<72, 256, 0, stream>>>(Wdst, att_dst, Wih, Whh, bih, bhh, Wsrc, att_src, raW1,
                                   Wq, Wk, Wv, wdall, biasv, raW1_pad, Wc_pad, qkv_pad, postB_pad);
    k_hist<<<dim3(NB_, 8), 256, 0, stream>>>(ei, rank, partial);
    k_scan1<<<dim3(NB_, 8), 256, 0, stream>>>(partial, offsets, chunktot);
    k_scan2<<<1, 64, 0, stream>>>(chunktot, chunkbase);
    k_scan3<<<dim3(79, 8), 256, 0, stream>>>(offsets, chunkbase);
    k_scatter<<<dim3(1250, 8), 256, 0, stream>>>(ei, offsets, rank, partial, csr);
    k_fold<<<dim3(313, 4), 256, 0, stream>>>(x, wdall, als_all, ald_all, x_bf);
    for (int t = 0; t < T_; ++t) {
        k_agg<<<dim3(5000, 2), 256, 0, stream>>>(offsets, csr,
                                                 als_all + (size_t)t * 2 * N_ * 4,
                                                 ald_all + (size_t)t * 2 * N_ * 4,
                                                 x_bf + (size_t)t * N_ * 64, xagg, t);
        k_post<<<dim3(313, 2), 256, 0, stream>>>(xagg, postB_pad, intra, t);
    }
    k_relagg<<<2500, 256, 0, stream>>>(intra, raW1_pad, rab1, raW2, svals);
    k_betasum<<<8, 256, 0, stream>>>(svals, ssum);
    k_betafinal<<<1, 64, 0, stream>>>(ssum, beta);
    hipMemsetAsync(cbuf, 0, (size_t)N_ * 64 * 4, stream);
    hipMemsetAsync(hbuf_bf, 0, (size_t)N_ * 64 * 2, stream);
    for (int t = 0; t < T_; ++t)
        k_lstm<<<313, 256, 0, stream>>>(intra, beta, Wc_pad, biasv, cbuf, hbuf_bf, feats, t);
    k_attn<<<1250, 256, 0, stream>>>(feats, pos, qkv_pad, out);
}

// Round 11
// 536.811 us; speedup vs baseline: 2.2537x; 1.0522x over previous
//
#include <hip/hip_runtime.h>
#include <hip/hip_bf16.h>

#define T_ 4
#define N_ 20000
#define E_ 320000
#define R_ 2
#define DIN 64
#define G_ 256   // H*Dh
#define P_ 8     // T*R
#define BPAD 18432  // 256 * 72 padded B-table halves per 64-k chunk
#define NB_ 32      // CSR-build blocks per p
#define EPB_ 10000  // edges per CSR-build block
#define CHN_ 625    // nodes per scan chunk (N_/32)

typedef unsigned short u16;
typedef __attribute__((ext_vector_type(8))) short bf16x8;
typedef __attribute__((ext_vector_type(4))) float f32x4;

__device__ __forceinline__ float bf2f(u16 u) {
    unsigned int i = ((unsigned int)u) << 16; float f;
    __builtin_memcpy(&f, &i, 4); return f;
}
__device__ __forceinline__ u16 f2bf(float f) {
    unsigned int i; __builtin_memcpy(&i, &f, 4);
    unsigned int r = i + 0x7fffu + ((i >> 16) & 1u);
    return (u16)(r >> 16);
}
__device__ __forceinline__ float sigm(float x) { return 1.f / (1.f + __expf(-x)); }
// fast tanh: 1 - 2/(exp(2x)+1); hardware v_exp_f32, correct saturation at +-inf
__device__ __forceinline__ float ftanh(float x) { return 1.f - 2.f / (__expf(2.f * x) + 1.f); }

// ---------------- LDS-free MFMA GEMM core (bf16 A) ----------------
__device__ __forceinline__ void gemm_direct(
    const u16* __restrict__ A, const u16* __restrict__ Bpad,
    int M, int Astride, int kchunks, int m0, f32x4* acc)
{
    const int tid = threadIdx.x;
    const int lane = tid & 63, wv = tid >> 6;
    const int col = lane & 15, quad = lane >> 4;
    #pragma unroll
    for (int cf = 0; cf < 16; ++cf) { acc[cf][0]=0.f; acc[cf][1]=0.f; acc[cf][2]=0.f; acc[cf][3]=0.f; }

    int row = m0 + wv * 16 + col;
    int row_c = (row < M) ? row : (M - 1);

    for (int kc = 0; kc < kchunks; ++kc) {
        #pragma unroll
        for (int ks = 0; ks < 2; ++ks) {
            bf16x8 a = *(const bf16x8*)(A + (size_t)row_c * Astride + kc * 64 + ks * 32 + quad * 8);
            const u16* bb = Bpad + kc * BPAD + ks * 32 + quad * 8;
            #pragma unroll
            for (int cf = 0; cf < 16; ++cf) {
                bf16x8 b = *(const bf16x8*)(bb + (cf * 16 + col) * 72);
                acc[cf] = __builtin_amdgcn_mfma_f32_16x16x32_bf16(a, b, acc[cf], 0, 0, 0);
            }
        }
    }
}

// ---------------- fold: als/ald GEMVs + x->bf16 cast; wdall staged in LDS ----------------
__global__ __launch_bounds__(256) void k_fold(
    const float* __restrict__ x, const float* __restrict__ wdall,
    float* __restrict__ als_all, float* __restrict__ ald_all, u16* __restrict__ x_bf)
{
    __shared__ float wds[1024];
    {
        int tid = threadIdx.x;
        *(float4*)(wds + tid * 4) = *(const float4*)(wdall + tid * 4);
    }
    __syncthreads();

    int t = blockIdx.y;
    int idx = blockIdx.x * 256 + threadIdx.x;
    if (idx >= N_ * 4) return;
    int n = idx >> 2, q = idx & 3;
    const float* xr = x + ((size_t)t * N_ + n) * 64 + q * 16;
    float4 xv[4];
    #pragma unroll
    for (int i = 0; i < 4; ++i) xv[i] = *(const float4*)(xr + i * 4);

    {
        union { u16 h[16]; ushort4 s4[4]; } cv;
        #pragma unroll
        for (int i = 0; i < 4; ++i) {
            cv.h[i*4+0] = f2bf(xv[i].x); cv.h[i*4+1] = f2bf(xv[i].y);
            cv.h[i*4+2] = f2bf(xv[i].z); cv.h[i*4+3] = f2bf(xv[i].w);
        }
        u16* xo = x_bf + ((size_t)t * N_ + n) * 64 + q * 16;
        #pragma unroll
        for (int i = 0; i < 4; ++i) *(ushort4*)(xo + i * 4) = cv.s4[i];
    }

    float s[16];
    #pragma unroll
    for (int i = 0; i < 16; ++i) s[i] = 0.f;
    #pragma unroll
    for (int i = 0; i < 4; ++i) {
        float xe[4] = {xv[i].x, xv[i].y, xv[i].z, xv[i].w};
        #pragma unroll
        for (int e = 0; e < 4; ++e) {
            int k = q * 16 + i * 4 + e;
            float xk = xe[e];
            #pragma unroll
            for (int tb = 0; tb < 4; ++tb) {
                float4 w = *(const float4*)(wds + tb * 256 + k * 4);
                s[tb*4+0] += xk * w.x; s[tb*4+1] += xk * w.y;
                s[tb*4+2] += xk * w.z; s[tb*4+3] += xk * w.w;
            }
        }
    }
    #pragma unroll
    for (int i = 0; i < 16; ++i) {
        s[i] += __shfl_xor(s[i], 1);
        s[i] += __shfl_xor(s[i], 2);
    }
    if (q == 0) {
        *(float4*)(als_all + ((size_t)(t*2+0) * N_ + n) * 4) = make_float4(s[0], s[1], s[2], s[3]);
        *(float4*)(als_all + ((size_t)(t*2+1) * N_ + n) * 4) = make_float4(s[4], s[5], s[6], s[7]);
        *(float4*)(ald_all + ((size_t)(t*2+0) * N_ + n) * 4) = make_float4(s[8], s[9], s[10], s[11]);
        *(float4*)(ald_all + ((size_t)(t*2+1) * N_ + n) * 4) = make_float4(s[12], s[13], s[14], s[15]);
    }
}

// ---------------- prep: folded GEMV tables, padded B-tables, folded bias ----------------
__global__ void k_prep(const float* __restrict__ Wdst, const float* __restrict__ att_dst,
                       const float* __restrict__ Wih, const float* __restrict__ Whh,
                       const float* __restrict__ bih, const float* __restrict__ bhh,
                       const float* __restrict__ Wsrc, const float* __restrict__ att_src,
                       const float* __restrict__ raW1,
                       const float* __restrict__ Wq, const float* __restrict__ Wk,
                       const float* __restrict__ Wv,
                       float* __restrict__ wdall, float* __restrict__ biasv,
                       u16* __restrict__ raW1_pad, u16* __restrict__ Wc_pad,
                       u16* __restrict__ qkv_pad, u16* __restrict__ postB_pad)
{
    int tid = threadIdx.x, bid = blockIdx.x;
    if (bid == 0) {
        int k = tid >> 2, h = tid & 3;
        for (int r = 0; r < 2; ++r) {
            float ss = 0.f, sd = 0.f;
            for (int c = 0; c < 64; ++c) {
                ss += Wsrc[((size_t)r * 64 + k) * 256 + h * 64 + c] * att_src[r * 256 + h * 64 + c];
                sd += Wdst[((size_t)r * 64 + k) * 256 + h * 64 + c] * att_dst[r * 256 + h * 64 + c];
            }
            wdall[r * 256 + k * 4 + h] = ss;
            wdall[512 + r * 256 + k * 4 + h] = sd;
        }
        biasv[tid] = bih[tid] + bhh[tid];
    }
    for (int i = bid * 256 + tid; i < BPAD; i += gridDim.x * 256) {
        int n = i / 72, kk = i % 72;
        raW1_pad[i] = (kk < 64) ? f2bf(raW1[kk * 256 + n]) : (u16)0;
    }
    for (int i = bid * 256 + tid; i < 2 * BPAD; i += gridDim.x * 256) {
        int kc = i / BPAD, q = i % BPAD, n = q / 72, kk = q % 72;
        const float* W = kc ? Whh : Wih;
        Wc_pad[i] = (kk < 64) ? f2bf(W[n * 64 + kk]) : (u16)0;
    }
    for (int i = bid * 256 + tid; i < 192 * 72; i += gridDim.x * 256) {
        int g = i / 72, kk = i % 72;
        int j = g >> 6, c = g & 63;
        const float* W = (j == 0) ? Wq : (j == 1) ? Wk : Wv;
        qkv_pad[i] = (kk < 64) ? f2bf(W[kk * 64 + c]) : (u16)0;
    }
    for (int i = bid * 256 + tid; i < 2 * 4 * 4608; i += gridDim.x * 256) {
        int r = i / 18432, q = i % 18432, kc = q / 4608, qq = q % 4608;
        int c = qq / 72, kk = qq % 72;
        postB_pad[i] = (kk < 64) ? f2bf(Wsrc[(size_t)r * 16384 + kk * 256 + kc * 64 + c]) : (u16)0;
    }
}

// ---------------- CSR build ----------------
__global__ __launch_bounds__(256) void k_hist(const int* __restrict__ ei,
                                              u16* __restrict__ rank, u16* __restrict__ partial)
{
    __shared__ unsigned int hist[N_ / 2];
    int b = blockIdx.x, p = blockIdx.y, tid = threadIdx.x;
    for (int i = tid; i < N_ / 2; i += 256) hist[i] = 0u;
    __syncthreads();
    const int* dsts = ei + ((size_t)p * 2 + 1) * E_ + b * EPB_;
    u16* rk = rank + (size_t)p * E_ + b * EPB_;
    for (int e = tid; e < EPB_; e += 256) {
        int dst = dsts[e];
        unsigned sh = (unsigned)(dst & 1) * 16u;
        unsigned old = atomicAdd(&hist[dst >> 1], 1u << sh);
        rk[e] = (u16)((old >> sh) & 0xffffu);
    }
    __syncthreads();
    u16* part = partial + ((size_t)p * NB_ + b) * N_;
    for (int n = tid; n < N_; n += 256) {
        unsigned hv = hist[n >> 1];
        part[n] = (u16)((hv >> ((unsigned)(n & 1) * 16u)) & 0xffffu);
    }
}

__global__ __launch_bounds__(256) void k_scan1(u16* __restrict__ partial,
                                               int* __restrict__ offsets, int* __restrict__ chunktot)
{
    int p = blockIdx.y, ch = blockIdx.x;
    int tid = threadIdx.x, lane = tid & 63, wid = tid >> 6;
    __shared__ int wtot[4];
    u16* part = partial + (size_t)p * NB_ * N_;
    int* ofs = offsets + (size_t)p * (N_ + 1);
    int n0 = ch * CHN_;
    int carry = 0;
    for (int rnd = 0; rnd < 3; ++rnd) {
        int i = rnd * 256 + tid;
        int n = n0 + i;
        int v = 0;
        if (i < CHN_) {
            int run = 0;
            #pragma unroll 8
            for (int b = 0; b < NB_; ++b) {
                int pv = part[b * N_ + n];
                part[b * N_ + n] = (u16)run;
                run += pv;
            }
            v = run;
        }
        int incl = v;
        for (int d = 1; d < 64; d <<= 1) { int u = __shfl_up(incl, d); if (lane >= d) incl += u; }
        if (lane == 63) wtot[wid] = incl;
        __syncthreads();
        if (tid < 4) {
            int iv = wtot[tid];
            for (int d = 1; d < 4; d <<= 1) { int u = __shfl_up(iv, d); if (tid >= d) iv += u; }
            wtot[tid] = iv;
        }
        __syncthreads();
        int woff = (wid > 0) ? wtot[wid - 1] : 0;
        int tot = wtot[3];
        int excl = carry + woff + incl - v;
        if (i < CHN_) ofs[n] = excl;
        carry += tot;
        __syncthreads();
    }
    if (tid == 0) chunktot[p * NB_ + ch] = carry;
}

__global__ void k_scan2(const int* __restrict__ chunktot, int* __restrict__ chunkbase) {
    int tid = threadIdx.x;
    if (tid < P_) {
        int run = 0;
        for (int c = 0; c < NB_; ++c) {
            chunkbase[tid * NB_ + c] = run;
            run += chunktot[tid * NB_ + c];
        }
    }
}

__global__ void k_scan3(int* __restrict__ offsets, const int* __restrict__ chunkbase) {
    int p = blockIdx.y;
    int n = blockIdx.x * 256 + threadIdx.x;
    if (n < N_)
        offsets[(size_t)p * (N_ + 1) + n] += chunkbase[p * NB_ + n / CHN_];
    if (n == 0)
        offsets[(size_t)p * (N_ + 1) + N_] = E_;
}

__global__ void k_scatter(const int* __restrict__ ei, const int* __restrict__ offsets,
                          const u16* __restrict__ rank, const u16* __restrict__ partial,
                          u16* __restrict__ csr) {
    int p = blockIdx.y;
    int e = blockIdx.x * 256 + threadIdx.x;
    if (e >= E_) return;
    int src = ei[((size_t)p * 2 + 0) * E_ + e];
    int dst = ei[((size_t)p * 2 + 1) * E_ + e];
    int b = e / EPB_;
    int pos = offsets[p * (N_ + 1) + dst]
            + (int)partial[((size_t)p * NB_ + b) * N_ + dst]
            + (int)rank[(size_t)p * E_ + e];
    csr[(size_t)p * E_ + pos] = (u16)src;
}

// ---------------- GAT aggregation over x: hoisted-gather batches ----------------
__global__ __launch_bounds__(256) void k_agg(
    const int* __restrict__ offsets, const u16* __restrict__ csr,
    const float* __restrict__ als_t, const float* __restrict__ ald_t,
    const u16* __restrict__ xb, u16* __restrict__ xagg, int t)
{
    int r = blockIdx.y;
    const int* off = offsets + (size_t)(t * 2 + r) * (N_ + 1);
    const u16* srcs = csr + (size_t)(t * 2 + r) * E_;
    const float* als = als_t + (size_t)r * N_ * 4;
    const float* ald = ald_t + (size_t)r * N_ * 4;

    int tid = threadIdx.x, lane = tid & 63, wv = tid >> 6;
    int n = blockIdx.x * 4 + wv;
    int h = lane >> 4, j16 = lane & 15, c4 = j16 * 4;
    int base48 = lane & 48;
    int o0 = off[n], o1 = off[n + 1];
    float aldv = ald[(size_t)n * 4 + h];

    float den = 0.f, a0 = 0.f, a1 = 0.f, a2 = 0.f, a3 = 0.f;
    for (int base = o0; base < o1; base += 16) {
        int idx = base + j16;
        int sv = 0; float pv = 0.f;
        if (idx < o1) {
            sv = (int)srcs[idx];
            float e = als[sv * 4 + h] + aldv;
            e = (e > 0.f) ? e : 0.2f * e;
            pv = __expf(e);
        }
        den += pv;
        int cnt = o1 - base;
        if (cnt >= 16) {
            ushort4 xr[16];
            #pragma unroll
            for (int j = 0; j < 16; ++j) {
                int s = __shfl(sv, j);
                xr[j] = *(const ushort4*)(xb + (size_t)s * 64 + c4);
            }
            #pragma unroll
            for (int j = 0; j < 16; ++j) {
                float pj = __shfl(pv, base48 + j);
                a0 += pj * bf2f(xr[j].x); a1 += pj * bf2f(xr[j].y);
                a2 += pj * bf2f(xr[j].z); a3 += pj * bf2f(xr[j].w);
            }
        } else {
            for (int j = 0; j < cnt; ++j) {
                int s = __shfl(sv, j);
                float pj = __shfl(pv, base48 + j);
                ushort4 xv = *(const ushort4*)(xb + (size_t)s * 64 + c4);
                a0 += pj * bf2f(xv.x); a1 += pj * bf2f(xv.y);
                a2 += pj * bf2f(xv.z); a3 += pj * bf2f(xv.w);
            }
        }
    }
    den += __shfl_xor(den, 1); den += __shfl_xor(den, 2);
    den += __shfl_xor(den, 4); den += __shfl_xor(den, 8);
    float sc = 0.25f / (den + 1e-16f);
    ushort4 ov;
    ov.x = f2bf(a0 * sc); ov.y = f2bf(a1 * sc);
    ov.z = f2bf(a2 * sc); ov.w = f2bf(a3 * sc);
    *(ushort4*)(xagg + ((size_t)r * N_ + n) * 256 + h * 64 + c4) = ov;
}

// ---------------- post-projection: intra = xagg @ B~ ----------------
__global__ __launch_bounds__(256) void k_post(
    const u16* __restrict__ xagg, const u16* __restrict__ postB_pad,
    u16* __restrict__ intra, int t)
{
    int r = blockIdx.y;
    const u16* A = xagg + (size_t)r * N_ * 256;
    const u16* Bp = postB_pad + (size_t)r * 4 * 4608;
    const int tid = threadIdx.x, lane = tid & 63, wv = tid >> 6;
    const int col = lane & 15, quad = lane >> 4;
    int m0 = blockIdx.x * 64;
    int row = m0 + wv * 16 + col;
    int row_c = (row < N_) ? row : (N_ - 1);

    f32x4 acc[4];
    #pragma unroll
    for (int cf = 0; cf < 4; ++cf) { acc[cf][0]=0.f; acc[cf][1]=0.f; acc[cf][2]=0.f; acc[cf][3]=0.f; }
    #pragma unroll
    for (int kc = 0; kc < 4; ++kc) {
        #pragma unroll
        for (int ks = 0; ks < 2; ++ks) {
            bf16x8 a = *(const bf16x8*)(A + (size_t)row_c * 256 + kc * 64 + ks * 32 + quad * 8);
            const u16* bb = Bp + kc * 4608 + ks * 32 + quad * 8;
            #pragma unroll
            for (int cf = 0; cf < 4; ++cf) {
                bf16x8 b = *(const bf16x8*)(bb + (cf * 16 + col) * 72);
                acc[cf] = __builtin_amdgcn_mfma_f32_16x16x32_bf16(a, b, acc[cf], 0, 0, 0);
            }
        }
    }
    int rowbase = m0 + wv * 16 + quad * 4;
    #pragma unroll
    for (int cf = 0; cf < 4; ++cf) {
        int c = cf * 16 + col;
        #pragma unroll
        for (int reg = 0; reg < 4; ++reg) {
            int rr = rowbase + reg;
            if (rr < N_)
                intra[(((size_t)t * N_ + rr) * 2 + r) * 64 + c] = f2bf(acc[cf][reg]);
        }
    }
}

// ---------------- RelationAgg GEMM with fused ftanh(.)@W2 epilogue ----------------
__global__ __launch_bounds__(256) void k_relagg(
    const u16* __restrict__ A, const u16* __restrict__ W1pad, const float* __restrict__ b1,
    const float* __restrict__ W2, float* __restrict__ svals)
{
    int m0 = blockIdx.x * 64;
    f32x4 acc[16];
    gemm_direct(A, W1pad, T_ * N_ * R_, 64, 1, m0, acc);

    const int tid = threadIdx.x, lane = tid & 63, wv = tid >> 6;
    const int col = lane & 15, quad = lane >> 4;
    int rowbase = m0 + wv * 16 + quad * 4;
    float sp[4] = {0.f, 0.f, 0.f, 0.f};
    #pragma unroll
    for (int cf = 0; cf < 16; ++cf) {
        int gcol = cf * 16 + col;
        float bb = b1[gcol];
        float ww = W2[gcol];
        #pragma unroll
        for (int reg = 0; reg < 4; ++reg)
            sp[reg] += ftanh(acc[cf][reg] + bb) * ww;
    }
    #pragma unroll
    for (int reg = 0; reg < 4; ++reg) {
        float v = sp[reg];
        v += __shfl_xor(v, 1); v += __shfl_xor(v, 2);
        v += __shfl_xor(v, 4); v += __shfl_xor(v, 8);
        sp[reg] = v;
    }
    if (col == 0) {
        #pragma unroll
        for (int reg = 0; reg < 4; ++reg) {
            int row = rowbase + reg;
            if (row < T_ * N_ * R_) svals[row] = sp[reg];
        }
    }
}

__global__ void k_betasum(const float* __restrict__ svals, float* __restrict__ ssum) {
    int p = blockIdx.x, t = p >> 1, r = p & 1;
    __shared__ float red[256];
    float s = 0.f;
    for (int n = threadIdx.x; n < N_; n += 256)
        s += svals[((size_t)t * N_ + n) * 2 + r];
    red[threadIdx.x] = s;
    __syncthreads();
    for (int st = 128; st > 0; st >>= 1) {
        if (threadIdx.x < st) red[threadIdx.x] += red[threadIdx.x + st];
        __syncthreads();
    }
    if (threadIdx.x == 0) ssum[p] = red[0];
}

__global__ void k_betafinal(const float* __restrict__ ssum, float* __restrict__ beta) {
    int t = threadIdx.x;
    if (t >= 4) return;
    float s0 = ssum[t * 2] * (1.f / N_), s1 = ssum[t * 2 + 1] * (1.f / N_);
    float mx = fmaxf(s0, s1);
    float e0 = __expf(s0 - mx), e1 = __expf(s1 - mx);
    float inv = 1.f / (e0 + e1);
    beta[t * 2] = e0 * inv; beta[t * 2 + 1] = e1 * inv;
}

// ---------------- LSTM GEMM (A assembled on the fly) + fused cell update ----------------
__global__ __launch_bounds__(256) void k_lstm(
    const u16* __restrict__ intra, const float* __restrict__ beta,
    const u16* __restrict__ Wc_pad, const float* __restrict__ biasv,
    float* __restrict__ cbuf, u16* __restrict__ hbuf_bf, u16* __restrict__ feats, int t)
{
    const int tid = threadIdx.x, lane = tid & 63, wv = tid >> 6;
    const int col = lane & 15, quad = lane >> 4;
    int m0 = blockIdx.x * 64;
    int row = m0 + wv * 16 + col;
    int row_c = (row < N_) ? row : (N_ - 1);
    float b0 = beta[t * 2], b1 = beta[t * 2 + 1];
    const u16* ib = intra + ((size_t)t * N_ + row_c) * 128;

    f32x4 acc[16];
    #pragma unroll
    for (int cf = 0; cf < 16; ++cf) { acc[cf][0]=0.f; acc[cf][1]=0.f; acc[cf][2]=0.f; acc[cf][3]=0.f; }

    #pragma unroll
    for (int kc = 0; kc < 2; ++kc) {
        #pragma unroll
        for (int ks = 0; ks < 2; ++ks) {
            bf16x8 a;
            if (kc == 0) {
                int coff = ks * 32 + quad * 8;
                bf16x8 i0 = *(const bf16x8*)(ib + coff);
                bf16x8 i1 = *(const bf16x8*)(ib + 64 + coff);
                union { u16 h[8]; bf16x8 v; } cv;
                #pragma unroll
                for (int j = 0; j < 8; ++j)
                    cv.h[j] = f2bf(b0 * bf2f((u16)i0[j]) + b1 * bf2f((u16)i1[j]));
                a = cv.v;
            } else {
                a = *(const bf16x8*)(hbuf_bf + (size_t)row_c * 64 + ks * 32 + quad * 8);
            }
            const u16* bb = Wc_pad + kc * BPAD + ks * 32 + quad * 8;
            #pragma unroll
            for (int cf = 0; cf < 16; ++cf) {
                bf16x8 b = *(const bf16x8*)(bb + (cf * 16 + col) * 72);
                acc[cf] = __builtin_amdgcn_mfma_f32_16x16x32_bf16(a, b, acc[cf], 0, 0, 0);
            }
        }
    }

    int rowbase = m0 + wv * 16 + quad * 4;
    #pragma unroll
    for (int j = 0; j < 4; ++j) {
        int c = j * 16 + col;
        float bi = biasv[c], bf_ = biasv[64 + c], bg = biasv[128 + c], bo = biasv[192 + c];
        #pragma unroll
        for (int reg = 0; reg < 4; ++reg) {
            int rr = rowbase + reg;
            if (rr < N_) {
                float gi = acc[j][reg] + bi;
                float gf = acc[j + 4][reg] + bf_;
                float gg = acc[j + 8][reg] + bg;
                float go = acc[j + 12][reg] + bo;
                float cc = cbuf[(size_t)rr * 64 + c];
                cc = sigm(gf) * cc + sigm(gi) * ftanh(gg);
                float hh = sigm(go) * ftanh(cc);
                cbuf[(size_t)rr * 64 + c] = cc;
                hbuf_bf[(size_t)rr * 64 + c] = f2bf(hh);
                feats[(size_t)rr * 256 + t * 64 + c] = f2bf(hh);
            }
        }
    }
}

// ---------------- temporal causal MHA: MFMA QKV + per-lane attention ----------------
__global__ __launch_bounds__(256) void k_attn(
    const u16* __restrict__ feats, const float* __restrict__ pos_emb,
    const u16* __restrict__ qkv_pad, float* __restrict__ out)
{
    __shared__ float qkv_s[64 * 200];
    const int tid = threadIdx.x, lane = tid & 63, wv = tid >> 6;
    const int col = lane & 15, quad = lane >> 4;
    int m0 = blockIdx.x * 64;
    int row = m0 + wv * 16 + col;
    int trow = row & 3;

    f32x4 acc[12];
    #pragma unroll
    for (int cf = 0; cf < 12; ++cf) { acc[cf][0]=0.f; acc[cf][1]=0.f; acc[cf][2]=0.f; acc[cf][3]=0.f; }
    #pragma unroll
    for (int ks = 0; ks < 2; ++ks) {
        int coff = ks * 32 + quad * 8;
        bf16x8 fv = *(const bf16x8*)(feats + (size_t)row * 64 + coff);
        float4 p0 = *(const float4*)(pos_emb + trow * 64 + coff);
        float4 p1 = *(const float4*)(pos_emb + trow * 64 + coff + 4);
        union { u16 h[8]; bf16x8 v; } cv;
        cv.h[0] = f2bf(bf2f((u16)fv[0]) + p0.x); cv.h[1] = f2bf(bf2f((u16)fv[1]) + p0.y);
        cv.h[2] = f2bf(bf2f((u16)fv[2]) + p0.z); cv.h[3] = f2bf(bf2f((u16)fv[3]) + p0.w);
        cv.h[4] = f2bf(bf2f((u16)fv[4]) + p1.x); cv.h[5] = f2bf(bf2f((u16)fv[5]) + p1.y);
        cv.h[6] = f2bf(bf2f((u16)fv[6]) + p1.z); cv.h[7] = f2bf(bf2f((u16)fv[7]) + p1.w);
        bf16x8 a = cv.v;
        const u16* bb = qkv_pad + ks * 32 + quad * 8;
        #pragma unroll
        for (int cf = 0; cf < 12; ++cf) {
            bf16x8 b = *(const bf16x8*)(bb + (cf * 16 + col) * 72);
            acc[cf] = __builtin_amdgcn_mfma_f32_16x16x32_bf16(a, b, acc[cf], 0, 0, 0);
        }
    }
    #pragma unroll
    for (int cf = 0; cf < 12; ++cf) {
        int g = cf * 16 + col;
        #pragma unroll
        for (int reg = 0; reg < 4; ++reg) {
            int rl = wv * 16 + quad * 4 + reg;
            qkv_s[rl * 200 + g] = acc[cf][reg];
        }
    }
    __syncthreads();

    int nl = wv * 4 + (lane >> 4);
    int sub = lane & 15;
    int h = sub >> 2, tq = sub & 3;
    const float* qrow = qkv_s + (nl * 4 + tq) * 200 + h * 16;

    float s[4];
    #pragma unroll
    for (int tk = 0; tk < 4; ++tk) {
        const float* krow = qkv_s + (nl * 4 + tk) * 200 + 64 + h * 16;
        float d = 0.f;
        #pragma unroll
        for (int j = 0; j < 16; ++j) d += qrow[j] * krow[j];
        s[tk] = (tk > tq) ? -4294967295.0f : d * 0.5f;
    }
    float mx = fmaxf(fmaxf(s[0], s[1]), fmaxf(s[2], s[3]));
    float a0 = __expf(s[0]-mx), a1 = __expf(s[1]-mx), a2 = __expf(s[2]-mx), a3 = __expf(s[3]-mx);
    float inv = 1.f / (a0 + a1 + a2 + a3);
    a0 *= inv; a1 *= inv; a2 *= inv; a3 *= inv;

    int n = blockIdx.x * 16 + nl;
    const float* v0 = qkv_s + (nl * 4 + 0) * 200 + 128 + h * 16;
    const float* v1 = v0 + 200, *v2 = v0 + 400, *v3 = v0 + 600;
    #pragma unroll
    for (int cc4 = 0; cc4 < 4; ++cc4) {
        float4 o;
        o.x = a0*v0[cc4*4+0] + a1*v1[cc4*4+0] + a2*v2[cc4*4+0] + a3*v3[cc4*4+0];
        o.y = a0*v0[cc4*4+1] + a1*v1[cc4*4+1] + a2*v2[cc4*4+1] + a3*v3[cc4*4+1];
        o.z = a0*v0[cc4*4+2] + a1*v1[cc4*4+2] + a2*v2[cc4*4+2] + a3*v3[cc4*4+2];
        o.w = a0*v0[cc4*4+3] + a1*v1[cc4*4+3] + a2*v2[cc4*4+3] + a3*v3[cc4*4+3];
        *(float4*)(out + (size_t)n * 256 + tq * 64 + h * 16 + cc4 * 4) = o;
    }
}

// ---------------- launcher ----------------
extern "C" void kernel_launch(void* const* d_in, const int* in_sizes, int n_in,
                              void* d_out, int out_size, void* d_ws, size_t ws_size,
                              hipStream_t stream) {
    const float* x     = (const float*)d_in[0];
    const int* ei      = (const int*)d_in[1];
    const float* Wsrc  = (const float*)d_in[2];
    const float* Wdst  = (const float*)d_in[3];
    const float* att_src = (const float*)d_in[4];
    const float* att_dst = (const float*)d_in[5];
    const float* raW1  = (const float*)d_in[6];
    const float* rab1  = (const float*)d_in[7];
    const float* raW2  = (const float*)d_in[8];
    const float* Wih   = (const float*)d_in[9];
    const float* Whh   = (const float*)d_in[10];
    const float* bih   = (const float*)d_in[11];
    const float* bhh   = (const float*)d_in[12];
    const float* pos   = (const float*)d_in[13];
    const float* Wq    = (const float*)d_in[14];
    const float* Wk    = (const float*)d_in[15];
    const float* Wv    = (const float*)d_in[16];
    float* out = (float*)d_out;

    char* w = (char*)d_ws;
    size_t off = 0;
    auto alloc = [&](size_t bytes) -> char* {
        char* pp = w + off; off += (bytes + 255) & ~(size_t)255; return pp;
    };
    // ---- long-lived ----
    u16*   intra     = (u16*)  alloc((size_t)T_ * N_ * R_ * 64 * 2);  // 20.48 MB
    u16*   x_bf      = (u16*)  alloc((size_t)T_ * N_ * 64 * 2);       // 10.24 MB
    float* svals     = (float*)alloc((size_t)T_ * N_ * R_ * 4);
    float* ssum      = (float*)alloc(256);
    float* beta      = (float*)alloc(256);
    float* wdall     = (float*)alloc(1024 * 4);
    float* biasv     = (float*)alloc(256 * 4);
    u16*   raW1_pad  = (u16*)  alloc(BPAD * 2);
    u16*   Wc_pad    = (u16*)  alloc(2 * BPAD * 2);
    u16*   qkv_pad   = (u16*)  alloc(192 * 72 * 2);
    u16*   postB_pad = (u16*)  alloc(2 * 4 * 4608 * 2);
    int*   chunktot  = (int*)  alloc(P_ * NB_ * 4);
    int*   chunkbase = (int*)  alloc(P_ * NB_ * 4);
    // ---- union region ----
    char*  ubase   = alloc(0);
    size_t uoff = 0;
    auto ualloc = [&](size_t bytes) -> char* {
        char* pp = ubase + uoff; uoff += (bytes + 255) & ~(size_t)255; return pp;
    };
    int*   offsets = (int*)  ualloc((size_t)P_ * (N_ + 1) * 4);
    u16*   csr     = (u16*)  ualloc((size_t)P_ * E_ * 2);
    float* als_all = (float*)ualloc((size_t)P_ * N_ * 4 * 4);
    float* ald_all = (float*)ualloc((size_t)P_ * N_ * 4 * 4);
    u16*   partial = (u16*)  ualloc((size_t)P_ * NB_ * N_ * 2);
    u16*   xagg    = (u16*)  ualloc((size_t)R_ * N_ * 256 * 2);   // 20.48 MB
    u16*   rank    = (u16*)  xagg;   // overlay: rank dead before first k_agg
    // phase 2 overlay (phase-1 sub-buffers dead after the k_agg loop)
    float* cbuf    = (float*)(ubase);
    u16*   hbuf_bf = (u16*)  (ubase + 5300000);
    u16*   feats   = (u16*)  (ubase + 8000000);
    (void)ws_size; (void)in_sizes; (void)n_in; (void)out_size;

    k_prep<<<72, 256, 0, stream>>>(Wdst, att_dst, Wih, Whh, bih, bhh, Wsrc, att_src, raW1,
                                   Wq, Wk, Wv, wdall, biasv, raW1_pad, Wc_pad, qkv_pad, postB_pad);
    k_hist<<<dim3(NB_, 8), 256, 0, stream>>>(ei, rank, partial);
    k_scan1<<<dim3(NB_, 8), 256, 0, stream>>>(partial, offsets, chunktot);
    k_scan2<<<1, 64, 0, stream>>>(chunktot, chunkbase);
    k_scan3<<<dim3(79, 8), 256, 0, stream>>>(offsets, chunkbase);
    k_scatter<<<dim3(1250, 8), 256, 0, stream>>>(ei, offsets, rank, partial, csr);
    k_fold<<<dim3(313, 4), 256, 0, stream>>>(x, wdall, als_all, ald_all, x_bf);
    for (int t = 0; t < T_; ++t) {
        k_agg<<<dim3(5000, 2), 256, 0, stream>>>(offsets, csr,
                                                 als_all + (size_t)t * 2 * N_ * 4,
                                                 ald_all + (size_t)t * 2 * N_ * 4,
                                                 x_bf + (size_t)t * N_ * 64, xagg, t);
        k_post<<<dim3(313, 2), 256, 0, stream>>>(xagg, postB_pad, intra, t);
    }
    k_relagg<<<2500, 256, 0, stream>>>(intra, raW1_pad, rab1, raW2, svals);
    k_betasum<<<8, 256, 0, stream>>>(svals, ssum);
    k_betafinal<<<1, 64, 0, stream>>>(ssum, beta);
    hipMemsetAsync(cbuf, 0, (size_t)N_ * 64 * 4, stream);
    hipMemsetAsync(hbuf_bf, 0, (size_t)N_ * 64 * 2, stream);
    for (int t = 0; t < T_; ++t)
        k_lstm<<<313, 256, 0, stream>>>(intra, beta, Wc_pad, biasv, cbuf, hbuf_bf, feats, t);
    k_attn<<<1250, 256, 0, stream>>>(feats, pos, qkv_pad, out);
}